// Round 1
// baseline (378.438 us; speedup 1.0000x reference)
//
#include <hip/hip_runtime.h>
#include <stdint.h>
#include <math.h>

// ReformerAttention on MI355X — fp32 I/O. B=2,T=2048,E=512,H=8,Dh=64,
// 2 hash rounds, buckets<32 attend.
// Projection row p = logical (b'=p>>11, t'=p&2047); gathers input row (b=p&1, t=p>>1).
//
// 8 launches:
//   prep (3-way bf16 split of query/key/Wq/Wk + hi/lo split Wv/Wo + zero attn/cnt)
//   -> qk_mfma (Q,K proj: 8-term bf16 MFMA == fp32-exact to ~1e-7; argmax-safe)
//   -> mfma(V, gather) -> hash(+hist) -> scan(+tasks) -> scatter2
//   -> attn_task -> mfma(out, perm)
// Q,K proj precision: x = h+m+l (3x bf16 = 24 mantissa bits, exact);
//   keep products hh,hm,mh,mm,hl,lh,ml,lm (drop only ll ~2^-32) -> logit error
//   in the fp32 accumulation-order class (~1e-7), same as the old fp32 tile GEMM.
// V/out proj: bf16 MFMA 16x16x32, 3-term hi/lo split, 2x4 tiles/wave (unchanged).

#define T_ 2048
#define E_ 512
#define H_ 8
#define DH_ 64
#define B_ 2
#define M_ 4096
#define NROUND 2
#define NBUCKET 32
#define NSEG 32
#define MAXTASK 5120

typedef short v8s __attribute__((ext_vector_type(8)));
typedef float v4f __attribute__((ext_vector_type(4)));

__device__ __forceinline__ float bf2f(uint16_t u) {
  union { uint32_t i; float f; } v; v.i = ((uint32_t)u) << 16; return v.f;
}
__device__ __forceinline__ uint16_t f2bf(float f) {
  union { float fv; uint32_t i; } v; v.fv = f;
  uint32_t x = v.i;
  x += 0x7fffu + ((x >> 16) & 1u);   // RN-even
  return (uint16_t)(x >> 16);
}
__device__ __forceinline__ void split8(const float4 a, const float4 b,
                                       v8s& h, v8s& l) {
  const float x[8] = {a.x, a.y, a.z, a.w, b.x, b.y, b.z, b.w};
#pragma unroll
  for (int j = 0; j < 8; j++) {
    const uint16_t hh = f2bf(x[j]);
    h[j] = (short)hh;
    l[j] = (short)f2bf(x[j] - bf2f(hh));
  }
}
__device__ __forceinline__ void split3_8(const float4 a, const float4 b,
                                         v8s& h, v8s& m, v8s& l) {
  const float x[8] = {a.x, a.y, a.z, a.w, b.x, b.y, b.z, b.w};
#pragma unroll
  for (int j = 0; j < 8; j++) {
    const uint16_t hh = f2bf(x[j]);
    const float r = x[j] - bf2f(hh);       // exact (Sterbenz)
    const uint16_t mm = f2bf(r);
    const float r2 = r - bf2f(mm);         // exact
    h[j] = (short)hh;
    m[j] = (short)mm;
    l[j] = (short)f2bf(r2);
  }
}

// ---------------------------------------------------------------------------
// prep: pure-bandwidth staging.
//   blocks [0,1024)    : query 3-way split, gathered into GEMM row order
//   blocks [1024,2048) : key   3-way split, gathered
//   blocks [2048,2176) : Wq 3-way split
//   blocks [2176,2304) : Wk 3-way split
//   blocks [2304,2432) : Wv hi/lo split
//   blocks [2432,2560) : Wo hi/lo split
//   blocks [2560,3584) : zero attn
//   block  3584        : zero cnt region
// ---------------------------------------------------------------------------
__global__ __launch_bounds__(256) void prep_kernel(
    const float* __restrict__ Xq, const float* __restrict__ Xk,
    const float* __restrict__ Wq, const float* __restrict__ Wk,
    const float* __restrict__ Wv, const float* __restrict__ Wo,
    uint16_t* __restrict__ Xqh, uint16_t* __restrict__ Xqm, uint16_t* __restrict__ Xql,
    uint16_t* __restrict__ Xkh, uint16_t* __restrict__ Xkm, uint16_t* __restrict__ Xkl,
    uint16_t* __restrict__ Wqh, uint16_t* __restrict__ Wqm, uint16_t* __restrict__ Wql,
    uint16_t* __restrict__ Wkh, uint16_t* __restrict__ Wkm, uint16_t* __restrict__ Wkl,
    uint16_t* __restrict__ Wvh, uint16_t* __restrict__ Wvl,
    uint16_t* __restrict__ Woh, uint16_t* __restrict__ Wol,
    float* __restrict__ attn, int* __restrict__ cnt)
{
  const int bid = blockIdx.x;
  const int tid = threadIdx.x;

  if (bid < 2048) {                      // query/key 3-way split (gathered)
    const int is_k = bid >> 10;
    const float* X = is_k ? Xk : Xq;
    uint16_t* H = is_k ? Xkh : Xqh;
    uint16_t* M = is_k ? Xkm : Xqm;
    uint16_t* L = is_k ? Xkl : Xql;
    const int e = ((bid & 1023) * 256 + tid) * 8;   // [0, M_*E_)
    const int p = e >> 9, k = e & 511;
    const long src = ((long)(p & 1) * T_ + (p >> 1)) * E_ + k;
    const float4 a = *(const float4*)(X + src);
    const float4 b = *(const float4*)(X + src + 4);
    v8s h, m, l;
    split3_8(a, b, h, m, l);
    *(v8s*)(H + e) = h;
    *(v8s*)(M + e) = m;
    *(v8s*)(L + e) = l;
    return;
  }

  if (bid < 2560) {                      // weight splits
    const int wsel = (bid - 2048) >> 7;  // 0=Wq,1=Wk,2=Wv,3=Wo
    const int e = (((bid - 2048) & 127) * 256 + tid) * 8;   // [0, E_*E_)
    if (wsel < 2) {
      const float* S = wsel ? Wk : Wq;
      const float4 a = *(const float4*)(S + e);
      const float4 b = *(const float4*)(S + e + 4);
      v8s h, m, l;
      split3_8(a, b, h, m, l);
      uint16_t* H = wsel ? Wkh : Wqh;
      uint16_t* M = wsel ? Wkm : Wqm;
      uint16_t* L = wsel ? Wkl : Wql;
      *(v8s*)(H + e) = h;
      *(v8s*)(M + e) = m;
      *(v8s*)(L + e) = l;
    } else {
      const float* S = (wsel == 2) ? Wv : Wo;
      const float4 a = *(const float4*)(S + e);
      const float4 b = *(const float4*)(S + e + 4);
      v8s h, l;
      split8(a, b, h, l);
      uint16_t* H = (wsel == 2) ? Wvh : Woh;
      uint16_t* L = (wsel == 2) ? Wvl : Wol;
      *(v8s*)(H + e) = h;
      *(v8s*)(L + e) = l;
    }
    return;
  }

  if (bid < 3584) {                      // zero attn: 1024 blocks x 512 float4
    float4* a4 = (float4*)attn;
    const int g = (bid - 2560) * 512 + tid * 2;
    a4[g] = make_float4(0.f, 0.f, 0.f, 0.f);
    a4[g + 1] = make_float4(0.f, 0.f, 0.f, 0.f);
    return;
  }

  for (int i = tid; i < 2 * NSEG * NBUCKET + 1; i += 256) cnt[i] = 0;
}

// ---------------------------------------------------------------------------
// qk_mfma: Q/K projection via 8-term 3-way-bf16-split MFMA (fp32-equivalent).
// grid (M/128, E/64, 2), 256 threads, 2x4 16x16 tiles/wave. A pre-split &
// pre-gathered (linear reads); C written fp32 in GEMM row order (= Q/K layout).
// ---------------------------------------------------------------------------
__global__ __launch_bounds__(256) void qk_mfma(
    const uint16_t* __restrict__ Aqh, const uint16_t* __restrict__ Aqm,
    const uint16_t* __restrict__ Aql,
    const uint16_t* __restrict__ Akh, const uint16_t* __restrict__ Akm,
    const uint16_t* __restrict__ Akl,
    const uint16_t* __restrict__ Bqh, const uint16_t* __restrict__ Bqm,
    const uint16_t* __restrict__ Bql,
    const uint16_t* __restrict__ Bkh, const uint16_t* __restrict__ Bkm,
    const uint16_t* __restrict__ Bkl,
    const float* __restrict__ bq, const float* __restrict__ bk,
    float* __restrict__ Qo, float* __restrict__ Ko)
{
  const uint16_t *Ah, *Am, *Al, *Bh, *Bm, *Bl;
  const float* bias; float* C;
  if (blockIdx.z == 0) {
    Ah = Aqh; Am = Aqm; Al = Aql; Bh = Bqh; Bm = Bqm; Bl = Bql;
    bias = bq; C = Qo;
  } else {
    Ah = Akh; Am = Akm; Al = Akl; Bh = Bkh; Bm = Bkm; Bl = Bkl;
    bias = bk; C = Ko;
  }

  const int wid = threadIdx.x >> 6, lane = threadIdx.x & 63;
  const int m0 = (blockIdx.x * 4 + wid) * 32;
  const int n0 = blockIdx.y * 64;
  const int l15 = lane & 15, quad = lane >> 4;

  const long sa0 = (long)(m0 + l15) * E_ + quad * 8;
  const long sa1 = sa0 + 16L * E_;
  long boff[4];
#pragma unroll
  for (int j = 0; j < 4; j++) boff[j] = (long)(n0 + j * 16 + l15) * E_ + quad * 8;

  v4f acc[2][4] = {};
  for (int k0 = 0; k0 < E_; k0 += 32) {
    const v8s ah0 = *(const v8s*)(Ah + sa0 + k0);
    const v8s am0 = *(const v8s*)(Am + sa0 + k0);
    const v8s al0 = *(const v8s*)(Al + sa0 + k0);
    const v8s ah1 = *(const v8s*)(Ah + sa1 + k0);
    const v8s am1 = *(const v8s*)(Am + sa1 + k0);
    const v8s al1 = *(const v8s*)(Al + sa1 + k0);
    v8s bh[4], bm[4], bl[4];
#pragma unroll
    for (int j = 0; j < 4; j++) {
      bh[j] = *(const v8s*)(Bh + boff[j] + k0);
      bm[j] = *(const v8s*)(Bm + boff[j] + k0);
      bl[j] = *(const v8s*)(Bl + boff[j] + k0);
    }
    // 8 product terms, magnitude-descending: hh; hm; mh; mm; hl; lh; ml; lm
#pragma unroll
    for (int j = 0; j < 4; j++) {
      acc[0][j] = __builtin_amdgcn_mfma_f32_16x16x32_bf16(ah0, bh[j], acc[0][j], 0, 0, 0);
      acc[1][j] = __builtin_amdgcn_mfma_f32_16x16x32_bf16(ah1, bh[j], acc[1][j], 0, 0, 0);
    }
#pragma unroll
    for (int j = 0; j < 4; j++) {
      acc[0][j] = __builtin_amdgcn_mfma_f32_16x16x32_bf16(ah0, bm[j], acc[0][j], 0, 0, 0);
      acc[1][j] = __builtin_amdgcn_mfma_f32_16x16x32_bf16(ah1, bm[j], acc[1][j], 0, 0, 0);
    }
#pragma unroll
    for (int j = 0; j < 4; j++) {
      acc[0][j] = __builtin_amdgcn_mfma_f32_16x16x32_bf16(am0, bh[j], acc[0][j], 0, 0, 0);
      acc[1][j] = __builtin_amdgcn_mfma_f32_16x16x32_bf16(am1, bh[j], acc[1][j], 0, 0, 0);
    }
#pragma unroll
    for (int j = 0; j < 4; j++) {
      acc[0][j] = __builtin_amdgcn_mfma_f32_16x16x32_bf16(am0, bm[j], acc[0][j], 0, 0, 0);
      acc[1][j] = __builtin_amdgcn_mfma_f32_16x16x32_bf16(am1, bm[j], acc[1][j], 0, 0, 0);
    }
#pragma unroll
    for (int j = 0; j < 4; j++) {
      acc[0][j] = __builtin_amdgcn_mfma_f32_16x16x32_bf16(ah0, bl[j], acc[0][j], 0, 0, 0);
      acc[1][j] = __builtin_amdgcn_mfma_f32_16x16x32_bf16(ah1, bl[j], acc[1][j], 0, 0, 0);
    }
#pragma unroll
    for (int j = 0; j < 4; j++) {
      acc[0][j] = __builtin_amdgcn_mfma_f32_16x16x32_bf16(al0, bh[j], acc[0][j], 0, 0, 0);
      acc[1][j] = __builtin_amdgcn_mfma_f32_16x16x32_bf16(al1, bh[j], acc[1][j], 0, 0, 0);
    }
#pragma unroll
    for (int j = 0; j < 4; j++) {
      acc[0][j] = __builtin_amdgcn_mfma_f32_16x16x32_bf16(am0, bl[j], acc[0][j], 0, 0, 0);
      acc[1][j] = __builtin_amdgcn_mfma_f32_16x16x32_bf16(am1, bl[j], acc[1][j], 0, 0, 0);
    }
#pragma unroll
    for (int j = 0; j < 4; j++) {
      acc[0][j] = __builtin_amdgcn_mfma_f32_16x16x32_bf16(al0, bm[j], acc[0][j], 0, 0, 0);
      acc[1][j] = __builtin_amdgcn_mfma_f32_16x16x32_bf16(al1, bm[j], acc[1][j], 0, 0, 0);
    }
  }

#pragma unroll
  for (int i = 0; i < 2; i++)
#pragma unroll
    for (int j = 0; j < 4; j++) {
      const int colg = n0 + j * 16 + l15;
      const float bb = bias[colg];
#pragma unroll
      for (int r = 0; r < 4; r++) {
        const int mm = m0 + i * 16 + quad * 4 + r;
        C[(long)mm * E_ + colg] = acc[i][j][r] + bb;
      }
    }
}

// ---------------------------------------------------------------------------
// bf16 MFMA GEMM, A fp32 converted in-register, 2x4 tiles/wave (32x64).
// grid (M/128, E/64) = 256 blocks (1/CU). r11 measured-best body. Unchanged.
// ---------------------------------------------------------------------------
__global__ __launch_bounds__(256) void mfma_gemm(
    const float* __restrict__ A,
    const uint16_t* __restrict__ Bh, const uint16_t* __restrict__ Bl,
    const float* __restrict__ bias, float* __restrict__ C,
    int gatherA, int permC)
{
  const int wid = threadIdx.x >> 6, lane = threadIdx.x & 63;
  const int m0 = (blockIdx.x * 4 + wid) * 32;
  const int n0 = blockIdx.y * 64;
  const int l15 = lane & 15, quad = lane >> 4;

  const int ra0 = m0 + l15, ra1 = m0 + 16 + l15;
  const long sa0 = (gatherA ? ((long)(ra0 & 1) * T_ + (ra0 >> 1)) : (long)ra0) * E_ + quad * 8;
  const long sa1 = (gatherA ? ((long)(ra1 & 1) * T_ + (ra1 >> 1)) : (long)ra1) * E_ + quad * 8;
  long boff[4];
#pragma unroll
  for (int j = 0; j < 4; j++) boff[j] = (long)(n0 + j * 16 + l15) * E_ + quad * 8;

  v4f acc[2][4] = {};
  for (int k0 = 0; k0 < E_; k0 += 32) {
    v8s ah0, al0, ah1, al1;
    split8(*(const float4*)(A + sa0 + k0), *(const float4*)(A + sa0 + k0 + 4),
           ah0, al0);
    split8(*(const float4*)(A + sa1 + k0), *(const float4*)(A + sa1 + k0 + 4),
           ah1, al1);
    v8s bh[4], bl[4];
#pragma unroll
    for (int j = 0; j < 4; j++) {
      bh[j] = *(const v8s*)(Bh + boff[j] + k0);
      bl[j] = *(const v8s*)(Bl + boff[j] + k0);
    }
#pragma unroll
    for (int j = 0; j < 4; j++) {
      acc[0][j] = __builtin_amdgcn_mfma_f32_16x16x32_bf16(ah0, bh[j], acc[0][j], 0, 0, 0);
      acc[1][j] = __builtin_amdgcn_mfma_f32_16x16x32_bf16(ah1, bh[j], acc[1][j], 0, 0, 0);
    }
#pragma unroll
    for (int j = 0; j < 4; j++) {
      acc[0][j] = __builtin_amdgcn_mfma_f32_16x16x32_bf16(ah0, bl[j], acc[0][j], 0, 0, 0);
      acc[1][j] = __builtin_amdgcn_mfma_f32_16x16x32_bf16(ah1, bl[j], acc[1][j], 0, 0, 0);
    }
#pragma unroll
    for (int j = 0; j < 4; j++) {
      acc[0][j] = __builtin_amdgcn_mfma_f32_16x16x32_bf16(al0, bh[j], acc[0][j], 0, 0, 0);
      acc[1][j] = __builtin_amdgcn_mfma_f32_16x16x32_bf16(al1, bh[j], acc[1][j], 0, 0, 0);
    }
  }

#pragma unroll
  for (int i = 0; i < 2; i++)
#pragma unroll
    for (int j = 0; j < 4; j++) {
      const int colg = n0 + j * 16 + l15;
      const float bb = bias[colg];
#pragma unroll
      for (int r = 0; r < 4; r++) {
        const int mm = m0 + i * 16 + quad * 4 + r;
        const int crow = permC ? ((mm & (T_ - 1)) * B_ + (mm >> 11)) : mm;
        C[(long)crow * E_ + colg] = acc[i][j][r] + bb;
      }
    }
}

// ---------------------------------------------------------------------------
// LSH hash: W[r] staged in LDS, 2-j unroll, 4-way split partials, inline
// histogram (cnt pre-zeroed by prep). First-index argmax preserved. Unchanged.
// ---------------------------------------------------------------------------
__global__ __launch_bounds__(128) void hash_kernel(
    const float* __restrict__ Q, const float* __restrict__ K,
    const float* __restrict__ lshW, const float* __restrict__ lshb,
    int* __restrict__ qh, int* __restrict__ kh,
    int* __restrict__ qcnt, int* __restrict__ kcnt)
{
  __shared__ __align__(16) float xs[128 * 68];
  __shared__ __align__(16) float ws[64 * 64];
  const int tid = threadIdx.x;
  const int tau0 = blockIdx.x * 128;
  const int src = tau0 >> 16;
  const int r = (tau0 >> 15) & 1;
  const int rowbase = tau0 & 32767;
  const float* X = src ? K : Q;
  int* outh = src ? kh : qh;
  int* cnt = src ? kcnt : qcnt;

  const float4* g = (const float4*)(X + (long)rowbase * 64);
#pragma unroll
  for (int it = 0; it < 16; it++) {
    const int gidx = it * 128 + tid;
    const int row = gidx >> 4, c4 = gidx & 15;
    *(float4*)&xs[row * 68 + c4 * 4] = g[gidx];
  }
  const float4* wg = (const float4*)(lshW + (long)r * DH_ * DH_);
#pragma unroll
  for (int it = 0; it < 8; it++) {
    const int fidx = it * 128 + tid;
    ((float4*)ws)[fidx] = wg[fidx];
  }
  __syncthreads();

  float4 x[16];
#pragma unroll
  for (int i = 0; i < 16; i++) x[i] = *(const float4*)&xs[tid * 68 + i * 4];

  const float* bb = lshb + r * DH_;

  float best = -INFINITY; int bi = 0;
  for (int j = 0; j < 64; j += 2) {
    const float4* w0 = (const float4*)&ws[j * 64];
    const float4* w1 = (const float4*)&ws[(j + 1) * 64];
    float p0 = 0.f, p1 = 0.f, p2 = 0.f, p3 = 0.f;
    float q0 = 0.f, q1 = 0.f, q2 = 0.f, q3 = 0.f;
#pragma unroll
    for (int d = 0; d < 16; d++) {
      const float4 a = w0[d];
      const float4 c = w1[d];
      p0 += x[d].x * a.x; p1 += x[d].y * a.y;
      p2 += x[d].z * a.z; p3 += x[d].w * a.w;
      q0 += x[d].x * c.x; q1 += x[d].y * c.y;
      q2 += x[d].z * c.z; q3 += x[d].w * c.w;
    }
    const float s0 = ((p0 + p1) + (p2 + p3)) + bb[j];
    const float s1 = ((q0 + q1) + (q2 + q3)) + bb[j + 1];
    if (s0 > best) { best = s0; bi = j; }
    if (s1 > best) { best = s1; bi = j + 1; }
  }

  const int rowidx = rowbase + tid;
  const int p = rowidx >> 3, h = rowidx & 7;
  const int b = p >> 11, t = p & (T_ - 1);
  const int seg = (r * 16) + b * H_ + h;
  outh[seg * T_ + t] = bi;
  if (bi < NBUCKET) atomicAdd(&cnt[seg * NBUCKET + bi], 1);
}

// ---------------------------------------------------------------------------
// Scan (+16-query task emission); fused k/q scatter. Unchanged.
// ---------------------------------------------------------------------------
__global__ void scan_kernel(const int* __restrict__ kcnt, int* __restrict__ koff,
                            int* __restrict__ kcur,
                            const int* __restrict__ qcnt, int* __restrict__ qoff,
                            int* __restrict__ qcur,
                            int* __restrict__ ntasks, int* __restrict__ tasks)
{
  const int t = threadIdx.x;
  const int seg = t & 31;
  const int* cnt = (t < 32) ? kcnt : qcnt;
  int* off = (t < 32) ? koff : qoff;
  int* cur = (t < 32) ? kcur : qcur;
  int run = 0;
  for (int b = 0; b < NBUCKET; b++) {
    off[seg * (NBUCKET + 1) + b] = run;
    cur[seg * NBUCKET + b] = run;
    run += cnt[seg * NBUCKET + b];
  }
  off[seg * (NBUCKET + 1) + NBUCKET] = run;

  if (t >= 32) {
    for (int b = 0; b < NBUCKET; b++) {
      const int nq = cnt[seg * NBUCKET + b];
      if (nq > 0) {
        const int nt = (nq + 15) >> 4;
        const int base = atomicAdd(ntasks, nt);
        for (int i = 0; i < nt; i++)
          tasks[base + i] = (seg << 16) | (b << 8) | i;
      }
    }
  }
}

__global__ __launch_bounds__(256) void scatter2_kernel(
    const int* __restrict__ kh, const int* __restrict__ qh,
    int* __restrict__ kcur, int* __restrict__ qcur,
    int* __restrict__ klist, int* __restrict__ qlist)
{
  const int idx = blockIdx.x * 256 + threadIdx.x;
  const int y = blockIdx.y;
  const int* hsh = y ? qh : kh;
  int* cur = y ? qcur : kcur;
  int* list = y ? qlist : klist;
  const int v = hsh[idx];
  if (v < NBUCKET) {
    const int seg = idx >> 11;
    const int pos = atomicAdd(&cur[seg * NBUCKET + v], 1);
    list[seg * T_ + pos] = idx & (T_ - 1);
  }
}

// ---------------------------------------------------------------------------
// Task-parallel dense bucket attention (unchanged — proven).
// ---------------------------------------------------------------------------
__global__ __launch_bounds__(256) void attn_task(
    const float* __restrict__ Q, const float* __restrict__ K,
    const float* __restrict__ V,
    const int* __restrict__ qlist, const int* __restrict__ qoff,
    const int* __restrict__ klist, const int* __restrict__ koff,
    const int* __restrict__ tasks, const int* __restrict__ ntasks,
    float* __restrict__ attn)
{
  __shared__ __align__(16) float QPs[16 * 68];
  __shared__ __align__(16) float Ks[64 * 68];
  __shared__ __align__(16) float Vs[64 * 68];

  if ((int)blockIdx.x >= *ntasks) return;
  const int tk = tasks[blockIdx.x];
  const int seg = tk >> 16, bucket = (tk >> 8) & 255, qt = tk & 255;
  const int ctx = seg & 15;
  const int b = ctx >> 3, h = ctx & 7;

  const int qlo = qoff[seg * (NBUCKET + 1) + bucket] + qt * 16;
  const int nqt = min(16, qoff[seg * (NBUCKET + 1) + bucket + 1] - qlo);
  const int klo = koff[seg * (NBUCKET + 1) + bucket];
  const int nk  = koff[seg * (NBUCKET + 1) + bucket + 1] - klo;
  if (nk == 0) return;

  const int tid = threadIdx.x;
  const int qrow = tid >> 4, col = tid & 15;
  const float* Qb = Q + ((long)b * T_) * E_ + h * DH_;
  const float* Kb = K + ((long)b * T_) * E_ + h * DH_;
  const float* Vb = V + ((long)b * T_) * E_ + h * DH_;
  const int* ql = qlist + seg * T_;
  const int* kl = klist + seg * T_;

  {
    float4 v = make_float4(0.f, 0.f, 0.f, 0.f);
    if (qrow < nqt) v = *(const float4*)(Qb + (long)ql[qlo + qrow] * E_ + col * 4);
    *(float4*)&QPs[qrow * 68 + col * 4] = v;
  }
  __syncthreads();
  float4 qreg[16];
#pragma unroll
  for (int i = 0; i < 16; i++) qreg[i] = *(const float4*)&QPs[qrow * 68 + i * 4];

  float l = 0.f;
  float4 o = make_float4(0.f, 0.f, 0.f, 0.f);

  for (int kt = 0; kt < nk; kt += 64) {
    const int nkt = min(64, nk - kt);
    __syncthreads();
#pragma unroll
    for (int it = 0; it < 4; it++) {
      const int fidx = it * 256 + tid;
      const int row = fidx >> 4, c4 = fidx & 15;
      if (row < nkt) {
        const long src = (long)kl[klo + kt + row] * E_ + c4 * 4;
        *(float4*)&Ks[row * 68 + c4 * 4] = *(const float4*)(Kb + src);
        *(float4*)&Vs[row * 68 + c4 * 4] = *(const float4*)(Vb + src);
      } else {
        *(float4*)&Vs[row * 68 + c4 * 4] = make_float4(0.f, 0.f, 0.f, 0.f);
      }
    }
    __syncthreads();
#pragma unroll
    for (int kk = 0; kk < 4; kk++) {
      const int k = kk * 16 + col;
      float p = 0.f;
      if (k < nkt) {
        const float* kp = &Ks[k * 68];
        float s = 0.f;
#pragma unroll
        for (int d4 = 0; d4 < 16; d4++) {
          const float4 c = *(const float4*)(kp + d4 * 4);
          s += qreg[d4].x * c.x + qreg[d4].y * c.y +
               qreg[d4].z * c.z + qreg[d4].w * c.w;
        }
        p = __expf(s * 0.125f);
      }
      QPs[qrow * 68 + k] = p;
    }
    __syncthreads();
    const int nk4 = (nkt + 3) >> 2;
#pragma unroll 2
    for (int k4 = 0; k4 < nk4; k4++) {
      const float4 pk = *(const float4*)&QPs[qrow * 68 + k4 * 4];
      const float4 v0 = *(const float4*)&Vs[(k4 * 4 + 0) * 68 + col * 4];
      const float4 v1 = *(const float4*)&Vs[(k4 * 4 + 1) * 68 + col * 4];
      const float4 v2 = *(const float4*)&Vs[(k4 * 4 + 2) * 68 + col * 4];
      const float4 v3 = *(const float4*)&Vs[(k4 * 4 + 3) * 68 + col * 4];
      l += (pk.x + pk.y) + (pk.z + pk.w);
      o.x += pk.x * v0.x + pk.y * v1.x + pk.z * v2.x + pk.w * v3.x;
      o.y += pk.x * v0.y + pk.y * v1.y + pk.z * v2.y + pk.w * v3.y;
      o.z += pk.x * v0.z + pk.y * v1.z + pk.z * v2.z + pk.w * v3.z;
      o.w += pk.x * v0.w + pk.y * v1.w + pk.z * v2.w + pk.w * v3.w;
    }
  }

  if (qrow < nqt) {
    const float inv = 0.5f / l;
    const int t = ql[qlo + qrow];
    float* op = attn + ((long)b * T_ + t) * E_ + h * DH_ + col * 4;
    atomicAdd(op + 0, o.x * inv);
    atomicAdd(op + 1, o.y * inv);
    atomicAdd(op + 2, o.z * inv);
    atomicAdd(op + 3, o.w * inv);
  }
}

// ---------------------------------------------------------------------------
extern "C" void kernel_launch(void* const* d_in, const int* in_sizes, int n_in,
                              void* d_out, int out_size, void* d_ws, size_t ws_size,
                              hipStream_t stream) {
  const float* query = (const float*)d_in[0];
  const float* key   = (const float*)d_in[1];
  const float* value = (const float*)d_in[2];
  const float* Wq = (const float*)d_in[3];
  const float* bq = (const float*)d_in[4];
  const float* Wk = (const float*)d_in[5];
  const float* bk = (const float*)d_in[6];
  const float* Wv = (const float*)d_in[7];
  const float* bv = (const float*)d_in[8];
  const float* Wo = (const float*)d_in[9];
  const float* bo = (const float*)d_in[10];
  const float* lshW = (const float*)d_in[11];
  const float* lshb = (const float*)d_in[12];

  const size_t MSZ = (size_t)M_ * E_;
  float* Q    = (float*)d_ws;
  float* K    = Q + MSZ;
  float* V    = K + MSZ;
  float* attn = V + MSZ;
  int* qh     = (int*)(attn + MSZ);
  int* kh     = qh + NSEG * T_;
  int* klist  = kh + NSEG * T_;
  int* qlist  = klist + NSEG * T_;
  int* kcnt   = qlist + NSEG * T_;       // start of zeroed region
  int* qcnt   = kcnt + NSEG * NBUCKET;
  int* ntasks = qcnt + NSEG * NBUCKET;   // end of zeroed region
  int* kcur   = ntasks + 1;
  int* qcur   = kcur + NSEG * NBUCKET;
  int* koff   = qcur + NSEG * NBUCKET;
  int* qoff   = koff + NSEG * (NBUCKET + 1);
  int* tasks  = qoff + NSEG * (NBUCKET + 1);
  uint16_t* Wvh = (uint16_t*)(((uintptr_t)(tasks + MAXTASK) + 15) & ~(uintptr_t)15);
  uint16_t* Wvl = Wvh + (size_t)E_ * E_;
  uint16_t* Woh = Wvl + (size_t)E_ * E_;
  uint16_t* Wol = Woh + (size_t)E_ * E_;
  uint16_t* Wqh = Wol + (size_t)E_ * E_;
  uint16_t* Wqm = Wqh + (size_t)E_ * E_;
  uint16_t* Wql = Wqm + (size_t)E_ * E_;
  uint16_t* Wkh = Wql + (size_t)E_ * E_;
  uint16_t* Wkm = Wkh + (size_t)E_ * E_;
  uint16_t* Wkl = Wkm + (size_t)E_ * E_;
  uint16_t* Xqh = Wkl + (size_t)E_ * E_;
  uint16_t* Xqm = Xqh + MSZ;
  uint16_t* Xql = Xqm + MSZ;
  uint16_t* Xkh = Xql + MSZ;
  uint16_t* Xkm = Xkh + MSZ;
  uint16_t* Xkl = Xkm + MSZ;

  prep_kernel<<<dim3(3585), 256, 0, stream>>>(
      query, key, Wq, Wk, Wv, Wo,
      Xqh, Xqm, Xql, Xkh, Xkm, Xkl,
      Wqh, Wqm, Wql, Wkh, Wkm, Wkl,
      Wvh, Wvl, Woh, Wol, attn, kcnt);
  qk_mfma<<<dim3(M_ / 128, E_ / 64, 2), 256, 0, stream>>>(
      Xqh, Xqm, Xql, Xkh, Xkm, Xkl,
      Wqh, Wqm, Wql, Wkh, Wkm, Wkl, bq, bk, Q, K);
  mfma_gemm<<<dim3(M_ / 128, E_ / 64), 256, 0, stream>>>(
      value, Wvh, Wvl, bv, V, 1, 0);
  hash_kernel<<<dim3(1024), 128, 0, stream>>>(
      Q, K, lshW, lshb, qh, kh, qcnt, kcnt);
  scan_kernel<<<dim3(1), 64, 0, stream>>>(kcnt, koff, kcur, qcnt, qoff, qcur,
                                          ntasks, tasks);
  scatter2_kernel<<<dim3(NSEG * T_ / 256, 2), 256, 0, stream>>>(
      kh, qh, kcur, qcur, klist, qlist);
  attn_task<<<dim3(MAXTASK), 256, 0, stream>>>(
      Q, K, V, qlist, qoff, klist, koff, tasks, ntasks, attn);
  mfma_gemm<<<dim3(M_ / 128, E_ / 64), 256, 0, stream>>>(
      attn, Woh, Wol, bo, (float*)d_out, 0, 1);
}

// Round 2
// 359.016 us; speedup vs baseline: 1.0541x; 1.0541x over previous
//
#include <hip/hip_runtime.h>
#include <stdint.h>
#include <math.h>

// ReformerAttention on MI355X — fp32 I/O. B=2,T=2048,E=512,H=8,Dh=64,
// 2 hash rounds, buckets<32 attend.
// Projection row p = logical (b'=p>>11, t'=p&2047); gathers input row (b=p&1, t=p>>1).
//
// 8 launches:
//   prep (2-way fp16 split of query/key/Wq/Wk + hi/lo bf16 split Wv/Wo + zero attn/cnt)
//   -> qk_mfma (Q,K proj: 3-term fp16 MFMA == fp32-exact; argmax-safe)
//   -> mfma(V, gather) -> hash(+hist) -> scan(+tasks) -> scatter2
//   -> attn_task -> mfma(out, perm)
//
// Q,K precision scheme (argmax needs fp32-class exactness):
//   x = h + l/4096 with h=fp16(x) (flushed to 0 if |x|<2^-14 so no subnormal
//   enters the matrix pipe), l=fp16((x-h)*2^12) — 2-way fp16 split carries
//   ~24 mantissa bits. Products hh -> accH; h*l' + l'*h -> accX (carries 2^12);
//   C = accH + accX*2^-12. Dropped ll ~ 2^-24 -> fp32-accumulation error class
//   (the 8-term bf16 variant of this, same class, passed argmax; old fp32 tile
//   kernel also same class). 3 MFMA terms vs 8 -> 2.67x fewer MFMAs.
// qk_mfma schedule: register double-buffer (prefetch next K-step's 12 frags
//   before the 24-MFMA block). r1 counters showed 17% MfmaUtil / 10% VALU /
//   7% HBM = pure latency stall with no prefetch at 2 waves/SIMD.
// V/out proj: bf16 MFMA 16x16x32, 3-term hi/lo split, 2x4 tiles/wave (unchanged).

#define T_ 2048
#define E_ 512
#define H_ 8
#define DH_ 64
#define B_ 2
#define M_ 4096
#define NROUND 2
#define NBUCKET 32
#define NSEG 32
#define MAXTASK 5120

typedef short v8s __attribute__((ext_vector_type(8)));
typedef _Float16 v8h __attribute__((ext_vector_type(8)));
typedef float v4f __attribute__((ext_vector_type(4)));

__device__ __forceinline__ float bf2f(uint16_t u) {
  union { uint32_t i; float f; } v; v.i = ((uint32_t)u) << 16; return v.f;
}
__device__ __forceinline__ uint16_t f2bf(float f) {
  union { float fv; uint32_t i; } v; v.fv = f;
  uint32_t x = v.i;
  x += 0x7fffu + ((x >> 16) & 1u);   // RN-even
  return (uint16_t)(x >> 16);
}
__device__ __forceinline__ void split8(const float4 a, const float4 b,
                                       v8s& h, v8s& l) {
  const float x[8] = {a.x, a.y, a.z, a.w, b.x, b.y, b.z, b.w};
#pragma unroll
  for (int j = 0; j < 8; j++) {
    const uint16_t hh = f2bf(x[j]);
    h[j] = (short)hh;
    l[j] = (short)f2bf(x[j] - bf2f(hh));
  }
}
// 2-way fp16 split with scaled residual: x = h + l*2^-12, no fp16 subnormals
// in h (flushed to l), l normal for |residual| > 2^-26 (below that: fp32-class).
__device__ __forceinline__ void split2h8(const float4 a, const float4 b,
                                         v8h& h, v8h& l) {
  const float x[8] = {a.x, a.y, a.z, a.w, b.x, b.y, b.z, b.w};
#pragma unroll
  for (int j = 0; j < 8; j++) {
    const float xv = x[j];
    const _Float16 hh = (fabsf(xv) < 6.1035156e-5f) ? (_Float16)0.0f
                                                    : (_Float16)xv;
    const float r = xv - (float)hh;          // exact (Sterbenz / hh==0)
    h[j] = hh;
    l[j] = (_Float16)(r * 4096.0f);
  }
}

// ---------------------------------------------------------------------------
// prep: pure-bandwidth staging.
//   blocks [0,1024)    : query 2-way fp16 split, gathered into GEMM row order
//   blocks [1024,2048) : key   2-way fp16 split, gathered
//   blocks [2048,2176) : Wq fp16 split
//   blocks [2176,2304) : Wk fp16 split
//   blocks [2304,2432) : Wv bf16 hi/lo split
//   blocks [2432,2560) : Wo bf16 hi/lo split
//   blocks [2560,3584) : zero attn
//   block  3584        : zero cnt region
// ---------------------------------------------------------------------------
__global__ __launch_bounds__(256) void prep_kernel(
    const float* __restrict__ Xq, const float* __restrict__ Xk,
    const float* __restrict__ Wq, const float* __restrict__ Wk,
    const float* __restrict__ Wv, const float* __restrict__ Wo,
    uint16_t* __restrict__ Xqh, uint16_t* __restrict__ Xql,
    uint16_t* __restrict__ Xkh, uint16_t* __restrict__ Xkl,
    uint16_t* __restrict__ Wqh, uint16_t* __restrict__ Wql,
    uint16_t* __restrict__ Wkh, uint16_t* __restrict__ Wkl,
    uint16_t* __restrict__ Wvh, uint16_t* __restrict__ Wvl,
    uint16_t* __restrict__ Woh, uint16_t* __restrict__ Wol,
    float* __restrict__ attn, int* __restrict__ cnt)
{
  const int bid = blockIdx.x;
  const int tid = threadIdx.x;

  if (bid < 2048) {                      // query/key fp16 split (gathered)
    const int is_k = bid >> 10;
    const float* X = is_k ? Xk : Xq;
    uint16_t* H = is_k ? Xkh : Xqh;
    uint16_t* L = is_k ? Xkl : Xql;
    const int e = ((bid & 1023) * 256 + tid) * 8;   // [0, M_*E_)
    const int p = e >> 9, k = e & 511;
    const long src = ((long)(p & 1) * T_ + (p >> 1)) * E_ + k;
    const float4 a = *(const float4*)(X + src);
    const float4 b = *(const float4*)(X + src + 4);
    v8h h, l;
    split2h8(a, b, h, l);
    *(v8h*)(H + e) = h;
    *(v8h*)(L + e) = l;
    return;
  }

  if (bid < 2560) {                      // weight splits
    const int wsel = (bid - 2048) >> 7;  // 0=Wq,1=Wk,2=Wv,3=Wo
    const int e = (((bid - 2048) & 127) * 256 + tid) * 8;   // [0, E_*E_)
    if (wsel < 2) {
      const float* S = wsel ? Wk : Wq;
      const float4 a = *(const float4*)(S + e);
      const float4 b = *(const float4*)(S + e + 4);
      v8h h, l;
      split2h8(a, b, h, l);
      uint16_t* H = wsel ? Wkh : Wqh;
      uint16_t* L = wsel ? Wkl : Wql;
      *(v8h*)(H + e) = h;
      *(v8h*)(L + e) = l;
    } else {
      const float* S = (wsel == 2) ? Wv : Wo;
      const float4 a = *(const float4*)(S + e);
      const float4 b = *(const float4*)(S + e + 4);
      v8s h, l;
      split8(a, b, h, l);
      uint16_t* H = (wsel == 2) ? Wvh : Woh;
      uint16_t* L = (wsel == 2) ? Wvl : Wol;
      *(v8s*)(H + e) = h;
      *(v8s*)(L + e) = l;
    }
    return;
  }

  if (bid < 3584) {                      // zero attn: 1024 blocks x 512 float4
    float4* a4 = (float4*)attn;
    const int g = (bid - 2560) * 512 + tid * 2;
    a4[g] = make_float4(0.f, 0.f, 0.f, 0.f);
    a4[g + 1] = make_float4(0.f, 0.f, 0.f, 0.f);
    return;
  }

  for (int i = tid; i < 2 * NSEG * NBUCKET + 1; i += 256) cnt[i] = 0;
}

// ---------------------------------------------------------------------------
// qk_mfma: Q/K projection via 3-term fp16-split MFMA (fp32-equivalent).
// grid (M/128, E/64, 2), 256 threads, 2x4 16x16 tiles/wave. A pre-split &
// pre-gathered (linear reads); register double-buffered K-loop; C written
// fp32 in GEMM row order (= Q/K layout).
// ---------------------------------------------------------------------------
__global__ __launch_bounds__(256) void qk_mfma(
    const uint16_t* __restrict__ Aqh, const uint16_t* __restrict__ Aql,
    const uint16_t* __restrict__ Akh, const uint16_t* __restrict__ Akl,
    const uint16_t* __restrict__ Bqh, const uint16_t* __restrict__ Bql,
    const uint16_t* __restrict__ Bkh, const uint16_t* __restrict__ Bkl,
    const float* __restrict__ bq, const float* __restrict__ bk,
    float* __restrict__ Qo, float* __restrict__ Ko)
{
  const uint16_t *Ah, *Al, *Bh, *Bl;
  const float* bias; float* C;
  if (blockIdx.z == 0) { Ah = Aqh; Al = Aql; Bh = Bqh; Bl = Bql; bias = bq; C = Qo; }
  else                 { Ah = Akh; Al = Akl; Bh = Bkh; Bl = Bkl; bias = bk; C = Ko; }

  const int wid = threadIdx.x >> 6, lane = threadIdx.x & 63;
  const int m0 = (blockIdx.x * 4 + wid) * 32;
  const int n0 = blockIdx.y * 64;
  const int l15 = lane & 15, quad = lane >> 4;

  const long sa0 = (long)(m0 + l15) * E_ + quad * 8;
  const long sa1 = sa0 + 16L * E_;
  long boff[4];
#pragma unroll
  for (int j = 0; j < 4; j++) boff[j] = (long)(n0 + j * 16 + l15) * E_ + quad * 8;

  v4f accH[2][4] = {};
  v4f accX[2][4] = {};

  // prologue: load K-step 0
  v8h ah0 = *(const v8h*)(Ah + sa0);
  v8h al0 = *(const v8h*)(Al + sa0);
  v8h ah1 = *(const v8h*)(Ah + sa1);
  v8h al1 = *(const v8h*)(Al + sa1);
  v8h bh[4], bl[4];
#pragma unroll
  for (int j = 0; j < 4; j++) {
    bh[j] = *(const v8h*)(Bh + boff[j]);
    bl[j] = *(const v8h*)(Bl + boff[j]);
  }

  for (int k0 = 0; k0 < E_; k0 += 32) {
    // prefetch next K-step (wraps to 0 on last iter; values unused)
    const int kn = (k0 + 32) & (E_ - 1);
    const v8h nah0 = *(const v8h*)(Ah + sa0 + kn);
    const v8h nal0 = *(const v8h*)(Al + sa0 + kn);
    const v8h nah1 = *(const v8h*)(Ah + sa1 + kn);
    const v8h nal1 = *(const v8h*)(Al + sa1 + kn);
    v8h nbh[4], nbl[4];
#pragma unroll
    for (int j = 0; j < 4; j++) {
      nbh[j] = *(const v8h*)(Bh + boff[j] + kn);
      nbl[j] = *(const v8h*)(Bl + boff[j] + kn);
    }

    // 24 MFMAs: hh -> accH; h*l' and l'*h -> accX (carries 2^12 scale)
#pragma unroll
    for (int j = 0; j < 4; j++) {
      accH[0][j] = __builtin_amdgcn_mfma_f32_16x16x32_f16(ah0, bh[j], accH[0][j], 0, 0, 0);
      accH[1][j] = __builtin_amdgcn_mfma_f32_16x16x32_f16(ah1, bh[j], accH[1][j], 0, 0, 0);
    }
#pragma unroll
    for (int j = 0; j < 4; j++) {
      accX[0][j] = __builtin_amdgcn_mfma_f32_16x16x32_f16(ah0, bl[j], accX[0][j], 0, 0, 0);
      accX[1][j] = __builtin_amdgcn_mfma_f32_16x16x32_f16(ah1, bl[j], accX[1][j], 0, 0, 0);
    }
#pragma unroll
    for (int j = 0; j < 4; j++) {
      accX[0][j] = __builtin_amdgcn_mfma_f32_16x16x32_f16(al0, bh[j], accX[0][j], 0, 0, 0);
      accX[1][j] = __builtin_amdgcn_mfma_f32_16x16x32_f16(al1, bh[j], accX[1][j], 0, 0, 0);
    }

    // rotate
    ah0 = nah0; al0 = nal0; ah1 = nah1; al1 = nal1;
#pragma unroll
    for (int j = 0; j < 4; j++) { bh[j] = nbh[j]; bl[j] = nbl[j]; }
  }

#pragma unroll
  for (int i = 0; i < 2; i++)
#pragma unroll
    for (int j = 0; j < 4; j++) {
      const int colg = n0 + j * 16 + l15;
      const float bb = bias[colg];
#pragma unroll
      for (int r = 0; r < 4; r++) {
        const int mm = m0 + i * 16 + quad * 4 + r;
        C[(long)mm * E_ + colg] =
            accH[i][j][r] + accX[i][j][r] * (1.0f / 4096.0f) + bb;
      }
    }
}

// ---------------------------------------------------------------------------
// bf16 MFMA GEMM, A fp32 converted in-register, 2x4 tiles/wave (32x64).
// grid (M/128, E/64) = 256 blocks (1/CU). r11 measured-best body. Unchanged.
// ---------------------------------------------------------------------------
__global__ __launch_bounds__(256) void mfma_gemm(
    const float* __restrict__ A,
    const uint16_t* __restrict__ Bh, const uint16_t* __restrict__ Bl,
    const float* __restrict__ bias, float* __restrict__ C,
    int gatherA, int permC)
{
  const int wid = threadIdx.x >> 6, lane = threadIdx.x & 63;
  const int m0 = (blockIdx.x * 4 + wid) * 32;
  const int n0 = blockIdx.y * 64;
  const int l15 = lane & 15, quad = lane >> 4;

  const int ra0 = m0 + l15, ra1 = m0 + 16 + l15;
  const long sa0 = (gatherA ? ((long)(ra0 & 1) * T_ + (ra0 >> 1)) : (long)ra0) * E_ + quad * 8;
  const long sa1 = (gatherA ? ((long)(ra1 & 1) * T_ + (ra1 >> 1)) : (long)ra1) * E_ + quad * 8;
  long boff[4];
#pragma unroll
  for (int j = 0; j < 4; j++) boff[j] = (long)(n0 + j * 16 + l15) * E_ + quad * 8;

  v4f acc[2][4] = {};
  for (int k0 = 0; k0 < E_; k0 += 32) {
    v8s ah0, al0, ah1, al1;
    split8(*(const float4*)(A + sa0 + k0), *(const float4*)(A + sa0 + k0 + 4),
           ah0, al0);
    split8(*(const float4*)(A + sa1 + k0), *(const float4*)(A + sa1 + k0 + 4),
           ah1, al1);
    v8s bh[4], bl[4];
#pragma unroll
    for (int j = 0; j < 4; j++) {
      bh[j] = *(const v8s*)(Bh + boff[j] + k0);
      bl[j] = *(const v8s*)(Bl + boff[j] + k0);
    }
#pragma unroll
    for (int j = 0; j < 4; j++) {
      acc[0][j] = __builtin_amdgcn_mfma_f32_16x16x32_bf16(ah0, bh[j], acc[0][j], 0, 0, 0);
      acc[1][j] = __builtin_amdgcn_mfma_f32_16x16x32_bf16(ah1, bh[j], acc[1][j], 0, 0, 0);
    }
#pragma unroll
    for (int j = 0; j < 4; j++) {
      acc[0][j] = __builtin_amdgcn_mfma_f32_16x16x32_bf16(ah0, bl[j], acc[0][j], 0, 0, 0);
      acc[1][j] = __builtin_amdgcn_mfma_f32_16x16x32_bf16(ah1, bl[j], acc[1][j], 0, 0, 0);
    }
#pragma unroll
    for (int j = 0; j < 4; j++) {
      acc[0][j] = __builtin_amdgcn_mfma_f32_16x16x32_bf16(al0, bh[j], acc[0][j], 0, 0, 0);
      acc[1][j] = __builtin_amdgcn_mfma_f32_16x16x32_bf16(al1, bh[j], acc[1][j], 0, 0, 0);
    }
  }

#pragma unroll
  for (int i = 0; i < 2; i++)
#pragma unroll
    for (int j = 0; j < 4; j++) {
      const int colg = n0 + j * 16 + l15;
      const float bb = bias[colg];
#pragma unroll
      for (int r = 0; r < 4; r++) {
        const int mm = m0 + i * 16 + quad * 4 + r;
        const int crow = permC ? ((mm & (T_ - 1)) * B_ + (mm >> 11)) : mm;
        C[(long)crow * E_ + colg] = acc[i][j][r] + bb;
      }
    }
}

// ---------------------------------------------------------------------------
// LSH hash: W[r] staged in LDS, 2-j unroll, 4-way split partials, inline
// histogram (cnt pre-zeroed by prep). First-index argmax preserved. Unchanged.
// ---------------------------------------------------------------------------
__global__ __launch_bounds__(128) void hash_kernel(
    const float* __restrict__ Q, const float* __restrict__ K,
    const float* __restrict__ lshW, const float* __restrict__ lshb,
    int* __restrict__ qh, int* __restrict__ kh,
    int* __restrict__ qcnt, int* __restrict__ kcnt)
{
  __shared__ __align__(16) float xs[128 * 68];
  __shared__ __align__(16) float ws[64 * 64];
  const int tid = threadIdx.x;
  const int tau0 = blockIdx.x * 128;
  const int src = tau0 >> 16;
  const int r = (tau0 >> 15) & 1;
  const int rowbase = tau0 & 32767;
  const float* X = src ? K : Q;
  int* outh = src ? kh : qh;
  int* cnt = src ? kcnt : qcnt;

  const float4* g = (const float4*)(X + (long)rowbase * 64);
#pragma unroll
  for (int it = 0; it < 16; it++) {
    const int gidx = it * 128 + tid;
    const int row = gidx >> 4, c4 = gidx & 15;
    *(float4*)&xs[row * 68 + c4 * 4] = g[gidx];
  }
  const float4* wg = (const float4*)(lshW + (long)r * DH_ * DH_);
#pragma unroll
  for (int it = 0; it < 8; it++) {
    const int fidx = it * 128 + tid;
    ((float4*)ws)[fidx] = wg[fidx];
  }
  __syncthreads();

  float4 x[16];
#pragma unroll
  for (int i = 0; i < 16; i++) x[i] = *(const float4*)&xs[tid * 68 + i * 4];

  const float* bb = lshb + r * DH_;

  float best = -INFINITY; int bi = 0;
  for (int j = 0; j < 64; j += 2) {
    const float4* w0 = (const float4*)&ws[j * 64];
    const float4* w1 = (const float4*)&ws[(j + 1) * 64];
    float p0 = 0.f, p1 = 0.f, p2 = 0.f, p3 = 0.f;
    float q0 = 0.f, q1 = 0.f, q2 = 0.f, q3 = 0.f;
#pragma unroll
    for (int d = 0; d < 16; d++) {
      const float4 a = w0[d];
      const float4 c = w1[d];
      p0 += x[d].x * a.x; p1 += x[d].y * a.y;
      p2 += x[d].z * a.z; p3 += x[d].w * a.w;
      q0 += x[d].x * c.x; q1 += x[d].y * c.y;
      q2 += x[d].z * c.z; q3 += x[d].w * c.w;
    }
    const float s0 = ((p0 + p1) + (p2 + p3)) + bb[j];
    const float s1 = ((q0 + q1) + (q2 + q3)) + bb[j + 1];
    if (s0 > best) { best = s0; bi = j; }
    if (s1 > best) { best = s1; bi = j + 1; }
  }

  const int rowidx = rowbase + tid;
  const int p = rowidx >> 3, h = rowidx & 7;
  const int b = p >> 11, t = p & (T_ - 1);
  const int seg = (r * 16) + b * H_ + h;
  outh[seg * T_ + t] = bi;
  if (bi < NBUCKET) atomicAdd(&cnt[seg * NBUCKET + bi], 1);
}

// ---------------------------------------------------------------------------
// Scan (+16-query task emission); fused k/q scatter. Unchanged.
// ---------------------------------------------------------------------------
__global__ void scan_kernel(const int* __restrict__ kcnt, int* __restrict__ koff,
                            int* __restrict__ kcur,
                            const int* __restrict__ qcnt, int* __restrict__ qoff,
                            int* __restrict__ qcur,
                            int* __restrict__ ntasks, int* __restrict__ tasks)
{
  const int t = threadIdx.x;
  const int seg = t & 31;
  const int* cnt = (t < 32) ? kcnt : qcnt;
  int* off = (t < 32) ? koff : qoff;
  int* cur = (t < 32) ? kcur : qcur;
  int run = 0;
  for (int b = 0; b < NBUCKET; b++) {
    off[seg * (NBUCKET + 1) + b] = run;
    cur[seg * NBUCKET + b] = run;
    run += cnt[seg * NBUCKET + b];
  }
  off[seg * (NBUCKET + 1) + NBUCKET] = run;

  if (t >= 32) {
    for (int b = 0; b < NBUCKET; b++) {
      const int nq = cnt[seg * NBUCKET + b];
      if (nq > 0) {
        const int nt = (nq + 15) >> 4;
        const int base = atomicAdd(ntasks, nt);
        for (int i = 0; i < nt; i++)
          tasks[base + i] = (seg << 16) | (b << 8) | i;
      }
    }
  }
}

__global__ __launch_bounds__(256) void scatter2_kernel(
    const int* __restrict__ kh, const int* __restrict__ qh,
    int* __restrict__ kcur, int* __restrict__ qcur,
    int* __restrict__ klist, int* __restrict__ qlist)
{
  const int idx = blockIdx.x * 256 + threadIdx.x;
  const int y = blockIdx.y;
  const int* hsh = y ? qh : kh;
  int* cur = y ? qcur : kcur;
  int* list = y ? qlist : klist;
  const int v = hsh[idx];
  if (v < NBUCKET) {
    const int seg = idx >> 11;
    const int pos = atomicAdd(&cur[seg * NBUCKET + v], 1);
    list[seg * T_ + pos] = idx & (T_ - 1);
  }
}

// ---------------------------------------------------------------------------
// Task-parallel dense bucket attention (unchanged — proven).
// ---------------------------------------------------------------------------
__global__ __launch_bounds__(256) void attn_task(
    const float* __restrict__ Q, const float* __restrict__ K,
    const float* __restrict__ V,
    const int* __restrict__ qlist, const int* __restrict__ qoff,
    const int* __restrict__ klist, const int* __restrict__ koff,
    const int* __restrict__ tasks, const int* __restrict__ ntasks,
    float* __restrict__ attn)
{
  __shared__ __align__(16) float QPs[16 * 68];
  __shared__ __align__(16) float Ks[64 * 68];
  __shared__ __align__(16) float Vs[64 * 68];

  if ((int)blockIdx.x >= *ntasks) return;
  const int tk = tasks[blockIdx.x];
  const int seg = tk >> 16, bucket = (tk >> 8) & 255, qt = tk & 255;
  const int ctx = seg & 15;
  const int b = ctx >> 3, h = ctx & 7;

  const int qlo = qoff[seg * (NBUCKET + 1) + bucket] + qt * 16;
  const int nqt = min(16, qoff[seg * (NBUCKET + 1) + bucket + 1] - qlo);
  const int klo = koff[seg * (NBUCKET + 1) + bucket];
  const int nk  = koff[seg * (NBUCKET + 1) + bucket + 1] - klo;
  if (nk == 0) return;

  const int tid = threadIdx.x;
  const int qrow = tid >> 4, col = tid & 15;
  const float* Qb = Q + ((long)b * T_) * E_ + h * DH_;
  const float* Kb = K + ((long)b * T_) * E_ + h * DH_;
  const float* Vb = V + ((long)b * T_) * E_ + h * DH_;
  const int* ql = qlist + seg * T_;
  const int* kl = klist + seg * T_;

  {
    float4 v = make_float4(0.f, 0.f, 0.f, 0.f);
    if (qrow < nqt) v = *(const float4*)(Qb + (long)ql[qlo + qrow] * E_ + col * 4);
    *(float4*)&QPs[qrow * 68 + col * 4] = v;
  }
  __syncthreads();
  float4 qreg[16];
#pragma unroll
  for (int i = 0; i < 16; i++) qreg[i] = *(const float4*)&QPs[qrow * 68 + i * 4];

  float l = 0.f;
  float4 o = make_float4(0.f, 0.f, 0.f, 0.f);

  for (int kt = 0; kt < nk; kt += 64) {
    const int nkt = min(64, nk - kt);
    __syncthreads();
#pragma unroll
    for (int it = 0; it < 4; it++) {
      const int fidx = it * 256 + tid;
      const int row = fidx >> 4, c4 = fidx & 15;
      if (row < nkt) {
        const long src = (long)kl[klo + kt + row] * E_ + c4 * 4;
        *(float4*)&Ks[row * 68 + c4 * 4] = *(const float4*)(Kb + src);
        *(float4*)&Vs[row * 68 + c4 * 4] = *(const float4*)(Vb + src);
      } else {
        *(float4*)&Vs[row * 68 + c4 * 4] = make_float4(0.f, 0.f, 0.f, 0.f);
      }
    }
    __syncthreads();
#pragma unroll
    for (int kk = 0; kk < 4; kk++) {
      const int k = kk * 16 + col;
      float p = 0.f;
      if (k < nkt) {
        const float* kp = &Ks[k * 68];
        float s = 0.f;
#pragma unroll
        for (int d4 = 0; d4 < 16; d4++) {
          const float4 c = *(const float4*)(kp + d4 * 4);
          s += qreg[d4].x * c.x + qreg[d4].y * c.y +
               qreg[d4].z * c.z + qreg[d4].w * c.w;
        }
        p = __expf(s * 0.125f);
      }
      QPs[qrow * 68 + k] = p;
    }
    __syncthreads();
    const int nk4 = (nkt + 3) >> 2;
#pragma unroll 2
    for (int k4 = 0; k4 < nk4; k4++) {
      const float4 pk = *(const float4*)&QPs[qrow * 68 + k4 * 4];
      const float4 v0 = *(const float4*)&Vs[(k4 * 4 + 0) * 68 + col * 4];
      const float4 v1 = *(const float4*)&Vs[(k4 * 4 + 1) * 68 + col * 4];
      const float4 v2 = *(const float4*)&Vs[(k4 * 4 + 2) * 68 + col * 4];
      const float4 v3 = *(const float4*)&Vs[(k4 * 4 + 3) * 68 + col * 4];
      l += (pk.x + pk.y) + (pk.z + pk.w);
      o.x += pk.x * v0.x + pk.y * v1.x + pk.z * v2.x + pk.w * v3.x;
      o.y += pk.x * v0.y + pk.y * v1.y + pk.z * v2.y + pk.w * v3.y;
      o.z += pk.x * v0.z + pk.y * v1.z + pk.z * v2.z + pk.w * v3.z;
      o.w += pk.x * v0.w + pk.y * v1.w + pk.z * v2.w + pk.w * v3.w;
    }
  }

  if (qrow < nqt) {
    const float inv = 0.5f / l;
    const int t = ql[qlo + qrow];
    float* op = attn + ((long)b * T_ + t) * E_ + h * DH_ + col * 4;
    atomicAdd(op + 0, o.x * inv);
    atomicAdd(op + 1, o.y * inv);
    atomicAdd(op + 2, o.z * inv);
    atomicAdd(op + 3, o.w * inv);
  }
}

// ---------------------------------------------------------------------------
extern "C" void kernel_launch(void* const* d_in, const int* in_sizes, int n_in,
                              void* d_out, int out_size, void* d_ws, size_t ws_size,
                              hipStream_t stream) {
  const float* query = (const float*)d_in[0];
  const float* key   = (const float*)d_in[1];
  const float* value = (const float*)d_in[2];
  const float* Wq = (const float*)d_in[3];
  const float* bq = (const float*)d_in[4];
  const float* Wk = (const float*)d_in[5];
  const float* bk = (const float*)d_in[6];
  const float* Wv = (const float*)d_in[7];
  const float* bv = (const float*)d_in[8];
  const float* Wo = (const float*)d_in[9];
  const float* bo = (const float*)d_in[10];
  const float* lshW = (const float*)d_in[11];
  const float* lshb = (const float*)d_in[12];

  const size_t MSZ = (size_t)M_ * E_;
  float* Q    = (float*)d_ws;
  float* K    = Q + MSZ;
  float* V    = K + MSZ;
  float* attn = V + MSZ;
  int* qh     = (int*)(attn + MSZ);
  int* kh     = qh + NSEG * T_;
  int* klist  = kh + NSEG * T_;
  int* qlist  = klist + NSEG * T_;
  int* kcnt   = qlist + NSEG * T_;       // start of zeroed region
  int* qcnt   = kcnt + NSEG * NBUCKET;
  int* ntasks = qcnt + NSEG * NBUCKET;   // end of zeroed region
  int* kcur   = ntasks + 1;
  int* qcur   = kcur + NSEG * NBUCKET;
  int* koff   = qcur + NSEG * NBUCKET;
  int* qoff   = koff + NSEG * (NBUCKET + 1);
  int* tasks  = qoff + NSEG * (NBUCKET + 1);
  uint16_t* Wvh = (uint16_t*)(((uintptr_t)(tasks + MAXTASK) + 15) & ~(uintptr_t)15);
  uint16_t* Wvl = Wvh + (size_t)E_ * E_;
  uint16_t* Woh = Wvl + (size_t)E_ * E_;
  uint16_t* Wol = Woh + (size_t)E_ * E_;
  uint16_t* Wqh = Wol + (size_t)E_ * E_;
  uint16_t* Wql = Wqh + (size_t)E_ * E_;
  uint16_t* Wkh = Wql + (size_t)E_ * E_;
  uint16_t* Wkl = Wkh + (size_t)E_ * E_;
  uint16_t* Xqh = Wkl + (size_t)E_ * E_;
  uint16_t* Xql = Xqh + MSZ;
  uint16_t* Xkh = Xql + MSZ;
  uint16_t* Xkl = Xkh + MSZ;

  prep_kernel<<<dim3(3585), 256, 0, stream>>>(
      query, key, Wq, Wk, Wv, Wo,
      Xqh, Xql, Xkh, Xkl,
      Wqh, Wql, Wkh, Wkl,
      Wvh, Wvl, Woh, Wol, attn, kcnt);
  qk_mfma<<<dim3(M_ / 128, E_ / 64, 2), 256, 0, stream>>>(
      Xqh, Xql, Xkh, Xkl,
      Wqh, Wql, Wkh, Wkl, bq, bk, Q, K);
  mfma_gemm<<<dim3(M_ / 128, E_ / 64), 256, 0, stream>>>(
      value, Wvh, Wvl, bv, V, 1, 0);
  hash_kernel<<<dim3(1024), 128, 0, stream>>>(
      Q, K, lshW, lshb, qh, kh, qcnt, kcnt);
  scan_kernel<<<dim3(1), 64, 0, stream>>>(kcnt, koff, kcur, qcnt, qoff, qcur,
                                          ntasks, tasks);
  scatter2_kernel<<<dim3(NSEG * T_ / 256, 2), 256, 0, stream>>>(
      kh, qh, kcur, qcur, klist, qlist);
  attn_task<<<dim3(MAXTASK), 256, 0, stream>>>(
      Q, K, V, qlist, qoff, klist, koff, tasks, ntasks, attn);
  mfma_gemm<<<dim3(M_ / 128, E_ / 64), 256, 0, stream>>>(
      attn, Woh, Wol, bo, (float*)d_out, 0, 1);
}

// Round 3
// 308.615 us; speedup vs baseline: 1.2262x; 1.1633x over previous
//
#include <hip/hip_runtime.h>
#include <stdint.h>
#include <math.h>

// ReformerAttention on MI355X — fp32 I/O. B=2,T=2048,E=512,H=8,Dh=64,
// 2 hash rounds, buckets<32 attend.
// Projection row p = logical (b'=p>>11, t'=p&2047); gathers input row (b=p&1, t=p>>1).
//
// 8 launches:
//   prep (2-way fp16 split of query/key/Wq/Wk + hi/lo bf16 split Wv/Wo + zero attn/cnt)
//   -> qk_mfma (Q,K proj: 3-term fp16 MFMA == fp32-exact; argmax-safe)
//   -> mfma(V, gather) -> hash(+hist) -> scan(+tasks) -> scatter2
//   -> attn_task -> mfma(out, perm)
//
// Q,K precision scheme (argmax needs fp32-class exactness):
//   x = h + l/4096 with h=fp16(x) (flushed to 0 if |x|<2^-14 so no subnormal
//   enters the matrix pipe), l=fp16((x-h)*2^12) — 2-way fp16 split carries
//   ~24 mantissa bits. Products hh -> accH; h*l' + l'*h -> accX (carries 2^12);
//   C = accH + accX*2^-12. Dropped ll ~ 2^-24 -> fp32-accumulation error class.
//   Verified passing (r2, absmax unchanged vs fp32 kernel).
// qk_mfma schedule: register double-buffer. r1 lesson: no prefetch at 2
//   waves/SIMD = latency-bound 17% MfmaUtil.
// scan: r2 counters showed 61.7us for ~35KB of traffic — 1024 same-address
//   atomicAdds from one wave serialize (~100-300cy each). v3: one thread per
//   (seg,bucket), shfl prefix scans, ONE atomicAdd per wave (16 total).
// V/out proj: bf16 MFMA 16x16x32, 3-term hi/lo split, 2x4 tiles/wave (unchanged).

#define T_ 2048
#define E_ 512
#define H_ 8
#define DH_ 64
#define B_ 2
#define M_ 4096
#define NROUND 2
#define NBUCKET 32
#define NSEG 32
#define MAXTASK 5120

typedef short v8s __attribute__((ext_vector_type(8)));
typedef _Float16 v8h __attribute__((ext_vector_type(8)));
typedef float v4f __attribute__((ext_vector_type(4)));

__device__ __forceinline__ float bf2f(uint16_t u) {
  union { uint32_t i; float f; } v; v.i = ((uint32_t)u) << 16; return v.f;
}
__device__ __forceinline__ uint16_t f2bf(float f) {
  union { float fv; uint32_t i; } v; v.fv = f;
  uint32_t x = v.i;
  x += 0x7fffu + ((x >> 16) & 1u);   // RN-even
  return (uint16_t)(x >> 16);
}
__device__ __forceinline__ void split8(const float4 a, const float4 b,
                                       v8s& h, v8s& l) {
  const float x[8] = {a.x, a.y, a.z, a.w, b.x, b.y, b.z, b.w};
#pragma unroll
  for (int j = 0; j < 8; j++) {
    const uint16_t hh = f2bf(x[j]);
    h[j] = (short)hh;
    l[j] = (short)f2bf(x[j] - bf2f(hh));
  }
}
// 2-way fp16 split with scaled residual: x = h + l*2^-12, no fp16 subnormals
// in h (flushed to l), l normal for |residual| > 2^-26 (below that: fp32-class).
__device__ __forceinline__ void split2h8(const float4 a, const float4 b,
                                         v8h& h, v8h& l) {
  const float x[8] = {a.x, a.y, a.z, a.w, b.x, b.y, b.z, b.w};
#pragma unroll
  for (int j = 0; j < 8; j++) {
    const float xv = x[j];
    const _Float16 hh = (fabsf(xv) < 6.1035156e-5f) ? (_Float16)0.0f
                                                    : (_Float16)xv;
    const float r = xv - (float)hh;          // exact (Sterbenz / hh==0)
    h[j] = hh;
    l[j] = (_Float16)(r * 4096.0f);
  }
}

// ---------------------------------------------------------------------------
// prep: pure-bandwidth staging.
//   blocks [0,1024)    : query 2-way fp16 split, gathered into GEMM row order
//   blocks [1024,2048) : key   2-way fp16 split, gathered
//   blocks [2048,2176) : Wq fp16 split
//   blocks [2176,2304) : Wk fp16 split
//   blocks [2304,2432) : Wv bf16 hi/lo split
//   blocks [2432,2560) : Wo bf16 hi/lo split
//   blocks [2560,3584) : zero attn
//   block  3584        : zero cnt region
// ---------------------------------------------------------------------------
__global__ __launch_bounds__(256) void prep_kernel(
    const float* __restrict__ Xq, const float* __restrict__ Xk,
    const float* __restrict__ Wq, const float* __restrict__ Wk,
    const float* __restrict__ Wv, const float* __restrict__ Wo,
    uint16_t* __restrict__ Xqh, uint16_t* __restrict__ Xql,
    uint16_t* __restrict__ Xkh, uint16_t* __restrict__ Xkl,
    uint16_t* __restrict__ Wqh, uint16_t* __restrict__ Wql,
    uint16_t* __restrict__ Wkh, uint16_t* __restrict__ Wkl,
    uint16_t* __restrict__ Wvh, uint16_t* __restrict__ Wvl,
    uint16_t* __restrict__ Woh, uint16_t* __restrict__ Wol,
    float* __restrict__ attn, int* __restrict__ cnt)
{
  const int bid = blockIdx.x;
  const int tid = threadIdx.x;

  if (bid < 2048) {                      // query/key fp16 split (gathered)
    const int is_k = bid >> 10;
    const float* X = is_k ? Xk : Xq;
    uint16_t* H = is_k ? Xkh : Xqh;
    uint16_t* L = is_k ? Xkl : Xql;
    const int e = ((bid & 1023) * 256 + tid) * 8;   // [0, M_*E_)
    const int p = e >> 9, k = e & 511;
    const long src = ((long)(p & 1) * T_ + (p >> 1)) * E_ + k;
    const float4 a = *(const float4*)(X + src);
    const float4 b = *(const float4*)(X + src + 4);
    v8h h, l;
    split2h8(a, b, h, l);
    *(v8h*)(H + e) = h;
    *(v8h*)(L + e) = l;
    return;
  }

  if (bid < 2560) {                      // weight splits
    const int wsel = (bid - 2048) >> 7;  // 0=Wq,1=Wk,2=Wv,3=Wo
    const int e = (((bid - 2048) & 127) * 256 + tid) * 8;   // [0, E_*E_)
    if (wsel < 2) {
      const float* S = wsel ? Wk : Wq;
      const float4 a = *(const float4*)(S + e);
      const float4 b = *(const float4*)(S + e + 4);
      v8h h, l;
      split2h8(a, b, h, l);
      uint16_t* H = wsel ? Wkh : Wqh;
      uint16_t* L = wsel ? Wkl : Wql;
      *(v8h*)(H + e) = h;
      *(v8h*)(L + e) = l;
    } else {
      const float* S = (wsel == 2) ? Wv : Wo;
      const float4 a = *(const float4*)(S + e);
      const float4 b = *(const float4*)(S + e + 4);
      v8s h, l;
      split8(a, b, h, l);
      uint16_t* H = (wsel == 2) ? Wvh : Woh;
      uint16_t* L = (wsel == 2) ? Wvl : Wol;
      *(v8s*)(H + e) = h;
      *(v8s*)(L + e) = l;
    }
    return;
  }

  if (bid < 3584) {                      // zero attn: 1024 blocks x 512 float4
    float4* a4 = (float4*)attn;
    const int g = (bid - 2560) * 512 + tid * 2;
    a4[g] = make_float4(0.f, 0.f, 0.f, 0.f);
    a4[g + 1] = make_float4(0.f, 0.f, 0.f, 0.f);
    return;
  }

  for (int i = tid; i < 2 * NSEG * NBUCKET + 1; i += 256) cnt[i] = 0;
}

// ---------------------------------------------------------------------------
// qk_mfma: Q/K projection via 3-term fp16-split MFMA (fp32-equivalent).
// grid (M/128, E/64, 2), 256 threads, 2x4 16x16 tiles/wave. A pre-split &
// pre-gathered (linear reads); register double-buffered K-loop; C written
// fp32 in GEMM row order (= Q/K layout).
// ---------------------------------------------------------------------------
__global__ __launch_bounds__(256) void qk_mfma(
    const uint16_t* __restrict__ Aqh, const uint16_t* __restrict__ Aql,
    const uint16_t* __restrict__ Akh, const uint16_t* __restrict__ Akl,
    const uint16_t* __restrict__ Bqh, const uint16_t* __restrict__ Bql,
    const uint16_t* __restrict__ Bkh, const uint16_t* __restrict__ Bkl,
    const float* __restrict__ bq, const float* __restrict__ bk,
    float* __restrict__ Qo, float* __restrict__ Ko)
{
  const uint16_t *Ah, *Al, *Bh, *Bl;
  const float* bias; float* C;
  if (blockIdx.z == 0) { Ah = Aqh; Al = Aql; Bh = Bqh; Bl = Bql; bias = bq; C = Qo; }
  else                 { Ah = Akh; Al = Akl; Bh = Bkh; Bl = Bkl; bias = bk; C = Ko; }

  const int wid = threadIdx.x >> 6, lane = threadIdx.x & 63;
  const int m0 = (blockIdx.x * 4 + wid) * 32;
  const int n0 = blockIdx.y * 64;
  const int l15 = lane & 15, quad = lane >> 4;

  const long sa0 = (long)(m0 + l15) * E_ + quad * 8;
  const long sa1 = sa0 + 16L * E_;
  long boff[4];
#pragma unroll
  for (int j = 0; j < 4; j++) boff[j] = (long)(n0 + j * 16 + l15) * E_ + quad * 8;

  v4f accH[2][4] = {};
  v4f accX[2][4] = {};

  // prologue: load K-step 0
  v8h ah0 = *(const v8h*)(Ah + sa0);
  v8h al0 = *(const v8h*)(Al + sa0);
  v8h ah1 = *(const v8h*)(Ah + sa1);
  v8h al1 = *(const v8h*)(Al + sa1);
  v8h bh[4], bl[4];
#pragma unroll
  for (int j = 0; j < 4; j++) {
    bh[j] = *(const v8h*)(Bh + boff[j]);
    bl[j] = *(const v8h*)(Bl + boff[j]);
  }

  for (int k0 = 0; k0 < E_; k0 += 32) {
    // prefetch next K-step (wraps to 0 on last iter; values unused)
    const int kn = (k0 + 32) & (E_ - 1);
    const v8h nah0 = *(const v8h*)(Ah + sa0 + kn);
    const v8h nal0 = *(const v8h*)(Al + sa0 + kn);
    const v8h nah1 = *(const v8h*)(Ah + sa1 + kn);
    const v8h nal1 = *(const v8h*)(Al + sa1 + kn);
    v8h nbh[4], nbl[4];
#pragma unroll
    for (int j = 0; j < 4; j++) {
      nbh[j] = *(const v8h*)(Bh + boff[j] + kn);
      nbl[j] = *(const v8h*)(Bl + boff[j] + kn);
    }

    // 24 MFMAs: hh -> accH; h*l' and l'*h -> accX (carries 2^12 scale)
#pragma unroll
    for (int j = 0; j < 4; j++) {
      accH[0][j] = __builtin_amdgcn_mfma_f32_16x16x32_f16(ah0, bh[j], accH[0][j], 0, 0, 0);
      accH[1][j] = __builtin_amdgcn_mfma_f32_16x16x32_f16(ah1, bh[j], accH[1][j], 0, 0, 0);
    }
#pragma unroll
    for (int j = 0; j < 4; j++) {
      accX[0][j] = __builtin_amdgcn_mfma_f32_16x16x32_f16(ah0, bl[j], accX[0][j], 0, 0, 0);
      accX[1][j] = __builtin_amdgcn_mfma_f32_16x16x32_f16(ah1, bl[j], accX[1][j], 0, 0, 0);
    }
#pragma unroll
    for (int j = 0; j < 4; j++) {
      accX[0][j] = __builtin_amdgcn_mfma_f32_16x16x32_f16(al0, bh[j], accX[0][j], 0, 0, 0);
      accX[1][j] = __builtin_amdgcn_mfma_f32_16x16x32_f16(al1, bh[j], accX[1][j], 0, 0, 0);
    }

    // rotate
    ah0 = nah0; al0 = nal0; ah1 = nah1; al1 = nal1;
#pragma unroll
    for (int j = 0; j < 4; j++) { bh[j] = nbh[j]; bl[j] = nbl[j]; }
  }

#pragma unroll
  for (int i = 0; i < 2; i++)
#pragma unroll
    for (int j = 0; j < 4; j++) {
      const int colg = n0 + j * 16 + l15;
      const float bb = bias[colg];
#pragma unroll
      for (int r = 0; r < 4; r++) {
        const int mm = m0 + i * 16 + quad * 4 + r;
        C[(long)mm * E_ + colg] =
            accH[i][j][r] + accX[i][j][r] * (1.0f / 4096.0f) + bb;
      }
    }
}

// ---------------------------------------------------------------------------
// bf16 MFMA GEMM, A fp32 converted in-register, 2x4 tiles/wave (32x64).
// grid (M/128, E/64) = 256 blocks (1/CU). r11 measured-best body. Unchanged.
// ---------------------------------------------------------------------------
__global__ __launch_bounds__(256) void mfma_gemm(
    const float* __restrict__ A,
    const uint16_t* __restrict__ Bh, const uint16_t* __restrict__ Bl,
    const float* __restrict__ bias, float* __restrict__ C,
    int gatherA, int permC)
{
  const int wid = threadIdx.x >> 6, lane = threadIdx.x & 63;
  const int m0 = (blockIdx.x * 4 + wid) * 32;
  const int n0 = blockIdx.y * 64;
  const int l15 = lane & 15, quad = lane >> 4;

  const int ra0 = m0 + l15, ra1 = m0 + 16 + l15;
  const long sa0 = (gatherA ? ((long)(ra0 & 1) * T_ + (ra0 >> 1)) : (long)ra0) * E_ + quad * 8;
  const long sa1 = (gatherA ? ((long)(ra1 & 1) * T_ + (ra1 >> 1)) : (long)ra1) * E_ + quad * 8;
  long boff[4];
#pragma unroll
  for (int j = 0; j < 4; j++) boff[j] = (long)(n0 + j * 16 + l15) * E_ + quad * 8;

  v4f acc[2][4] = {};
  for (int k0 = 0; k0 < E_; k0 += 32) {
    v8s ah0, al0, ah1, al1;
    split8(*(const float4*)(A + sa0 + k0), *(const float4*)(A + sa0 + k0 + 4),
           ah0, al0);
    split8(*(const float4*)(A + sa1 + k0), *(const float4*)(A + sa1 + k0 + 4),
           ah1, al1);
    v8s bh[4], bl[4];
#pragma unroll
    for (int j = 0; j < 4; j++) {
      bh[j] = *(const v8s*)(Bh + boff[j] + k0);
      bl[j] = *(const v8s*)(Bl + boff[j] + k0);
    }
#pragma unroll
    for (int j = 0; j < 4; j++) {
      acc[0][j] = __builtin_amdgcn_mfma_f32_16x16x32_bf16(ah0, bh[j], acc[0][j], 0, 0, 0);
      acc[1][j] = __builtin_amdgcn_mfma_f32_16x16x32_bf16(ah1, bh[j], acc[1][j], 0, 0, 0);
    }
#pragma unroll
    for (int j = 0; j < 4; j++) {
      acc[0][j] = __builtin_amdgcn_mfma_f32_16x16x32_bf16(ah0, bl[j], acc[0][j], 0, 0, 0);
      acc[1][j] = __builtin_amdgcn_mfma_f32_16x16x32_bf16(ah1, bl[j], acc[1][j], 0, 0, 0);
    }
#pragma unroll
    for (int j = 0; j < 4; j++) {
      acc[0][j] = __builtin_amdgcn_mfma_f32_16x16x32_bf16(al0, bh[j], acc[0][j], 0, 0, 0);
      acc[1][j] = __builtin_amdgcn_mfma_f32_16x16x32_bf16(al1, bh[j], acc[1][j], 0, 0, 0);
    }
  }

#pragma unroll
  for (int i = 0; i < 2; i++)
#pragma unroll
    for (int j = 0; j < 4; j++) {
      const int colg = n0 + j * 16 + l15;
      const float bb = bias[colg];
#pragma unroll
      for (int r = 0; r < 4; r++) {
        const int mm = m0 + i * 16 + quad * 4 + r;
        const int crow = permC ? ((mm & (T_ - 1)) * B_ + (mm >> 11)) : mm;
        C[(long)crow * E_ + colg] = acc[i][j][r] + bb;
      }
    }
}

// ---------------------------------------------------------------------------
// LSH hash: W[r] staged in LDS, 2-j unroll, 4-way split partials, inline
// histogram (cnt pre-zeroed by prep). First-index argmax preserved. Unchanged.
// ---------------------------------------------------------------------------
__global__ __launch_bounds__(128) void hash_kernel(
    const float* __restrict__ Q, const float* __restrict__ K,
    const float* __restrict__ lshW, const float* __restrict__ lshb,
    int* __restrict__ qh, int* __restrict__ kh,
    int* __restrict__ qcnt, int* __restrict__ kcnt)
{
  __shared__ __align__(16) float xs[128 * 68];
  __shared__ __align__(16) float ws[64 * 64];
  const int tid = threadIdx.x;
  const int tau0 = blockIdx.x * 128;
  const int src = tau0 >> 16;
  const int r = (tau0 >> 15) & 1;
  const int rowbase = tau0 & 32767;
  const float* X = src ? K : Q;
  int* outh = src ? kh : qh;
  int* cnt = src ? kcnt : qcnt;

  const float4* g = (const float4*)(X + (long)rowbase * 64);
#pragma unroll
  for (int it = 0; it < 16; it++) {
    const int gidx = it * 128 + tid;
    const int row = gidx >> 4, c4 = gidx & 15;
    *(float4*)&xs[row * 68 + c4 * 4] = g[gidx];
  }
  const float4* wg = (const float4*)(lshW + (long)r * DH_ * DH_);
#pragma unroll
  for (int it = 0; it < 8; it++) {
    const int fidx = it * 128 + tid;
    ((float4*)ws)[fidx] = wg[fidx];
  }
  __syncthreads();

  float4 x[16];
#pragma unroll
  for (int i = 0; i < 16; i++) x[i] = *(const float4*)&xs[tid * 68 + i * 4];

  const float* bb = lshb + r * DH_;

  float best = -INFINITY; int bi = 0;
  for (int j = 0; j < 64; j += 2) {
    const float4* w0 = (const float4*)&ws[j * 64];
    const float4* w1 = (const float4*)&ws[(j + 1) * 64];
    float p0 = 0.f, p1 = 0.f, p2 = 0.f, p3 = 0.f;
    float q0 = 0.f, q1 = 0.f, q2 = 0.f, q3 = 0.f;
#pragma unroll
    for (int d = 0; d < 16; d++) {
      const float4 a = w0[d];
      const float4 c = w1[d];
      p0 += x[d].x * a.x; p1 += x[d].y * a.y;
      p2 += x[d].z * a.z; p3 += x[d].w * a.w;
      q0 += x[d].x * c.x; q1 += x[d].y * c.y;
      q2 += x[d].z * c.z; q3 += x[d].w * c.w;
    }
    const float s0 = ((p0 + p1) + (p2 + p3)) + bb[j];
    const float s1 = ((q0 + q1) + (q2 + q3)) + bb[j + 1];
    if (s0 > best) { best = s0; bi = j; }
    if (s1 > best) { best = s1; bi = j + 1; }
  }

  const int rowidx = rowbase + tid;
  const int p = rowidx >> 3, h = rowidx & 7;
  const int b = p >> 11, t = p & (T_ - 1);
  const int seg = (r * 16) + b * H_ + h;
  outh[seg * T_ + t] = bi;
  if (bi < NBUCKET) atomicAdd(&cnt[seg * NBUCKET + bi], 1);
}

// ---------------------------------------------------------------------------
// Scan v3: 2 blocks x 1024 threads; one thread per (seg,bucket).
// Bucket prefix via shfl width=32; task emission via per-wave prefix +
// ONE atomicAdd per wave (16 total vs 1024 serialized same-address before).
// Task order differs from v2 — attn_task treats tasks[] as unordered.
// ---------------------------------------------------------------------------
__global__ __launch_bounds__(1024) void scan_kernel(
    const int* __restrict__ kcnt, int* __restrict__ koff,
    int* __restrict__ kcur,
    const int* __restrict__ qcnt, int* __restrict__ qoff,
    int* __restrict__ qcur,
    int* __restrict__ ntasks, int* __restrict__ tasks)
{
  const int tid = threadIdx.x;          // 0..1023
  const int isq = blockIdx.x;           // 0 = k-side, 1 = q-side
  const int seg = tid >> 5;             // 0..31
  const int b   = tid & 31;             // bucket
  const int* cnt = isq ? qcnt : kcnt;
  int* off = isq ? qoff : koff;
  int* cur = isq ? qcur : kcur;

  const int c = cnt[seg * NBUCKET + b];

  // inclusive prefix over the 32 buckets of this segment (width-32 subgroups)
  int s = c;
#pragma unroll
  for (int d = 1; d < 32; d <<= 1) {
    const int t = __shfl_up(s, d, 32);
    if (b >= d) s += t;
  }
  const int excl = s - c;
  off[seg * (NBUCKET + 1) + b] = excl;
  cur[seg * NBUCKET + b] = excl;
  if (b == 31) off[seg * (NBUCKET + 1) + NBUCKET] = s;

  if (isq) {
    // task emission: nt 16-query tasks for this (seg,bucket)
    const int nt = (c + 15) >> 4;
    const int lane = tid & 63;
    int ws = nt;
#pragma unroll
    for (int d = 1; d < 64; d <<= 1) {
      const int t = __shfl_up(ws, d, 64);
      if (lane >= d) ws += t;
    }
    const int wtotal = __shfl(ws, 63, 64);
    int base = 0;
    if (lane == 63 && wtotal > 0) base = atomicAdd(ntasks, wtotal);
    base = __shfl(base, 63, 64);
    const int my = base + ws - nt;
    for (int i = 0; i < nt; i++)
      tasks[my + i] = (seg << 16) | (b << 8) | i;
  }
}

__global__ __launch_bounds__(256) void scatter2_kernel(
    const int* __restrict__ kh, const int* __restrict__ qh,
    int* __restrict__ kcur, int* __restrict__ qcur,
    int* __restrict__ klist, int* __restrict__ qlist)
{
  const int idx = blockIdx.x * 256 + threadIdx.x;
  const int y = blockIdx.y;
  const int* hsh = y ? qh : kh;
  int* cur = y ? qcur : kcur;
  int* list = y ? qlist : klist;
  const int v = hsh[idx];
  if (v < NBUCKET) {
    const int seg = idx >> 11;
    const int pos = atomicAdd(&cur[seg * NBUCKET + v], 1);
    list[seg * T_ + pos] = idx & (T_ - 1);
  }
}

// ---------------------------------------------------------------------------
// Task-parallel dense bucket attention (unchanged — proven).
// ---------------------------------------------------------------------------
__global__ __launch_bounds__(256) void attn_task(
    const float* __restrict__ Q, const float* __restrict__ K,
    const float* __restrict__ V,
    const int* __restrict__ qlist, const int* __restrict__ qoff,
    const int* __restrict__ klist, const int* __restrict__ koff,
    const int* __restrict__ tasks, const int* __restrict__ ntasks,
    float* __restrict__ attn)
{
  __shared__ __align__(16) float QPs[16 * 68];
  __shared__ __align__(16) float Ks[64 * 68];
  __shared__ __align__(16) float Vs[64 * 68];

  if ((int)blockIdx.x >= *ntasks) return;
  const int tk = tasks[blockIdx.x];
  const int seg = tk >> 16, bucket = (tk >> 8) & 255, qt = tk & 255;
  const int ctx = seg & 15;
  const int b = ctx >> 3, h = ctx & 7;

  const int qlo = qoff[seg * (NBUCKET + 1) + bucket] + qt * 16;
  const int nqt = min(16, qoff[seg * (NBUCKET + 1) + bucket + 1] - qlo);
  const int klo = koff[seg * (NBUCKET + 1) + bucket];
  const int nk  = koff[seg * (NBUCKET + 1) + bucket + 1] - klo;
  if (nk == 0) return;

  const int tid = threadIdx.x;
  const int qrow = tid >> 4, col = tid & 15;
  const float* Qb = Q + ((long)b * T_) * E_ + h * DH_;
  const float* Kb = K + ((long)b * T_) * E_ + h * DH_;
  const float* Vb = V + ((long)b * T_) * E_ + h * DH_;
  const int* ql = qlist + seg * T_;
  const int* kl = klist + seg * T_;

  {
    float4 v = make_float4(0.f, 0.f, 0.f, 0.f);
    if (qrow < nqt) v = *(const float4*)(Qb + (long)ql[qlo + qrow] * E_ + col * 4);
    *(float4*)&QPs[qrow * 68 + col * 4] = v;
  }
  __syncthreads();
  float4 qreg[16];
#pragma unroll
  for (int i = 0; i < 16; i++) qreg[i] = *(const float4*)&QPs[qrow * 68 + i * 4];

  float l = 0.f;
  float4 o = make_float4(0.f, 0.f, 0.f, 0.f);

  for (int kt = 0; kt < nk; kt += 64) {
    const int nkt = min(64, nk - kt);
    __syncthreads();
#pragma unroll
    for (int it = 0; it < 4; it++) {
      const int fidx = it * 256 + tid;
      const int row = fidx >> 4, c4 = fidx & 15;
      if (row < nkt) {
        const long src = (long)kl[klo + kt + row] * E_ + c4 * 4;
        *(float4*)&Ks[row * 68 + c4 * 4] = *(const float4*)(Kb + src);
        *(float4*)&Vs[row * 68 + c4 * 4] = *(const float4*)(Vb + src);
      } else {
        *(float4*)&Vs[row * 68 + c4 * 4] = make_float4(0.f, 0.f, 0.f, 0.f);
      }
    }
    __syncthreads();
#pragma unroll
    for (int kk = 0; kk < 4; kk++) {
      const int k = kk * 16 + col;
      float p = 0.f;
      if (k < nkt) {
        const float* kp = &Ks[k * 68];
        float s = 0.f;
#pragma unroll
        for (int d4 = 0; d4 < 16; d4++) {
          const float4 c = *(const float4*)(kp + d4 * 4);
          s += qreg[d4].x * c.x + qreg[d4].y * c.y +
               qreg[d4].z * c.z + qreg[d4].w * c.w;
        }
        p = __expf(s * 0.125f);
      }
      QPs[qrow * 68 + k] = p;
    }
    __syncthreads();
    const int nk4 = (nkt + 3) >> 2;
#pragma unroll 2
    for (int k4 = 0; k4 < nk4; k4++) {
      const float4 pk = *(const float4*)&QPs[qrow * 68 + k4 * 4];
      const float4 v0 = *(const float4*)&Vs[(k4 * 4 + 0) * 68 + col * 4];
      const float4 v1 = *(const float4*)&Vs[(k4 * 4 + 1) * 68 + col * 4];
      const float4 v2 = *(const float4*)&Vs[(k4 * 4 + 2) * 68 + col * 4];
      const float4 v3 = *(const float4*)&Vs[(k4 * 4 + 3) * 68 + col * 4];
      l += (pk.x + pk.y) + (pk.z + pk.w);
      o.x += pk.x * v0.x + pk.y * v1.x + pk.z * v2.x + pk.w * v3.x;
      o.y += pk.x * v0.y + pk.y * v1.y + pk.z * v2.y + pk.w * v3.y;
      o.z += pk.x * v0.z + pk.y * v1.z + pk.z * v2.z + pk.w * v3.z;
      o.w += pk.x * v0.w + pk.y * v1.w + pk.z * v2.w + pk.w * v3.w;
    }
  }

  if (qrow < nqt) {
    const float inv = 0.5f / l;
    const int t = ql[qlo + qrow];
    float* op = attn + ((long)b * T_ + t) * E_ + h * DH_ + col * 4;
    atomicAdd(op + 0, o.x * inv);
    atomicAdd(op + 1, o.y * inv);
    atomicAdd(op + 2, o.z * inv);
    atomicAdd(op + 3, o.w * inv);
  }
}

// ---------------------------------------------------------------------------
extern "C" void kernel_launch(void* const* d_in, const int* in_sizes, int n_in,
                              void* d_out, int out_size, void* d_ws, size_t ws_size,
                              hipStream_t stream) {
  const float* query = (const float*)d_in[0];
  const float* key   = (const float*)d_in[1];
  const float* value = (const float*)d_in[2];
  const float* Wq = (const float*)d_in[3];
  const float* bq = (const float*)d_in[4];
  const float* Wk = (const float*)d_in[5];
  const float* bk = (const float*)d_in[6];
  const float* Wv = (const float*)d_in[7];
  const float* bv = (const float*)d_in[8];
  const float* Wo = (const float*)d_in[9];
  const float* bo = (const float*)d_in[10];
  const float* lshW = (const float*)d_in[11];
  const float* lshb = (const float*)d_in[12];

  const size_t MSZ = (size_t)M_ * E_;
  float* Q    = (float*)d_ws;
  float* K    = Q + MSZ;
  float* V    = K + MSZ;
  float* attn = V + MSZ;
  int* qh     = (int*)(attn + MSZ);
  int* kh     = qh + NSEG * T_;
  int* klist  = kh + NSEG * T_;
  int* qlist  = klist + NSEG * T_;
  int* kcnt   = qlist + NSEG * T_;       // start of zeroed region
  int* qcnt   = kcnt + NSEG * NBUCKET;
  int* ntasks = qcnt + NSEG * NBUCKET;   // end of zeroed region
  int* kcur   = ntasks + 1;
  int* qcur   = kcur + NSEG * NBUCKET;
  int* koff   = qcur + NSEG * NBUCKET;
  int* qoff   = koff + NSEG * (NBUCKET + 1);
  int* tasks  = qoff + NSEG * (NBUCKET + 1);
  uint16_t* Wvh = (uint16_t*)(((uintptr_t)(tasks + MAXTASK) + 15) & ~(uintptr_t)15);
  uint16_t* Wvl = Wvh + (size_t)E_ * E_;
  uint16_t* Woh = Wvl + (size_t)E_ * E_;
  uint16_t* Wol = Woh + (size_t)E_ * E_;
  uint16_t* Wqh = Wol + (size_t)E_ * E_;
  uint16_t* Wql = Wqh + (size_t)E_ * E_;
  uint16_t* Wkh = Wql + (size_t)E_ * E_;
  uint16_t* Wkl = Wkh + (size_t)E_ * E_;
  uint16_t* Xqh = Wkl + (size_t)E_ * E_;
  uint16_t* Xql = Xqh + MSZ;
  uint16_t* Xkh = Xql + MSZ;
  uint16_t* Xkl = Xkh + MSZ;

  prep_kernel<<<dim3(3585), 256, 0, stream>>>(
      query, key, Wq, Wk, Wv, Wo,
      Xqh, Xql, Xkh, Xkl,
      Wqh, Wql, Wkh, Wkl,
      Wvh, Wvl, Woh, Wol, attn, kcnt);
  qk_mfma<<<dim3(M_ / 128, E_ / 64, 2), 256, 0, stream>>>(
      Xqh, Xql, Xkh, Xkl,
      Wqh, Wql, Wkh, Wkl, bq, bk, Q, K);
  mfma_gemm<<<dim3(M_ / 128, E_ / 64), 256, 0, stream>>>(
      value, Wvh, Wvl, bv, V, 1, 0);
  hash_kernel<<<dim3(1024), 128, 0, stream>>>(
      Q, K, lshW, lshb, qh, kh, qcnt, kcnt);
  scan_kernel<<<dim3(2), 1024, 0, stream>>>(kcnt, koff, kcur, qcnt, qoff, qcur,
                                            ntasks, tasks);
  scatter2_kernel<<<dim3(NSEG * T_ / 256, 2), 256, 0, stream>>>(
      kh, qh, kcur, qcur, klist, qlist);
  attn_task<<<dim3(MAXTASK), 256, 0, stream>>>(
      Q, K, V, qlist, qoff, klist, koff, tasks, ntasks, attn);
  mfma_gemm<<<dim3(M_ / 128, E_ / 64), 256, 0, stream>>>(
      attn, Woh, Wol, bo, (float*)d_out, 0, 1);
}

// Round 4
// 294.013 us; speedup vs baseline: 1.2872x; 1.0497x over previous
//
#include <hip/hip_runtime.h>
#include <stdint.h>
#include <math.h>

// ReformerAttention on MI355X — fp32 I/O. B=2,T=2048,E=512,H=8,Dh=64,
// 2 hash rounds, buckets<32 attend.
// Projection row p = logical (b'=p>>11, t'=p&2047); gathers input row (b=p&1, t=p>>1).
//
// 8 launches:
//   prep (2-way fp16 split of query/key/Wq/Wk/lshW + hi/lo bf16 split Wv/Wo + zero attn/cnt)
//   -> qk_mfma (Q,K proj: 3-term fp16 MFMA == fp32-exact; argmax-safe)
//   -> mfma(V, gather) -> hash_mfma(+hist) -> scan(+tasks) -> scatter2
//   -> attn_task -> mfma(out, perm)
//
// Q,K precision scheme (argmax needs fp32-class exactness):
//   x = h + l/4096 with h=fp16(x) (flushed to 0 if |x|<2^-14 so no subnormal
//   enters the matrix pipe), l=fp16((x-h)*2^12) — 2-way fp16 split carries
//   ~24 mantissa bits. Products hh -> accH; h*l' + l'*h -> accX (carries 2^12);
//   C = accH + accX*2^-12. Dropped ll ~ 2^-24 -> fp32-accumulation error class.
//   Verified passing (r2/r3, absmax unchanged vs fp32 kernel).
// qk_mfma schedule: register double-buffer. r1 lesson: no prefetch at 2
//   waves/SIMD = latency-bound 17% MfmaUtil.
// scan v3 (r3 win): one thread per (seg,bucket), shfl prefix scans, ONE
//   atomicAdd per wave. 61.7us -> off the profile.
// hash v4: r3 counters showed hash_kernel 54us @ 39% VALU / 9.6% occ —
//   LDS-read-bound fp32 dot loop at 3 blocks/CU (51KB LDS). Rewritten as
//   3-term fp16 MFMA GEMM (X[32768x64] @ lshW[r]^T), argmax in-register from
//   accumulator layout via quad shfl_xor reduce; no LDS; first-index
//   tie-break preserved.
// V/out proj: bf16 MFMA 16x16x32, 3-term hi/lo split, 2x4 tiles/wave (unchanged).

#define T_ 2048
#define E_ 512
#define H_ 8
#define DH_ 64
#define B_ 2
#define M_ 4096
#define NROUND 2
#define NBUCKET 32
#define NSEG 32
#define MAXTASK 5120

typedef short v8s __attribute__((ext_vector_type(8)));
typedef _Float16 v8h __attribute__((ext_vector_type(8)));
typedef float v4f __attribute__((ext_vector_type(4)));

__device__ __forceinline__ float bf2f(uint16_t u) {
  union { uint32_t i; float f; } v; v.i = ((uint32_t)u) << 16; return v.f;
}
__device__ __forceinline__ uint16_t f2bf(float f) {
  union { float fv; uint32_t i; } v; v.fv = f;
  uint32_t x = v.i;
  x += 0x7fffu + ((x >> 16) & 1u);   // RN-even
  return (uint16_t)(x >> 16);
}
__device__ __forceinline__ void split8(const float4 a, const float4 b,
                                       v8s& h, v8s& l) {
  const float x[8] = {a.x, a.y, a.z, a.w, b.x, b.y, b.z, b.w};
#pragma unroll
  for (int j = 0; j < 8; j++) {
    const uint16_t hh = f2bf(x[j]);
    h[j] = (short)hh;
    l[j] = (short)f2bf(x[j] - bf2f(hh));
  }
}
// 2-way fp16 split with scaled residual: x = h + l*2^-12, no fp16 subnormals
// in h (flushed to l), l normal for |residual| > 2^-26 (below that: fp32-class).
__device__ __forceinline__ void split2h8(const float4 a, const float4 b,
                                         v8h& h, v8h& l) {
  const float x[8] = {a.x, a.y, a.z, a.w, b.x, b.y, b.z, b.w};
#pragma unroll
  for (int j = 0; j < 8; j++) {
    const float xv = x[j];
    const _Float16 hh = (fabsf(xv) < 6.1035156e-5f) ? (_Float16)0.0f
                                                    : (_Float16)xv;
    const float r = xv - (float)hh;          // exact (Sterbenz / hh==0)
    h[j] = hh;
    l[j] = (_Float16)(r * 4096.0f);
  }
}

// ---------------------------------------------------------------------------
// prep: pure-bandwidth staging.
//   blocks [0,1024)    : query 2-way fp16 split, gathered into GEMM row order
//   blocks [1024,2048) : key   2-way fp16 split, gathered
//   blocks [2048,2176) : Wq fp16 split
//   blocks [2176,2304) : Wk fp16 split
//   blocks [2304,2432) : Wv bf16 hi/lo split
//   blocks [2432,2560) : Wo bf16 hi/lo split
//   blocks [2560,3584) : zero attn
//   block  3584        : zero cnt region + lshW fp16 split
// ---------------------------------------------------------------------------
__global__ __launch_bounds__(256) void prep_kernel(
    const float* __restrict__ Xq, const float* __restrict__ Xk,
    const float* __restrict__ Wq, const float* __restrict__ Wk,
    const float* __restrict__ Wv, const float* __restrict__ Wo,
    const float* __restrict__ lshW,
    uint16_t* __restrict__ Xqh, uint16_t* __restrict__ Xql,
    uint16_t* __restrict__ Xkh, uint16_t* __restrict__ Xkl,
    uint16_t* __restrict__ Wqh, uint16_t* __restrict__ Wql,
    uint16_t* __restrict__ Wkh, uint16_t* __restrict__ Wkl,
    uint16_t* __restrict__ Wvh, uint16_t* __restrict__ Wvl,
    uint16_t* __restrict__ Woh, uint16_t* __restrict__ Wol,
    uint16_t* __restrict__ Lwh, uint16_t* __restrict__ Lwl,
    float* __restrict__ attn, int* __restrict__ cnt)
{
  const int bid = blockIdx.x;
  const int tid = threadIdx.x;

  if (bid < 2048) {                      // query/key fp16 split (gathered)
    const int is_k = bid >> 10;
    const float* X = is_k ? Xk : Xq;
    uint16_t* H = is_k ? Xkh : Xqh;
    uint16_t* L = is_k ? Xkl : Xql;
    const int e = ((bid & 1023) * 256 + tid) * 8;   // [0, M_*E_)
    const int p = e >> 9, k = e & 511;
    const long src = ((long)(p & 1) * T_ + (p >> 1)) * E_ + k;
    const float4 a = *(const float4*)(X + src);
    const float4 b = *(const float4*)(X + src + 4);
    v8h h, l;
    split2h8(a, b, h, l);
    *(v8h*)(H + e) = h;
    *(v8h*)(L + e) = l;
    return;
  }

  if (bid < 2560) {                      // weight splits
    const int wsel = (bid - 2048) >> 7;  // 0=Wq,1=Wk,2=Wv,3=Wo
    const int e = (((bid - 2048) & 127) * 256 + tid) * 8;   // [0, E_*E_)
    if (wsel < 2) {
      const float* S = wsel ? Wk : Wq;
      const float4 a = *(const float4*)(S + e);
      const float4 b = *(const float4*)(S + e + 4);
      v8h h, l;
      split2h8(a, b, h, l);
      uint16_t* H = wsel ? Wkh : Wqh;
      uint16_t* L = wsel ? Wkl : Wql;
      *(v8h*)(H + e) = h;
      *(v8h*)(L + e) = l;
    } else {
      const float* S = (wsel == 2) ? Wv : Wo;
      const float4 a = *(const float4*)(S + e);
      const float4 b = *(const float4*)(S + e + 4);
      v8s h, l;
      split8(a, b, h, l);
      uint16_t* H = (wsel == 2) ? Wvh : Woh;
      uint16_t* L = (wsel == 2) ? Wvl : Wol;
      *(v8s*)(H + e) = h;
      *(v8s*)(L + e) = l;
    }
    return;
  }

  if (bid < 3584) {                      // zero attn: 1024 blocks x 512 float4
    float4* a4 = (float4*)attn;
    const int g = (bid - 2560) * 512 + tid * 2;
    a4[g] = make_float4(0.f, 0.f, 0.f, 0.f);
    a4[g + 1] = make_float4(0.f, 0.f, 0.f, 0.f);
    return;
  }

  for (int i = tid; i < 2 * NSEG * NBUCKET + 1; i += 256) cnt[i] = 0;
  for (int i = tid; i < NROUND * DH_ * DH_; i += 256) {  // lshW fp16 split
    const float xv = lshW[i];
    const _Float16 hh = (fabsf(xv) < 6.1035156e-5f) ? (_Float16)0.0f
                                                    : (_Float16)xv;
    const float r = xv - (float)hh;
    *(_Float16*)(Lwh + i) = hh;
    *(_Float16*)(Lwl + i) = (_Float16)(r * 4096.0f);
  }
}

// ---------------------------------------------------------------------------
// qk_mfma: Q/K projection via 3-term fp16-split MFMA (fp32-equivalent).
// grid (M/128, E/64, 2), 256 threads, 2x4 16x16 tiles/wave. A pre-split &
// pre-gathered (linear reads); register double-buffered K-loop; C written
// fp32 in GEMM row order (= Q/K layout).
// ---------------------------------------------------------------------------
__global__ __launch_bounds__(256) void qk_mfma(
    const uint16_t* __restrict__ Aqh, const uint16_t* __restrict__ Aql,
    const uint16_t* __restrict__ Akh, const uint16_t* __restrict__ Akl,
    const uint16_t* __restrict__ Bqh, const uint16_t* __restrict__ Bql,
    const uint16_t* __restrict__ Bkh, const uint16_t* __restrict__ Bkl,
    const float* __restrict__ bq, const float* __restrict__ bk,
    float* __restrict__ Qo, float* __restrict__ Ko)
{
  const uint16_t *Ah, *Al, *Bh, *Bl;
  const float* bias; float* C;
  if (blockIdx.z == 0) { Ah = Aqh; Al = Aql; Bh = Bqh; Bl = Bql; bias = bq; C = Qo; }
  else                 { Ah = Akh; Al = Akl; Bh = Bkh; Bl = Bkl; bias = bk; C = Ko; }

  const int wid = threadIdx.x >> 6, lane = threadIdx.x & 63;
  const int m0 = (blockIdx.x * 4 + wid) * 32;
  const int n0 = blockIdx.y * 64;
  const int l15 = lane & 15, quad = lane >> 4;

  const long sa0 = (long)(m0 + l15) * E_ + quad * 8;
  const long sa1 = sa0 + 16L * E_;
  long boff[4];
#pragma unroll
  for (int j = 0; j < 4; j++) boff[j] = (long)(n0 + j * 16 + l15) * E_ + quad * 8;

  v4f accH[2][4] = {};
  v4f accX[2][4] = {};

  // prologue: load K-step 0
  v8h ah0 = *(const v8h*)(Ah + sa0);
  v8h al0 = *(const v8h*)(Al + sa0);
  v8h ah1 = *(const v8h*)(Ah + sa1);
  v8h al1 = *(const v8h*)(Al + sa1);
  v8h bh[4], bl[4];
#pragma unroll
  for (int j = 0; j < 4; j++) {
    bh[j] = *(const v8h*)(Bh + boff[j]);
    bl[j] = *(const v8h*)(Bl + boff[j]);
  }

  for (int k0 = 0; k0 < E_; k0 += 32) {
    // prefetch next K-step (wraps to 0 on last iter; values unused)
    const int kn = (k0 + 32) & (E_ - 1);
    const v8h nah0 = *(const v8h*)(Ah + sa0 + kn);
    const v8h nal0 = *(const v8h*)(Al + sa0 + kn);
    const v8h nah1 = *(const v8h*)(Ah + sa1 + kn);
    const v8h nal1 = *(const v8h*)(Al + sa1 + kn);
    v8h nbh[4], nbl[4];
#pragma unroll
    for (int j = 0; j < 4; j++) {
      nbh[j] = *(const v8h*)(Bh + boff[j] + kn);
      nbl[j] = *(const v8h*)(Bl + boff[j] + kn);
    }

    // 24 MFMAs: hh -> accH; h*l' and l'*h -> accX (carries 2^12 scale)
#pragma unroll
    for (int j = 0; j < 4; j++) {
      accH[0][j] = __builtin_amdgcn_mfma_f32_16x16x32_f16(ah0, bh[j], accH[0][j], 0, 0, 0);
      accH[1][j] = __builtin_amdgcn_mfma_f32_16x16x32_f16(ah1, bh[j], accH[1][j], 0, 0, 0);
    }
#pragma unroll
    for (int j = 0; j < 4; j++) {
      accX[0][j] = __builtin_amdgcn_mfma_f32_16x16x32_f16(ah0, bl[j], accX[0][j], 0, 0, 0);
      accX[1][j] = __builtin_amdgcn_mfma_f32_16x16x32_f16(ah1, bl[j], accX[1][j], 0, 0, 0);
    }
#pragma unroll
    for (int j = 0; j < 4; j++) {
      accX[0][j] = __builtin_amdgcn_mfma_f32_16x16x32_f16(al0, bh[j], accX[0][j], 0, 0, 0);
      accX[1][j] = __builtin_amdgcn_mfma_f32_16x16x32_f16(al1, bh[j], accX[1][j], 0, 0, 0);
    }

    // rotate
    ah0 = nah0; al0 = nal0; ah1 = nah1; al1 = nal1;
#pragma unroll
    for (int j = 0; j < 4; j++) { bh[j] = nbh[j]; bl[j] = nbl[j]; }
  }

#pragma unroll
  for (int i = 0; i < 2; i++)
#pragma unroll
    for (int j = 0; j < 4; j++) {
      const int colg = n0 + j * 16 + l15;
      const float bb = bias[colg];
#pragma unroll
      for (int r = 0; r < 4; r++) {
        const int mm = m0 + i * 16 + quad * 4 + r;
        C[(long)mm * E_ + colg] =
            accH[i][j][r] + accX[i][j][r] * (1.0f / 4096.0f) + bb;
      }
    }
}

// ---------------------------------------------------------------------------
// bf16 MFMA GEMM, A fp32 converted in-register, 2x4 tiles/wave (32x64).
// grid (M/128, E/64) = 256 blocks (1/CU). r11 measured-best body. Unchanged.
// ---------------------------------------------------------------------------
__global__ __launch_bounds__(256) void mfma_gemm(
    const float* __restrict__ A,
    const uint16_t* __restrict__ Bh, const uint16_t* __restrict__ Bl,
    const float* __restrict__ bias, float* __restrict__ C,
    int gatherA, int permC)
{
  const int wid = threadIdx.x >> 6, lane = threadIdx.x & 63;
  const int m0 = (blockIdx.x * 4 + wid) * 32;
  const int n0 = blockIdx.y * 64;
  const int l15 = lane & 15, quad = lane >> 4;

  const int ra0 = m0 + l15, ra1 = m0 + 16 + l15;
  const long sa0 = (gatherA ? ((long)(ra0 & 1) * T_ + (ra0 >> 1)) : (long)ra0) * E_ + quad * 8;
  const long sa1 = (gatherA ? ((long)(ra1 & 1) * T_ + (ra1 >> 1)) : (long)ra1) * E_ + quad * 8;
  long boff[4];
#pragma unroll
  for (int j = 0; j < 4; j++) boff[j] = (long)(n0 + j * 16 + l15) * E_ + quad * 8;

  v4f acc[2][4] = {};
  for (int k0 = 0; k0 < E_; k0 += 32) {
    v8s ah0, al0, ah1, al1;
    split8(*(const float4*)(A + sa0 + k0), *(const float4*)(A + sa0 + k0 + 4),
           ah0, al0);
    split8(*(const float4*)(A + sa1 + k0), *(const float4*)(A + sa1 + k0 + 4),
           ah1, al1);
    v8s bh[4], bl[4];
#pragma unroll
    for (int j = 0; j < 4; j++) {
      bh[j] = *(const v8s*)(Bh + boff[j] + k0);
      bl[j] = *(const v8s*)(Bl + boff[j] + k0);
    }
#pragma unroll
    for (int j = 0; j < 4; j++) {
      acc[0][j] = __builtin_amdgcn_mfma_f32_16x16x32_bf16(ah0, bh[j], acc[0][j], 0, 0, 0);
      acc[1][j] = __builtin_amdgcn_mfma_f32_16x16x32_bf16(ah1, bh[j], acc[1][j], 0, 0, 0);
    }
#pragma unroll
    for (int j = 0; j < 4; j++) {
      acc[0][j] = __builtin_amdgcn_mfma_f32_16x16x32_bf16(ah0, bl[j], acc[0][j], 0, 0, 0);
      acc[1][j] = __builtin_amdgcn_mfma_f32_16x16x32_bf16(ah1, bl[j], acc[1][j], 0, 0, 0);
    }
#pragma unroll
    for (int j = 0; j < 4; j++) {
      acc[0][j] = __builtin_amdgcn_mfma_f32_16x16x32_bf16(al0, bh[j], acc[0][j], 0, 0, 0);
      acc[1][j] = __builtin_amdgcn_mfma_f32_16x16x32_bf16(al1, bh[j], acc[1][j], 0, 0, 0);
    }
  }

#pragma unroll
  for (int i = 0; i < 2; i++)
#pragma unroll
    for (int j = 0; j < 4; j++) {
      const int colg = n0 + j * 16 + l15;
      const float bb = bias[colg];
#pragma unroll
      for (int r = 0; r < 4; r++) {
        const int mm = m0 + i * 16 + quad * 4 + r;
        const int crow = permC ? ((mm & (T_ - 1)) * B_ + (mm >> 11)) : mm;
        C[(long)crow * E_ + colg] = acc[i][j][r] + bb;
      }
    }
}

// ---------------------------------------------------------------------------
// hash_mfma v4: LSH hash as 3-term fp16 MFMA GEMM + in-register argmax.
// X head-rows [32768 x 64] @ lshW[r]^T [64 x 64] + lshb, argmax over 64.
// grid (256, 4): y = src*2 + r; 256 thr; wave does 32 rows (2x4 tiles, K=64).
// A read fp32 from Q/K (L2-resident), split in-register; B pre-split by prep.
// Argmax: local over 4 n-tiles, then shfl_xor over the quad's 16 lanes;
// first-index tie-break (v>best || (v==best && idx<besti)) == jnp.argmax.
// ---------------------------------------------------------------------------
__global__ __launch_bounds__(256) void hash_mfma(
    const float* __restrict__ Q, const float* __restrict__ K,
    const uint16_t* __restrict__ Lwh, const uint16_t* __restrict__ Lwl,
    const float* __restrict__ lshb,
    int* __restrict__ qh, int* __restrict__ kh,
    int* __restrict__ qcnt, int* __restrict__ kcnt)
{
  const int comb = blockIdx.y;               // 0..3
  const int src = comb >> 1, r = comb & 1;
  const float* X = src ? K : Q;
  int* outh = src ? kh : qh;
  int* cnt  = src ? kcnt : qcnt;

  const int wid = threadIdx.x >> 6, lane = threadIdx.x & 63;
  const int m0 = (blockIdx.x * 4 + wid) * 32;  // head-row base (32 rows/wave)
  const int l15 = lane & 15, quad = lane >> 4;

  // B fragments: lshW[r] is [64 buckets][64 dims] row-major = N x K.
  v8h bh[4][2], bl[4][2];
#pragma unroll
  for (int n = 0; n < 4; n++)
#pragma unroll
    for (int k = 0; k < 2; k++) {
      const int o = r * (DH_ * DH_) + (n * 16 + l15) * DH_ + k * 32 + quad * 8;
      bh[n][k] = *(const v8h*)(Lwh + o);
      bl[n][k] = *(const v8h*)(Lwl + o);
    }

  v4f accH[2][4] = {};
  v4f accX[2][4] = {};
#pragma unroll
  for (int k = 0; k < 2; k++) {
    const long a0 = (long)(m0 + l15) * DH_ + k * 32 + quad * 8;
    const long a1 = a0 + 16L * DH_;
    v8h ah0, al0, ah1, al1;
    split2h8(*(const float4*)(X + a0), *(const float4*)(X + a0 + 4), ah0, al0);
    split2h8(*(const float4*)(X + a1), *(const float4*)(X + a1 + 4), ah1, al1);
#pragma unroll
    for (int n = 0; n < 4; n++) {
      accH[0][n] = __builtin_amdgcn_mfma_f32_16x16x32_f16(ah0, bh[n][k], accH[0][n], 0, 0, 0);
      accH[1][n] = __builtin_amdgcn_mfma_f32_16x16x32_f16(ah1, bh[n][k], accH[1][n], 0, 0, 0);
      accX[0][n] = __builtin_amdgcn_mfma_f32_16x16x32_f16(ah0, bl[n][k], accX[0][n], 0, 0, 0);
      accX[1][n] = __builtin_amdgcn_mfma_f32_16x16x32_f16(ah1, bl[n][k], accX[1][n], 0, 0, 0);
      accX[0][n] = __builtin_amdgcn_mfma_f32_16x16x32_f16(al0, bh[n][k], accX[0][n], 0, 0, 0);
      accX[1][n] = __builtin_amdgcn_mfma_f32_16x16x32_f16(al1, bh[n][k], accX[1][n], 0, 0, 0);
    }
  }

  float bb[4];
#pragma unroll
  for (int n = 0; n < 4; n++) bb[n] = lshb[r * DH_ + n * 16 + l15];

#pragma unroll
  for (int i = 0; i < 2; i++)
#pragma unroll
    for (int reg = 0; reg < 4; reg++) {
      float bv = -INFINITY; int bi = 0x7fffffff;
#pragma unroll
      for (int n = 0; n < 4; n++) {
        const float v = accH[i][n][reg] + accX[i][n][reg] * (1.0f / 4096.0f)
                        + bb[n];
        const int idx = n * 16 + l15;
        if (v > bv || (v == bv && idx < bi)) { bv = v; bi = idx; }
      }
#pragma unroll
      for (int d = 8; d >= 1; d >>= 1) {
        const float ov = __shfl_xor(bv, d);
        const int oi = __shfl_xor(bi, d);
        if (ov > bv || (ov == bv && oi < bi)) { bv = ov; bi = oi; }
      }
      if (l15 == 0) {
        const int hr = m0 + i * 16 + quad * 4 + reg;
        const int p = hr >> 3, hh = hr & 7;
        const int bt = p >> 11, t = p & (T_ - 1);
        const int seg = r * 16 + bt * H_ + hh;
        outh[seg * T_ + t] = bi;
        if (bi < NBUCKET) atomicAdd(&cnt[seg * NBUCKET + bi], 1);
      }
    }
}

// ---------------------------------------------------------------------------
// Scan v3: 2 blocks x 1024 threads; one thread per (seg,bucket).
// Bucket prefix via shfl width=32; task emission via per-wave prefix +
// ONE atomicAdd per wave (16 total). Task order is irrelevant to attn_task.
// ---------------------------------------------------------------------------
__global__ __launch_bounds__(1024) void scan_kernel(
    const int* __restrict__ kcnt, int* __restrict__ koff,
    int* __restrict__ kcur,
    const int* __restrict__ qcnt, int* __restrict__ qoff,
    int* __restrict__ qcur,
    int* __restrict__ ntasks, int* __restrict__ tasks)
{
  const int tid = threadIdx.x;          // 0..1023
  const int isq = blockIdx.x;           // 0 = k-side, 1 = q-side
  const int seg = tid >> 5;             // 0..31
  const int b   = tid & 31;             // bucket
  const int* cnt = isq ? qcnt : kcnt;
  int* off = isq ? qoff : koff;
  int* cur = isq ? qcur : kcur;

  const int c = cnt[seg * NBUCKET + b];

  int s = c;
#pragma unroll
  for (int d = 1; d < 32; d <<= 1) {
    const int t = __shfl_up(s, d, 32);
    if (b >= d) s += t;
  }
  const int excl = s - c;
  off[seg * (NBUCKET + 1) + b] = excl;
  cur[seg * NBUCKET + b] = excl;
  if (b == 31) off[seg * (NBUCKET + 1) + NBUCKET] = s;

  if (isq) {
    const int nt = (c + 15) >> 4;
    const int lane = tid & 63;
    int ws = nt;
#pragma unroll
    for (int d = 1; d < 64; d <<= 1) {
      const int t = __shfl_up(ws, d, 64);
      if (lane >= d) ws += t;
    }
    const int wtotal = __shfl(ws, 63, 64);
    int base = 0;
    if (lane == 63 && wtotal > 0) base = atomicAdd(ntasks, wtotal);
    base = __shfl(base, 63, 64);
    const int my = base + ws - nt;
    for (int i = 0; i < nt; i++)
      tasks[my + i] = (seg << 16) | (b << 8) | i;
  }
}

__global__ __launch_bounds__(256) void scatter2_kernel(
    const int* __restrict__ kh, const int* __restrict__ qh,
    int* __restrict__ kcur, int* __restrict__ qcur,
    int* __restrict__ klist, int* __restrict__ qlist)
{
  const int idx = blockIdx.x * 256 + threadIdx.x;
  const int y = blockIdx.y;
  const int* hsh = y ? qh : kh;
  int* cur = y ? qcur : kcur;
  int* list = y ? qlist : klist;
  const int v = hsh[idx];
  if (v < NBUCKET) {
    const int seg = idx >> 11;
    const int pos = atomicAdd(&cur[seg * NBUCKET + v], 1);
    list[seg * T_ + pos] = idx & (T_ - 1);
  }
}

// ---------------------------------------------------------------------------
// Task-parallel dense bucket attention (unchanged — proven).
// ---------------------------------------------------------------------------
__global__ __launch_bounds__(256) void attn_task(
    const float* __restrict__ Q, const float* __restrict__ K,
    const float* __restrict__ V,
    const int* __restrict__ qlist, const int* __restrict__ qoff,
    const int* __restrict__ klist, const int* __restrict__ koff,
    const int* __restrict__ tasks, const int* __restrict__ ntasks,
    float* __restrict__ attn)
{
  __shared__ __align__(16) float QPs[16 * 68];
  __shared__ __align__(16) float Ks[64 * 68];
  __shared__ __align__(16) float Vs[64 * 68];

  if ((int)blockIdx.x >= *ntasks) return;
  const int tk = tasks[blockIdx.x];
  const int seg = tk >> 16, bucket = (tk >> 8) & 255, qt = tk & 255;
  const int ctx = seg & 15;
  const int b = ctx >> 3, h = ctx & 7;

  const int qlo = qoff[seg * (NBUCKET + 1) + bucket] + qt * 16;
  const int nqt = min(16, qoff[seg * (NBUCKET + 1) + bucket + 1] - qlo);
  const int klo = koff[seg * (NBUCKET + 1) + bucket];
  const int nk  = koff[seg * (NBUCKET + 1) + bucket + 1] - klo;
  if (nk == 0) return;

  const int tid = threadIdx.x;
  const int qrow = tid >> 4, col = tid & 15;
  const float* Qb = Q + ((long)b * T_) * E_ + h * DH_;
  const float* Kb = K + ((long)b * T_) * E_ + h * DH_;
  const float* Vb = V + ((long)b * T_) * E_ + h * DH_;
  const int* ql = qlist + seg * T_;
  const int* kl = klist + seg * T_;

  {
    float4 v = make_float4(0.f, 0.f, 0.f, 0.f);
    if (qrow < nqt) v = *(const float4*)(Qb + (long)ql[qlo + qrow] * E_ + col * 4);
    *(float4*)&QPs[qrow * 68 + col * 4] = v;
  }
  __syncthreads();
  float4 qreg[16];
#pragma unroll
  for (int i = 0; i < 16; i++) qreg[i] = *(const float4*)&QPs[qrow * 68 + i * 4];

  float l = 0.f;
  float4 o = make_float4(0.f, 0.f, 0.f, 0.f);

  for (int kt = 0; kt < nk; kt += 64) {
    const int nkt = min(64, nk - kt);
    __syncthreads();
#pragma unroll
    for (int it = 0; it < 4; it++) {
      const int fidx = it * 256 + tid;
      const int row = fidx >> 4, c4 = fidx & 15;
      if (row < nkt) {
        const long src = (long)kl[klo + kt + row] * E_ + c4 * 4;
        *(float4*)&Ks[row * 68 + c4 * 4] = *(const float4*)(Kb + src);
        *(float4*)&Vs[row * 68 + c4 * 4] = *(const float4*)(Vb + src);
      } else {
        *(float4*)&Vs[row * 68 + c4 * 4] = make_float4(0.f, 0.f, 0.f, 0.f);
      }
    }
    __syncthreads();
#pragma unroll
    for (int kk = 0; kk < 4; kk++) {
      const int k = kk * 16 + col;
      float p = 0.f;
      if (k < nkt) {
        const float* kp = &Ks[k * 68];
        float s = 0.f;
#pragma unroll
        for (int d4 = 0; d4 < 16; d4++) {
          const float4 c = *(const float4*)(kp + d4 * 4);
          s += qreg[d4].x * c.x + qreg[d4].y * c.y +
               qreg[d4].z * c.z + qreg[d4].w * c.w;
        }
        p = __expf(s * 0.125f);
      }
      QPs[qrow * 68 + k] = p;
    }
    __syncthreads();
    const int nk4 = (nkt + 3) >> 2;
#pragma unroll 2
    for (int k4 = 0; k4 < nk4; k4++) {
      const float4 pk = *(const float4*)&QPs[qrow * 68 + k4 * 4];
      const float4 v0 = *(const float4*)&Vs[(k4 * 4 + 0) * 68 + col * 4];
      const float4 v1 = *(const float4*)&Vs[(k4 * 4 + 1) * 68 + col * 4];
      const float4 v2 = *(const float4*)&Vs[(k4 * 4 + 2) * 68 + col * 4];
      const float4 v3 = *(const float4*)&Vs[(k4 * 4 + 3) * 68 + col * 4];
      l += (pk.x + pk.y) + (pk.z + pk.w);
      o.x += pk.x * v0.x + pk.y * v1.x + pk.z * v2.x + pk.w * v3.x;
      o.y += pk.x * v0.y + pk.y * v1.y + pk.z * v2.y + pk.w * v3.y;
      o.z += pk.x * v0.z + pk.y * v1.z + pk.z * v2.z + pk.w * v3.z;
      o.w += pk.x * v0.w + pk.y * v1.w + pk.z * v2.w + pk.w * v3.w;
    }
  }

  if (qrow < nqt) {
    const float inv = 0.5f / l;
    const int t = ql[qlo + qrow];
    float* op = attn + ((long)b * T_ + t) * E_ + h * DH_ + col * 4;
    atomicAdd(op + 0, o.x * inv);
    atomicAdd(op + 1, o.y * inv);
    atomicAdd(op + 2, o.z * inv);
    atomicAdd(op + 3, o.w * inv);
  }
}

// ---------------------------------------------------------------------------
extern "C" void kernel_launch(void* const* d_in, const int* in_sizes, int n_in,
                              void* d_out, int out_size, void* d_ws, size_t ws_size,
                              hipStream_t stream) {
  const float* query = (const float*)d_in[0];
  const float* key   = (const float*)d_in[1];
  const float* value = (const float*)d_in[2];
  const float* Wq = (const float*)d_in[3];
  const float* bq = (const float*)d_in[4];
  const float* Wk = (const float*)d_in[5];
  const float* bk = (const float*)d_in[6];
  const float* Wv = (const float*)d_in[7];
  const float* bv = (const float*)d_in[8];
  const float* Wo = (const float*)d_in[9];
  const float* bo = (const float*)d_in[10];
  const float* lshW = (const float*)d_in[11];
  const float* lshb = (const float*)d_in[12];

  const size_t MSZ = (size_t)M_ * E_;
  float* Q    = (float*)d_ws;
  float* K    = Q + MSZ;
  float* V    = K + MSZ;
  float* attn = V + MSZ;
  int* qh     = (int*)(attn + MSZ);
  int* kh     = qh + NSEG * T_;
  int* klist  = kh + NSEG * T_;
  int* qlist  = klist + NSEG * T_;
  int* kcnt   = qlist + NSEG * T_;       // start of zeroed region
  int* qcnt   = kcnt + NSEG * NBUCKET;
  int* ntasks = qcnt + NSEG * NBUCKET;   // end of zeroed region
  int* kcur   = ntasks + 1;
  int* qcur   = kcur + NSEG * NBUCKET;
  int* koff   = qcur + NSEG * NBUCKET;
  int* qoff   = koff + NSEG * (NBUCKET + 1);
  int* tasks  = qoff + NSEG * (NBUCKET + 1);
  uint16_t* Wvh = (uint16_t*)(((uintptr_t)(tasks + MAXTASK) + 15) & ~(uintptr_t)15);
  uint16_t* Wvl = Wvh + (size_t)E_ * E_;
  uint16_t* Woh = Wvl + (size_t)E_ * E_;
  uint16_t* Wol = Woh + (size_t)E_ * E_;
  uint16_t* Wqh = Wol + (size_t)E_ * E_;
  uint16_t* Wql = Wqh + (size_t)E_ * E_;
  uint16_t* Wkh = Wql + (size_t)E_ * E_;
  uint16_t* Wkl = Wkh + (size_t)E_ * E_;
  uint16_t* Xqh = Wkl + (size_t)E_ * E_;
  uint16_t* Xql = Xqh + MSZ;
  uint16_t* Xkh = Xql + MSZ;
  uint16_t* Xkl = Xkh + MSZ;
  uint16_t* Lwh = Xkl + MSZ;
  uint16_t* Lwl = Lwh + (size_t)NROUND * DH_ * DH_;

  prep_kernel<<<dim3(3585), 256, 0, stream>>>(
      query, key, Wq, Wk, Wv, Wo, lshW,
      Xqh, Xql, Xkh, Xkl,
      Wqh, Wql, Wkh, Wkl,
      Wvh, Wvl, Woh, Wol, Lwh, Lwl, attn, kcnt);
  qk_mfma<<<dim3(M_ / 128, E_ / 64, 2), 256, 0, stream>>>(
      Xqh, Xql, Xkh, Xkl,
      Wqh, Wql, Wkh, Wkl, bq, bk, Q, K);
  mfma_gemm<<<dim3(M_ / 128, E_ / 64), 256, 0, stream>>>(
      value, Wvh, Wvl, bv, V, 1, 0);
  hash_mfma<<<dim3(M_ * H_ / 128, 4), 256, 0, stream>>>(
      Q, K, Lwh, Lwl, lshb, qh, kh, qcnt, kcnt);
  scan_kernel<<<dim3(2), 1024, 0, stream>>>(kcnt, koff, kcur, qcnt, qoff, qcur,
                                            ntasks, tasks);
  scatter2_kernel<<<dim3(NSEG * T_ / 256, 2), 256, 0, stream>>>(
      kh, qh, kcur, qcur, klist, qlist);
  attn_task<<<dim3(MAXTASK), 256, 0, stream>>>(
      Q, K, V, qlist, qoff, klist, koff, tasks, ntasks, attn);
  mfma_gemm<<<dim3(M_ / 128, E_ / 64), 256, 0, stream>>>(
      attn, Woh, Wol, bo, (float*)d_out, 0, 1);
}

// Round 5
// 288.900 us; speedup vs baseline: 1.3099x; 1.0177x over previous
//
#include <hip/hip_runtime.h>
#include <stdint.h>
#include <math.h>

// ReformerAttention on MI355X — fp32 I/O. B=2,T=2048,E=512,H=8,Dh=64,
// 2 hash rounds, buckets<32 attend.
// Projection row p = logical (b'=p>>11, t'=p&2047); gathers input row (b=p&1, t=p>>1).
//
// 7 launches:
//   prep (2-way fp16 split of query/key/Wq/Wk/lshW + hi/lo bf16 split Wv/Wo + zero attn/cnt)
//   -> proj_mfma (fused Q,K,V projections: z=0/1 fp16 3-term; z=2 bf16 3-term)
//   -> hash_mfma(+hist) -> scan(+tasks) -> scatter2
//   -> attn_task -> mfma(out, perm)
//
// Q,K precision scheme (argmax needs fp32-class exactness):
//   x = h + l/4096 with h=fp16(x) (flushed to 0 if |x|<2^-14 so no subnormal
//   enters the matrix pipe), l=fp16((x-h)*2^12) — 2-way fp16 split carries
//   ~24 mantissa bits. Products hh -> accH; h*l' + l'*h -> accX (carries 2^12);
//   C = accH + accX*2^-12. Dropped ll ~ 2^-24 -> fp32-accumulation error class.
//   Verified passing (r2-r4, absmax unchanged vs fp32 kernel).
// r4 lesson: qk_mfma at 53us with MfmaUtil 8.8 / VALU 7.5 / HBM 8 / occ 16%
//   — pure latency-bound; time tracked LOAD COUNT (18->12 loads = 77->53us).
//   Grid was the occupancy cap (512 blocks = 2 waves/SIMD). v5: fuse Q,K,V
//   projections into ONE dispatch (768 blocks = 3 blocks/CU = 12 waves/CU);
//   V's MFMAs hide qk's load-waits and vice versa.
// scan v3 (r3 win): one thread per (seg,bucket), shfl prefix scans, ONE
//   atomicAdd per wave. hash v4 (r4 win): 3-term fp16 MFMA + in-reg argmax.
// V/out proj: bf16 MFMA 16x16x32, 3-term hi/lo split, 2x4 tiles/wave.

#define T_ 2048
#define E_ 512
#define H_ 8
#define DH_ 64
#define B_ 2
#define M_ 4096
#define NROUND 2
#define NBUCKET 32
#define NSEG 32
#define MAXTASK 5120

typedef short v8s __attribute__((ext_vector_type(8)));
typedef _Float16 v8h __attribute__((ext_vector_type(8)));
typedef float v4f __attribute__((ext_vector_type(4)));

__device__ __forceinline__ float bf2f(uint16_t u) {
  union { uint32_t i; float f; } v; v.i = ((uint32_t)u) << 16; return v.f;
}
__device__ __forceinline__ uint16_t f2bf(float f) {
  union { float fv; uint32_t i; } v; v.fv = f;
  uint32_t x = v.i;
  x += 0x7fffu + ((x >> 16) & 1u);   // RN-even
  return (uint16_t)(x >> 16);
}
__device__ __forceinline__ void split8(const float4 a, const float4 b,
                                       v8s& h, v8s& l) {
  const float x[8] = {a.x, a.y, a.z, a.w, b.x, b.y, b.z, b.w};
#pragma unroll
  for (int j = 0; j < 8; j++) {
    const uint16_t hh = f2bf(x[j]);
    h[j] = (short)hh;
    l[j] = (short)f2bf(x[j] - bf2f(hh));
  }
}
// 2-way fp16 split with scaled residual: x = h + l*2^-12, no fp16 subnormals
// in h (flushed to l), l normal for |residual| > 2^-26 (below that: fp32-class).
__device__ __forceinline__ void split2h8(const float4 a, const float4 b,
                                         v8h& h, v8h& l) {
  const float x[8] = {a.x, a.y, a.z, a.w, b.x, b.y, b.z, b.w};
#pragma unroll
  for (int j = 0; j < 8; j++) {
    const float xv = x[j];
    const _Float16 hh = (fabsf(xv) < 6.1035156e-5f) ? (_Float16)0.0f
                                                    : (_Float16)xv;
    const float r = xv - (float)hh;          // exact (Sterbenz / hh==0)
    h[j] = hh;
    l[j] = (_Float16)(r * 4096.0f);
  }
}

// ---------------------------------------------------------------------------
// prep: pure-bandwidth staging.
//   blocks [0,1024)    : query 2-way fp16 split, gathered into GEMM row order
//   blocks [1024,2048) : key   2-way fp16 split, gathered
//   blocks [2048,2176) : Wq fp16 split
//   blocks [2176,2304) : Wk fp16 split
//   blocks [2304,2432) : Wv bf16 hi/lo split
//   blocks [2432,2560) : Wo bf16 hi/lo split
//   blocks [2560,3584) : zero attn
//   block  3584        : zero cnt region + lshW fp16 split
// ---------------------------------------------------------------------------
__global__ __launch_bounds__(256) void prep_kernel(
    const float* __restrict__ Xq, const float* __restrict__ Xk,
    const float* __restrict__ Wq, const float* __restrict__ Wk,
    const float* __restrict__ Wv, const float* __restrict__ Wo,
    const float* __restrict__ lshW,
    uint16_t* __restrict__ Xqh, uint16_t* __restrict__ Xql,
    uint16_t* __restrict__ Xkh, uint16_t* __restrict__ Xkl,
    uint16_t* __restrict__ Wqh, uint16_t* __restrict__ Wql,
    uint16_t* __restrict__ Wkh, uint16_t* __restrict__ Wkl,
    uint16_t* __restrict__ Wvh, uint16_t* __restrict__ Wvl,
    uint16_t* __restrict__ Woh, uint16_t* __restrict__ Wol,
    uint16_t* __restrict__ Lwh, uint16_t* __restrict__ Lwl,
    float* __restrict__ attn, int* __restrict__ cnt)
{
  const int bid = blockIdx.x;
  const int tid = threadIdx.x;

  if (bid < 2048) {                      // query/key fp16 split (gathered)
    const int is_k = bid >> 10;
    const float* X = is_k ? Xk : Xq;
    uint16_t* H = is_k ? Xkh : Xqh;
    uint16_t* L = is_k ? Xkl : Xql;
    const int e = ((bid & 1023) * 256 + tid) * 8;   // [0, M_*E_)
    const int p = e >> 9, k = e & 511;
    const long src = ((long)(p & 1) * T_ + (p >> 1)) * E_ + k;
    const float4 a = *(const float4*)(X + src);
    const float4 b = *(const float4*)(X + src + 4);
    v8h h, l;
    split2h8(a, b, h, l);
    *(v8h*)(H + e) = h;
    *(v8h*)(L + e) = l;
    return;
  }

  if (bid < 2560) {                      // weight splits
    const int wsel = (bid - 2048) >> 7;  // 0=Wq,1=Wk,2=Wv,3=Wo
    const int e = (((bid - 2048) & 127) * 256 + tid) * 8;   // [0, E_*E_)
    if (wsel < 2) {
      const float* S = wsel ? Wk : Wq;
      const float4 a = *(const float4*)(S + e);
      const float4 b = *(const float4*)(S + e + 4);
      v8h h, l;
      split2h8(a, b, h, l);
      uint16_t* H = wsel ? Wkh : Wqh;
      uint16_t* L = wsel ? Wkl : Wql;
      *(v8h*)(H + e) = h;
      *(v8h*)(L + e) = l;
    } else {
      const float* S = (wsel == 2) ? Wv : Wo;
      const float4 a = *(const float4*)(S + e);
      const float4 b = *(const float4*)(S + e + 4);
      v8s h, l;
      split8(a, b, h, l);
      uint16_t* H = (wsel == 2) ? Wvh : Woh;
      uint16_t* L = (wsel == 2) ? Wvl : Wol;
      *(v8s*)(H + e) = h;
      *(v8s*)(L + e) = l;
    }
    return;
  }

  if (bid < 3584) {                      // zero attn: 1024 blocks x 512 float4
    float4* a4 = (float4*)attn;
    const int g = (bid - 2560) * 512 + tid * 2;
    a4[g] = make_float4(0.f, 0.f, 0.f, 0.f);
    a4[g + 1] = make_float4(0.f, 0.f, 0.f, 0.f);
    return;
  }

  for (int i = tid; i < 2 * NSEG * NBUCKET + 1; i += 256) cnt[i] = 0;
  for (int i = tid; i < NROUND * DH_ * DH_; i += 256) {  // lshW fp16 split
    const float xv = lshW[i];
    const _Float16 hh = (fabsf(xv) < 6.1035156e-5f) ? (_Float16)0.0f
                                                    : (_Float16)xv;
    const float r = xv - (float)hh;
    *(_Float16*)(Lwh + i) = hh;
    *(_Float16*)(Lwl + i) = (_Float16)(r * 4096.0f);
  }
}

// ---------------------------------------------------------------------------
// proj_mfma v5: fused Q/K/V projections, one dispatch, 768 blocks (3/CU,
// 12 waves/CU). z=0: Q proj, z=1: K proj (fp16 3-term, pre-split A/B,
// register double-buffered). z=2: V proj (bf16 3-term, fp32 A gathered,
// in-register split). Bodies identical to the r4 kernels (bit-identical out).
// ---------------------------------------------------------------------------
__global__ __launch_bounds__(256) void proj_mfma(
    const uint16_t* __restrict__ Aqh, const uint16_t* __restrict__ Aql,
    const uint16_t* __restrict__ Akh, const uint16_t* __restrict__ Akl,
    const uint16_t* __restrict__ Bqh, const uint16_t* __restrict__ Bql,
    const uint16_t* __restrict__ Bkh, const uint16_t* __restrict__ Bkl,
    const float* __restrict__ bq, const float* __restrict__ bk,
    float* __restrict__ Qo, float* __restrict__ Ko,
    const float* __restrict__ Av,
    const uint16_t* __restrict__ Bvh, const uint16_t* __restrict__ Bvl,
    const float* __restrict__ bv, float* __restrict__ Vo)
{
  const int wid = threadIdx.x >> 6, lane = threadIdx.x & 63;
  const int m0 = (blockIdx.x * 4 + wid) * 32;
  const int n0 = blockIdx.y * 64;
  const int l15 = lane & 15, quad = lane >> 4;

  if (blockIdx.z == 2) {
    // ---- V path: bf16 3-term, fp32 A gathered + split in-register ----
    const int ra0 = m0 + l15, ra1 = m0 + 16 + l15;
    const long sa0 = ((long)(ra0 & 1) * T_ + (ra0 >> 1)) * E_ + quad * 8;
    const long sa1 = ((long)(ra1 & 1) * T_ + (ra1 >> 1)) * E_ + quad * 8;
    long boff[4];
#pragma unroll
    for (int j = 0; j < 4; j++) boff[j] = (long)(n0 + j * 16 + l15) * E_ + quad * 8;

    v4f acc[2][4] = {};
    for (int k0 = 0; k0 < E_; k0 += 32) {
      v8s ah0, al0, ah1, al1;
      split8(*(const float4*)(Av + sa0 + k0), *(const float4*)(Av + sa0 + k0 + 4),
             ah0, al0);
      split8(*(const float4*)(Av + sa1 + k0), *(const float4*)(Av + sa1 + k0 + 4),
             ah1, al1);
      v8s bh[4], bl[4];
#pragma unroll
      for (int j = 0; j < 4; j++) {
        bh[j] = *(const v8s*)(Bvh + boff[j] + k0);
        bl[j] = *(const v8s*)(Bvl + boff[j] + k0);
      }
#pragma unroll
      for (int j = 0; j < 4; j++) {
        acc[0][j] = __builtin_amdgcn_mfma_f32_16x16x32_bf16(ah0, bh[j], acc[0][j], 0, 0, 0);
        acc[1][j] = __builtin_amdgcn_mfma_f32_16x16x32_bf16(ah1, bh[j], acc[1][j], 0, 0, 0);
      }
#pragma unroll
      for (int j = 0; j < 4; j++) {
        acc[0][j] = __builtin_amdgcn_mfma_f32_16x16x32_bf16(ah0, bl[j], acc[0][j], 0, 0, 0);
        acc[1][j] = __builtin_amdgcn_mfma_f32_16x16x32_bf16(ah1, bl[j], acc[1][j], 0, 0, 0);
      }
#pragma unroll
      for (int j = 0; j < 4; j++) {
        acc[0][j] = __builtin_amdgcn_mfma_f32_16x16x32_bf16(al0, bh[j], acc[0][j], 0, 0, 0);
        acc[1][j] = __builtin_amdgcn_mfma_f32_16x16x32_bf16(al1, bh[j], acc[1][j], 0, 0, 0);
      }
    }

#pragma unroll
    for (int i = 0; i < 2; i++)
#pragma unroll
      for (int j = 0; j < 4; j++) {
        const int colg = n0 + j * 16 + l15;
        const float bb = bv[colg];
#pragma unroll
        for (int r = 0; r < 4; r++) {
          const int mm = m0 + i * 16 + quad * 4 + r;
          Vo[(long)mm * E_ + colg] = acc[i][j][r] + bb;
        }
      }
    return;
  }

  // ---- Q/K path: fp16 3-term, pre-split A/B, register double-buffer ----
  const uint16_t *Ah, *Al, *Bh, *Bl;
  const float* bias; float* C;
  if (blockIdx.z == 0) { Ah = Aqh; Al = Aql; Bh = Bqh; Bl = Bql; bias = bq; C = Qo; }
  else                 { Ah = Akh; Al = Akl; Bh = Bkh; Bl = Bkl; bias = bk; C = Ko; }

  const long sa0 = (long)(m0 + l15) * E_ + quad * 8;
  const long sa1 = sa0 + 16L * E_;
  long boff[4];
#pragma unroll
  for (int j = 0; j < 4; j++) boff[j] = (long)(n0 + j * 16 + l15) * E_ + quad * 8;

  v4f accH[2][4] = {};
  v4f accX[2][4] = {};

  // prologue: load K-step 0
  v8h ah0 = *(const v8h*)(Ah + sa0);
  v8h al0 = *(const v8h*)(Al + sa0);
  v8h ah1 = *(const v8h*)(Ah + sa1);
  v8h al1 = *(const v8h*)(Al + sa1);
  v8h bh[4], bl[4];
#pragma unroll
  for (int j = 0; j < 4; j++) {
    bh[j] = *(const v8h*)(Bh + boff[j]);
    bl[j] = *(const v8h*)(Bl + boff[j]);
  }

  for (int k0 = 0; k0 < E_; k0 += 32) {
    // prefetch next K-step (wraps to 0 on last iter; values unused)
    const int kn = (k0 + 32) & (E_ - 1);
    const v8h nah0 = *(const v8h*)(Ah + sa0 + kn);
    const v8h nal0 = *(const v8h*)(Al + sa0 + kn);
    const v8h nah1 = *(const v8h*)(Ah + sa1 + kn);
    const v8h nal1 = *(const v8h*)(Al + sa1 + kn);
    v8h nbh[4], nbl[4];
#pragma unroll
    for (int j = 0; j < 4; j++) {
      nbh[j] = *(const v8h*)(Bh + boff[j] + kn);
      nbl[j] = *(const v8h*)(Bl + boff[j] + kn);
    }

    // 24 MFMAs: hh -> accH; h*l' and l'*h -> accX (carries 2^12 scale)
#pragma unroll
    for (int j = 0; j < 4; j++) {
      accH[0][j] = __builtin_amdgcn_mfma_f32_16x16x32_f16(ah0, bh[j], accH[0][j], 0, 0, 0);
      accH[1][j] = __builtin_amdgcn_mfma_f32_16x16x32_f16(ah1, bh[j], accH[1][j], 0, 0, 0);
    }
#pragma unroll
    for (int j = 0; j < 4; j++) {
      accX[0][j] = __builtin_amdgcn_mfma_f32_16x16x32_f16(ah0, bl[j], accX[0][j], 0, 0, 0);
      accX[1][j] = __builtin_amdgcn_mfma_f32_16x16x32_f16(ah1, bl[j], accX[1][j], 0, 0, 0);
    }
#pragma unroll
    for (int j = 0; j < 4; j++) {
      accX[0][j] = __builtin_amdgcn_mfma_f32_16x16x32_f16(al0, bh[j], accX[0][j], 0, 0, 0);
      accX[1][j] = __builtin_amdgcn_mfma_f32_16x16x32_f16(al1, bh[j], accX[1][j], 0, 0, 0);
    }

    // rotate
    ah0 = nah0; al0 = nal0; ah1 = nah1; al1 = nal1;
#pragma unroll
    for (int j = 0; j < 4; j++) { bh[j] = nbh[j]; bl[j] = nbl[j]; }
  }

#pragma unroll
  for (int i = 0; i < 2; i++)
#pragma unroll
    for (int j = 0; j < 4; j++) {
      const int colg = n0 + j * 16 + l15;
      const float bb = bias[colg];
#pragma unroll
      for (int r = 0; r < 4; r++) {
        const int mm = m0 + i * 16 + quad * 4 + r;
        C[(long)mm * E_ + colg] =
            accH[i][j][r] + accX[i][j][r] * (1.0f / 4096.0f) + bb;
      }
    }
}

// ---------------------------------------------------------------------------
// bf16 MFMA GEMM, A fp32 converted in-register, 2x4 tiles/wave (32x64).
// Used only for the out-projection (attn @ Wo, permC=1). Proven body.
// ---------------------------------------------------------------------------
__global__ __launch_bounds__(256) void mfma_gemm(
    const float* __restrict__ A,
    const uint16_t* __restrict__ Bh, const uint16_t* __restrict__ Bl,
    const float* __restrict__ bias, float* __restrict__ C,
    int gatherA, int permC)
{
  const int wid = threadIdx.x >> 6, lane = threadIdx.x & 63;
  const int m0 = (blockIdx.x * 4 + wid) * 32;
  const int n0 = blockIdx.y * 64;
  const int l15 = lane & 15, quad = lane >> 4;

  const int ra0 = m0 + l15, ra1 = m0 + 16 + l15;
  const long sa0 = (gatherA ? ((long)(ra0 & 1) * T_ + (ra0 >> 1)) : (long)ra0) * E_ + quad * 8;
  const long sa1 = (gatherA ? ((long)(ra1 & 1) * T_ + (ra1 >> 1)) : (long)ra1) * E_ + quad * 8;
  long boff[4];
#pragma unroll
  for (int j = 0; j < 4; j++) boff[j] = (long)(n0 + j * 16 + l15) * E_ + quad * 8;

  v4f acc[2][4] = {};
  for (int k0 = 0; k0 < E_; k0 += 32) {
    v8s ah0, al0, ah1, al1;
    split8(*(const float4*)(A + sa0 + k0), *(const float4*)(A + sa0 + k0 + 4),
           ah0, al0);
    split8(*(const float4*)(A + sa1 + k0), *(const float4*)(A + sa1 + k0 + 4),
           ah1, al1);
    v8s bh[4], bl[4];
#pragma unroll
    for (int j = 0; j < 4; j++) {
      bh[j] = *(const v8s*)(Bh + boff[j] + k0);
      bl[j] = *(const v8s*)(Bl + boff[j] + k0);
    }
#pragma unroll
    for (int j = 0; j < 4; j++) {
      acc[0][j] = __builtin_amdgcn_mfma_f32_16x16x32_bf16(ah0, bh[j], acc[0][j], 0, 0, 0);
      acc[1][j] = __builtin_amdgcn_mfma_f32_16x16x32_bf16(ah1, bh[j], acc[1][j], 0, 0, 0);
    }
#pragma unroll
    for (int j = 0; j < 4; j++) {
      acc[0][j] = __builtin_amdgcn_mfma_f32_16x16x32_bf16(ah0, bl[j], acc[0][j], 0, 0, 0);
      acc[1][j] = __builtin_amdgcn_mfma_f32_16x16x32_bf16(ah1, bl[j], acc[1][j], 0, 0, 0);
    }
#pragma unroll
    for (int j = 0; j < 4; j++) {
      acc[0][j] = __builtin_amdgcn_mfma_f32_16x16x32_bf16(al0, bh[j], acc[0][j], 0, 0, 0);
      acc[1][j] = __builtin_amdgcn_mfma_f32_16x16x32_bf16(al1, bh[j], acc[1][j], 0, 0, 0);
    }
  }

#pragma unroll
  for (int i = 0; i < 2; i++)
#pragma unroll
    for (int j = 0; j < 4; j++) {
      const int colg = n0 + j * 16 + l15;
      const float bb = bias[colg];
#pragma unroll
      for (int r = 0; r < 4; r++) {
        const int mm = m0 + i * 16 + quad * 4 + r;
        const int crow = permC ? ((mm & (T_ - 1)) * B_ + (mm >> 11)) : mm;
        C[(long)crow * E_ + colg] = acc[i][j][r] + bb;
      }
    }
}

// ---------------------------------------------------------------------------
// hash_mfma v4: LSH hash as 3-term fp16 MFMA GEMM + in-register argmax.
// X head-rows [32768 x 64] @ lshW[r]^T [64 x 64] + lshb, argmax over 64.
// grid (256, 4): y = src*2 + r; 256 thr; wave does 32 rows (2x4 tiles, K=64).
// ---------------------------------------------------------------------------
__global__ __launch_bounds__(256) void hash_mfma(
    const float* __restrict__ Q, const float* __restrict__ K,
    const uint16_t* __restrict__ Lwh, const uint16_t* __restrict__ Lwl,
    const float* __restrict__ lshb,
    int* __restrict__ qh, int* __restrict__ kh,
    int* __restrict__ qcnt, int* __restrict__ kcnt)
{
  const int comb = blockIdx.y;               // 0..3
  const int src = comb >> 1, r = comb & 1;
  const float* X = src ? K : Q;
  int* outh = src ? kh : qh;
  int* cnt  = src ? kcnt : qcnt;

  const int wid = threadIdx.x >> 6, lane = threadIdx.x & 63;
  const int m0 = (blockIdx.x * 4 + wid) * 32;  // head-row base (32 rows/wave)
  const int l15 = lane & 15, quad = lane >> 4;

  // B fragments: lshW[r] is [64 buckets][64 dims] row-major = N x K.
  v8h bh[4][2], bl[4][2];
#pragma unroll
  for (int n = 0; n < 4; n++)
#pragma unroll
    for (int k = 0; k < 2; k++) {
      const int o = r * (DH_ * DH_) + (n * 16 + l15) * DH_ + k * 32 + quad * 8;
      bh[n][k] = *(const v8h*)(Lwh + o);
      bl[n][k] = *(const v8h*)(Lwl + o);
    }

  v4f accH[2][4] = {};
  v4f accX[2][4] = {};
#pragma unroll
  for (int k = 0; k < 2; k++) {
    const long a0 = (long)(m0 + l15) * DH_ + k * 32 + quad * 8;
    const long a1 = a0 + 16L * DH_;
    v8h ah0, al0, ah1, al1;
    split2h8(*(const float4*)(X + a0), *(const float4*)(X + a0 + 4), ah0, al0);
    split2h8(*(const float4*)(X + a1), *(const float4*)(X + a1 + 4), ah1, al1);
#pragma unroll
    for (int n = 0; n < 4; n++) {
      accH[0][n] = __builtin_amdgcn_mfma_f32_16x16x32_f16(ah0, bh[n][k], accH[0][n], 0, 0, 0);
      accH[1][n] = __builtin_amdgcn_mfma_f32_16x16x32_f16(ah1, bh[n][k], accH[1][n], 0, 0, 0);
      accX[0][n] = __builtin_amdgcn_mfma_f32_16x16x32_f16(ah0, bl[n][k], accX[0][n], 0, 0, 0);
      accX[1][n] = __builtin_amdgcn_mfma_f32_16x16x32_f16(ah1, bl[n][k], accX[1][n], 0, 0, 0);
      accX[0][n] = __builtin_amdgcn_mfma_f32_16x16x32_f16(al0, bh[n][k], accX[0][n], 0, 0, 0);
      accX[1][n] = __builtin_amdgcn_mfma_f32_16x16x32_f16(al1, bh[n][k], accX[1][n], 0, 0, 0);
    }
  }

  float bb[4];
#pragma unroll
  for (int n = 0; n < 4; n++) bb[n] = lshb[r * DH_ + n * 16 + l15];

#pragma unroll
  for (int i = 0; i < 2; i++)
#pragma unroll
    for (int reg = 0; reg < 4; reg++) {
      float bv = -INFINITY; int bi = 0x7fffffff;
#pragma unroll
      for (int n = 0; n < 4; n++) {
        const float v = accH[i][n][reg] + accX[i][n][reg] * (1.0f / 4096.0f)
                        + bb[n];
        const int idx = n * 16 + l15;
        if (v > bv || (v == bv && idx < bi)) { bv = v; bi = idx; }
      }
#pragma unroll
      for (int d = 8; d >= 1; d >>= 1) {
        const float ov = __shfl_xor(bv, d);
        const int oi = __shfl_xor(bi, d);
        if (ov > bv || (ov == bv && oi < bi)) { bv = ov; bi = oi; }
      }
      if (l15 == 0) {
        const int hr = m0 + i * 16 + quad * 4 + reg;
        const int p = hr >> 3, hh = hr & 7;
        const int bt = p >> 11, t = p & (T_ - 1);
        const int seg = r * 16 + bt * H_ + hh;
        outh[seg * T_ + t] = bi;
        if (bi < NBUCKET) atomicAdd(&cnt[seg * NBUCKET + bi], 1);
      }
    }
}

// ---------------------------------------------------------------------------
// Scan v3: 2 blocks x 1024 threads; one thread per (seg,bucket).
// Bucket prefix via shfl width=32; task emission via per-wave prefix +
// ONE atomicAdd per wave (16 total). Task order is irrelevant to attn_task.
// ---------------------------------------------------------------------------
__global__ __launch_bounds__(1024) void scan_kernel(
    const int* __restrict__ kcnt, int* __restrict__ koff,
    int* __restrict__ kcur,
    const int* __restrict__ qcnt, int* __restrict__ qoff,
    int* __restrict__ qcur,
    int* __restrict__ ntasks, int* __restrict__ tasks)
{
  const int tid = threadIdx.x;          // 0..1023
  const int isq = blockIdx.x;           // 0 = k-side, 1 = q-side
  const int seg = tid >> 5;             // 0..31
  const int b   = tid & 31;             // bucket
  const int* cnt = isq ? qcnt : kcnt;
  int* off = isq ? qoff : koff;
  int* cur = isq ? qcur : kcur;

  const int c = cnt[seg * NBUCKET + b];

  int s = c;
#pragma unroll
  for (int d = 1; d < 32; d <<= 1) {
    const int t = __shfl_up(s, d, 32);
    if (b >= d) s += t;
  }
  const int excl = s - c;
  off[seg * (NBUCKET + 1) + b] = excl;
  cur[seg * NBUCKET + b] = excl;
  if (b == 31) off[seg * (NBUCKET + 1) + NBUCKET] = s;

  if (isq) {
    const int nt = (c + 15) >> 4;
    const int lane = tid & 63;
    int ws = nt;
#pragma unroll
    for (int d = 1; d < 64; d <<= 1) {
      const int t = __shfl_up(ws, d, 64);
      if (lane >= d) ws += t;
    }
    const int wtotal = __shfl(ws, 63, 64);
    int base = 0;
    if (lane == 63 && wtotal > 0) base = atomicAdd(ntasks, wtotal);
    base = __shfl(base, 63, 64);
    const int my = base + ws - nt;
    for (int i = 0; i < nt; i++)
      tasks[my + i] = (seg << 16) | (b << 8) | i;
  }
}

__global__ __launch_bounds__(256) void scatter2_kernel(
    const int* __restrict__ kh, const int* __restrict__ qh,
    int* __restrict__ kcur, int* __restrict__ qcur,
    int* __restrict__ klist, int* __restrict__ qlist)
{
  const int idx = blockIdx.x * 256 + threadIdx.x;
  const int y = blockIdx.y;
  const int* hsh = y ? qh : kh;
  int* cur = y ? qcur : kcur;
  int* list = y ? qlist : klist;
  const int v = hsh[idx];
  if (v < NBUCKET) {
    const int seg = idx >> 11;
    const int pos = atomicAdd(&cur[seg * NBUCKET + v], 1);
    list[seg * T_ + pos] = idx & (T_ - 1);
  }
}

// ---------------------------------------------------------------------------
// Task-parallel dense bucket attention (unchanged — proven).
// ---------------------------------------------------------------------------
__global__ __launch_bounds__(256) void attn_task(
    const float* __restrict__ Q, const float* __restrict__ K,
    const float* __restrict__ V,
    const int* __restrict__ qlist, const int* __restrict__ qoff,
    const int* __restrict__ klist, const int* __restrict__ koff,
    const int* __restrict__ tasks, const int* __restrict__ ntasks,
    float* __restrict__ attn)
{
  __shared__ __align__(16) float QPs[16 * 68];
  __shared__ __align__(16) float Ks[64 * 68];
  __shared__ __align__(16) float Vs[64 * 68];

  if ((int)blockIdx.x >= *ntasks) return;
  const int tk = tasks[blockIdx.x];
  const int seg = tk >> 16, bucket = (tk >> 8) & 255, qt = tk & 255;
  const int ctx = seg & 15;
  const int b = ctx >> 3, h = ctx & 7;

  const int qlo = qoff[seg * (NBUCKET + 1) + bucket] + qt * 16;
  const int nqt = min(16, qoff[seg * (NBUCKET + 1) + bucket + 1] - qlo);
  const int klo = koff[seg * (NBUCKET + 1) + bucket];
  const int nk  = koff[seg * (NBUCKET + 1) + bucket + 1] - klo;
  if (nk == 0) return;

  const int tid = threadIdx.x;
  const int qrow = tid >> 4, col = tid & 15;
  const float* Qb = Q + ((long)b * T_) * E_ + h * DH_;
  const float* Kb = K + ((long)b * T_) * E_ + h * DH_;
  const float* Vb = V + ((long)b * T_) * E_ + h * DH_;
  const int* ql = qlist + seg * T_;
  const int* kl = klist + seg * T_;

  {
    float4 v = make_float4(0.f, 0.f, 0.f, 0.f);
    if (qrow < nqt) v = *(const float4*)(Qb + (long)ql[qlo + qrow] * E_ + col * 4);
    *(float4*)&QPs[qrow * 68 + col * 4] = v;
  }
  __syncthreads();
  float4 qreg[16];
#pragma unroll
  for (int i = 0; i < 16; i++) qreg[i] = *(const float4*)&QPs[qrow * 68 + i * 4];

  float l = 0.f;
  float4 o = make_float4(0.f, 0.f, 0.f, 0.f);

  for (int kt = 0; kt < nk; kt += 64) {
    const int nkt = min(64, nk - kt);
    __syncthreads();
#pragma unroll
    for (int it = 0; it < 4; it++) {
      const int fidx = it * 256 + tid;
      const int row = fidx >> 4, c4 = fidx & 15;
      if (row < nkt) {
        const long src = (long)kl[klo + kt + row] * E_ + c4 * 4;
        *(float4*)&Ks[row * 68 + c4 * 4] = *(const float4*)(Kb + src);
        *(float4*)&Vs[row * 68 + c4 * 4] = *(const float4*)(Vb + src);
      } else {
        *(float4*)&Vs[row * 68 + c4 * 4] = make_float4(0.f, 0.f, 0.f, 0.f);
      }
    }
    __syncthreads();
#pragma unroll
    for (int kk = 0; kk < 4; kk++) {
      const int k = kk * 16 + col;
      float p = 0.f;
      if (k < nkt) {
        const float* kp = &Ks[k * 68];
        float s = 0.f;
#pragma unroll
        for (int d4 = 0; d4 < 16; d4++) {
          const float4 c = *(const float4*)(kp + d4 * 4);
          s += qreg[d4].x * c.x + qreg[d4].y * c.y +
               qreg[d4].z * c.z + qreg[d4].w * c.w;
        }
        p = __expf(s * 0.125f);
      }
      QPs[qrow * 68 + k] = p;
    }
    __syncthreads();
    const int nk4 = (nkt + 3) >> 2;
#pragma unroll 2
    for (int k4 = 0; k4 < nk4; k4++) {
      const float4 pk = *(const float4*)&QPs[qrow * 68 + k4 * 4];
      const float4 v0 = *(const float4*)&Vs[(k4 * 4 + 0) * 68 + col * 4];
      const float4 v1 = *(const float4*)&Vs[(k4 * 4 + 1) * 68 + col * 4];
      const float4 v2 = *(const float4*)&Vs[(k4 * 4 + 2) * 68 + col * 4];
      const float4 v3 = *(const float4*)&Vs[(k4 * 4 + 3) * 68 + col * 4];
      l += (pk.x + pk.y) + (pk.z + pk.w);
      o.x += pk.x * v0.x + pk.y * v1.x + pk.z * v2.x + pk.w * v3.x;
      o.y += pk.x * v0.y + pk.y * v1.y + pk.z * v2.y + pk.w * v3.y;
      o.z += pk.x * v0.z + pk.y * v1.z + pk.z * v2.z + pk.w * v3.z;
      o.w += pk.x * v0.w + pk.y * v1.w + pk.z * v2.w + pk.w * v3.w;
    }
  }

  if (qrow < nqt) {
    const float inv = 0.5f / l;
    const int t = ql[qlo + qrow];
    float* op = attn + ((long)b * T_ + t) * E_ + h * DH_ + col * 4;
    atomicAdd(op + 0, o.x * inv);
    atomicAdd(op + 1, o.y * inv);
    atomicAdd(op + 2, o.z * inv);
    atomicAdd(op + 3, o.w * inv);
  }
}

// ---------------------------------------------------------------------------
extern "C" void kernel_launch(void* const* d_in, const int* in_sizes, int n_in,
                              void* d_out, int out_size, void* d_ws, size_t ws_size,
                              hipStream_t stream) {
  const float* query = (const float*)d_in[0];
  const float* key   = (const float*)d_in[1];
  const float* value = (const float*)d_in[2];
  const float* Wq = (const float*)d_in[3];
  const float* bq = (const float*)d_in[4];
  const float* Wk = (const float*)d_in[5];
  const float* bk = (const float*)d_in[6];
  const float* Wv = (const float*)d_in[7];
  const float* bv = (const float*)d_in[8];
  const float* Wo = (const float*)d_in[9];
  const float* bo = (const float*)d_in[10];
  const float* lshW = (const float*)d_in[11];
  const float* lshb = (const float*)d_in[12];

  const size_t MSZ = (size_t)M_ * E_;
  float* Q    = (float*)d_ws;
  float* K    = Q + MSZ;
  float* V    = K + MSZ;
  float* attn = V + MSZ;
  int* qh     = (int*)(attn + MSZ);
  int* kh     = qh + NSEG * T_;
  int* klist  = kh + NSEG * T_;
  int* qlist  = klist + NSEG * T_;
  int* kcnt   = qlist + NSEG * T_;       // start of zeroed region
  int* qcnt   = kcnt + NSEG * NBUCKET;
  int* ntasks = qcnt + NSEG * NBUCKET;   // end of zeroed region
  int* kcur   = ntasks + 1;
  int* qcur   = kcur + NSEG * NBUCKET;
  int* koff   = qcur + NSEG * NBUCKET;
  int* qoff   = koff + NSEG * (NBUCKET + 1);
  int* tasks  = qoff + NSEG * (NBUCKET + 1);
  uint16_t* Wvh = (uint16_t*)(((uintptr_t)(tasks + MAXTASK) + 15) & ~(uintptr_t)15);
  uint16_t* Wvl = Wvh + (size_t)E_ * E_;
  uint16_t* Woh = Wvl + (size_t)E_ * E_;
  uint16_t* Wol = Woh + (size_t)E_ * E_;
  uint16_t* Wqh = Wol + (size_t)E_ * E_;
  uint16_t* Wql = Wqh + (size_t)E_ * E_;
  uint16_t* Wkh = Wql + (size_t)E_ * E_;
  uint16_t* Wkl = Wkh + (size_t)E_ * E_;
  uint16_t* Xqh = Wkl + (size_t)E_ * E_;
  uint16_t* Xql = Xqh + MSZ;
  uint16_t* Xkh = Xql + MSZ;
  uint16_t* Xkl = Xkh + MSZ;
  uint16_t* Lwh = Xkl + MSZ;
  uint16_t* Lwl = Lwh + (size_t)NROUND * DH_ * DH_;

  prep_kernel<<<dim3(3585), 256, 0, stream>>>(
      query, key, Wq, Wk, Wv, Wo, lshW,
      Xqh, Xql, Xkh, Xkl,
      Wqh, Wql, Wkh, Wkl,
      Wvh, Wvl, Woh, Wol, Lwh, Lwl, attn, kcnt);
  proj_mfma<<<dim3(M_ / 128, E_ / 64, 3), 256, 0, stream>>>(
      Xqh, Xql, Xkh, Xkl,
      Wqh, Wql, Wkh, Wkl, bq, bk, Q, K,
      value, Wvh, Wvl, bv, V);
  hash_mfma<<<dim3(M_ * H_ / 128, 4), 256, 0, stream>>>(
      Q, K, Lwh, Lwl, lshb, qh, kh, qcnt, kcnt);
  scan_kernel<<<dim3(2), 1024, 0, stream>>>(kcnt, koff, kcur, qcnt, qoff, qcur,
                                            ntasks, tasks);
  scatter2_kernel<<<dim3(NSEG * T_ / 256, 2), 256, 0, stream>>>(
      kh, qh, kcur, qcur, klist, qlist);
  attn_task<<<dim3(MAXTASK), 256, 0, stream>>>(
      Q, K, V, qlist, qoff, klist, koff, tasks, ntasks, attn);
  mfma_gemm<<<dim3(M_ / 128, E_ / 64), 256, 0, stream>>>(
      attn, Woh, Wol, bo, (float*)d_out, 0, 1);
}

// Round 6
// 239.914 us; speedup vs baseline: 1.5774x; 1.2042x over previous
//
#include <hip/hip_runtime.h>
#include <stdint.h>
#include <math.h>

// ReformerAttention on MI355X — fp32 I/O. B=2,T=2048,E=512,H=8,Dh=64,
// 2 hash rounds, buckets<32 attend.
// Projection row p = logical (b'=p>>11, t'=p&2047); gathers input row (b=p&1, t=p>>1).
//
// 7 launches:
//   prep (fp16 2-way split of query/key/value/Wq/Wk/Wv + bf16 hi/lo Wo, all
//         written in TILED MFMA-fragment order; + lshW split + zero attn/cnt)
//   -> proj_mfma (fused Q,K,V projections, fp16 3-term, tiled operands)
//   -> hash_mfma(+hist) -> scan(+tasks) -> scatter2
//   -> attn_task -> mfma_gemm(out, tiled-B, perm)
//
// r5 lesson (the big one): proj time scaled with blocks/CU (2/CU=53us,
//   3/CU=78us) at <13% on every pipe — per-CU serialized resource. Cause:
//   every operand load read 16 rows at 1-2KB stride = 16 scattered 64B lines
//   per instruction; 2304 load-instr/CU x 16 lines x ~5cy = 185k cy = the
//   measured 78us. Fix: PRE-TILED fragment layout. A-frag(mb,ks,half) /
//   B-frag(nb,ks) are contiguous 1KB blocks, lane-linear (elem = base+lane*8)
//   -> every load is a coalesced 16B/lane burst. Scatter cost moves to prep's
//   one-time writes.
// Tiled layouts (elem offsets, fp16/bf16 units):
//   A[mb][ks][half]: ((mb*32 + ks*2 + half)*64 + lane)*8,
//     lane=(k8&3)*16+(row&15); row=mb*32+half*16+(lane&15), k=ks*32+(lane>>4)*8
//   B[nb][ks]: ((nb*16 + ks)*64 + lane)*8, col=nb*16+(lane&15), k=ks*32+(lane>>4)*8
// Q,K precision scheme (argmax needs fp32-class exactness):
//   x = h + l/4096, h=fp16(x) (|x|<2^-14 flushed to l), l=fp16((x-h)*2^12).
//   hh -> accH; h*l'+l'*h -> accX; C = accH + accX*2^-12. Dropped ll ~2^-24.
//   Verified passing r2-r5 (absmax unchanged vs fp32 kernel). V now uses the
//   same path (was bf16 3-term) — strictly more accurate.
// scan v3 (r3): shfl prefix scans, ONE atomicAdd per wave.
// hash v4 (r4): 3-term fp16 MFMA + in-reg argmax.

#define T_ 2048
#define E_ 512
#define H_ 8
#define DH_ 64
#define B_ 2
#define M_ 4096
#define NROUND 2
#define NBUCKET 32
#define NSEG 32
#define MAXTASK 5120

typedef short v8s __attribute__((ext_vector_type(8)));
typedef _Float16 v8h __attribute__((ext_vector_type(8)));
typedef float v4f __attribute__((ext_vector_type(4)));

__device__ __forceinline__ float bf2f(uint16_t u) {
  union { uint32_t i; float f; } v; v.i = ((uint32_t)u) << 16; return v.f;
}
__device__ __forceinline__ uint16_t f2bf(float f) {
  union { float fv; uint32_t i; } v; v.fv = f;
  uint32_t x = v.i;
  x += 0x7fffu + ((x >> 16) & 1u);   // RN-even
  return (uint16_t)(x >> 16);
}
__device__ __forceinline__ void split8(const float4 a, const float4 b,
                                       v8s& h, v8s& l) {
  const float x[8] = {a.x, a.y, a.z, a.w, b.x, b.y, b.z, b.w};
#pragma unroll
  for (int j = 0; j < 8; j++) {
    const uint16_t hh = f2bf(x[j]);
    h[j] = (short)hh;
    l[j] = (short)f2bf(x[j] - bf2f(hh));
  }
}
// 2-way fp16 split with scaled residual: x = h + l*2^-12, no fp16 subnormals.
__device__ __forceinline__ void split2h8(const float4 a, const float4 b,
                                         v8h& h, v8h& l) {
  const float x[8] = {a.x, a.y, a.z, a.w, b.x, b.y, b.z, b.w};
#pragma unroll
  for (int j = 0; j < 8; j++) {
    const float xv = x[j];
    const _Float16 hh = (fabsf(xv) < 6.1035156e-5f) ? (_Float16)0.0f
                                                    : (_Float16)xv;
    const float r = xv - (float)hh;          // exact (Sterbenz / hh==0)
    h[j] = hh;
    l[j] = (_Float16)(r * 4096.0f);
  }
}

// ---------------------------------------------------------------------------
// prep: staging into tiled fragment layouts.
//   blocks [0,3072)    : query/key/value fp16 split, gathered, TILED
//   blocks [3072,3456) : Wq/Wk/Wv fp16 split, TILED
//   blocks [3456,3584) : Wo bf16 hi/lo split, TILED
//   blocks [3584,4608) : zero attn
//   block  4608        : zero cnt region + lshW fp16 split
// ---------------------------------------------------------------------------
__global__ __launch_bounds__(256) void prep_kernel(
    const float* __restrict__ Xq, const float* __restrict__ Xk,
    const float* __restrict__ Xv,
    const float* __restrict__ Wq, const float* __restrict__ Wk,
    const float* __restrict__ Wv, const float* __restrict__ Wo,
    const float* __restrict__ lshW,
    uint16_t* __restrict__ Xqh, uint16_t* __restrict__ Xql,
    uint16_t* __restrict__ Xkh, uint16_t* __restrict__ Xkl,
    uint16_t* __restrict__ Xvh, uint16_t* __restrict__ Xvl,
    uint16_t* __restrict__ Wqh, uint16_t* __restrict__ Wql,
    uint16_t* __restrict__ Wkh, uint16_t* __restrict__ Wkl,
    uint16_t* __restrict__ Wvh, uint16_t* __restrict__ Wvl,
    uint16_t* __restrict__ Woh, uint16_t* __restrict__ Wol,
    uint16_t* __restrict__ Lwh, uint16_t* __restrict__ Lwl,
    float* __restrict__ attn, int* __restrict__ cnt)
{
  const int bid = blockIdx.x;
  const int tid = threadIdx.x;

  if (bid < 3072) {                      // q/k/v fp16 split (gathered, tiled)
    const int sel = bid >> 10;           // 0=q,1=k,2=v
    const float* X = (sel == 0) ? Xq : (sel == 1) ? Xk : Xv;
    uint16_t* H = (sel == 0) ? Xqh : (sel == 1) ? Xkh : Xvh;
    uint16_t* L = (sel == 0) ? Xql : (sel == 1) ? Xkl : Xvl;
    const int e = ((bid & 1023) * 256 + tid) * 8;   // [0, M_*E_)
    const int p = e >> 9, k = e & 511;
    const long src = ((long)(p & 1) * T_ + (p >> 1)) * E_ + k;
    const float4 a = *(const float4*)(X + src);
    const float4 b = *(const float4*)(X + src + 4);
    v8h h, l;
    split2h8(a, b, h, l);
    // tiled offset: frag(mb=p>>5, ks=k>>5, half=(p>>4)&1), lane=(k>>3&3)*16+(p&15)
    const long to = ((long)((p >> 5) * 32 + (k >> 5) * 2 + ((p >> 4) & 1)) * 64
                     + ((k >> 3) & 3) * 16 + (p & 15)) * 8;
    *(v8h*)(H + to) = h;
    *(v8h*)(L + to) = l;
    return;
  }

  if (bid < 3584) {                      // weight splits, tiled
    const int wsel = (bid - 3072) >> 7;  // 0=Wq,1=Wk,2=Wv,3=Wo
    const int e = (((bid - 3072) & 127) * 256 + tid) * 8;   // [0, E_*E_)
    const int n = e >> 9, k = e & 511;
    const long to = ((long)((n >> 4) * 16 + (k >> 5)) * 64
                     + ((k >> 3) & 3) * 16 + (n & 15)) * 8;
    if (wsel < 3) {
      const float* S = (wsel == 0) ? Wq : (wsel == 1) ? Wk : Wv;
      const float4 a = *(const float4*)(S + e);
      const float4 b = *(const float4*)(S + e + 4);
      v8h h, l;
      split2h8(a, b, h, l);
      uint16_t* H = (wsel == 0) ? Wqh : (wsel == 1) ? Wkh : Wvh;
      uint16_t* L = (wsel == 0) ? Wql : (wsel == 1) ? Wkl : Wvl;
      *(v8h*)(H + to) = h;
      *(v8h*)(L + to) = l;
    } else {
      const float4 a = *(const float4*)(Wo + e);
      const float4 b = *(const float4*)(Wo + e + 4);
      v8s h, l;
      split8(a, b, h, l);
      *(v8s*)(Woh + to) = h;
      *(v8s*)(Wol + to) = l;
    }
    return;
  }

  if (bid < 4608) {                      // zero attn: 1024 blocks x 512 float4
    float4* a4 = (float4*)attn;
    const int g = (bid - 3584) * 512 + tid * 2;
    a4[g] = make_float4(0.f, 0.f, 0.f, 0.f);
    a4[g + 1] = make_float4(0.f, 0.f, 0.f, 0.f);
    return;
  }

  for (int i = tid; i < 2 * NSEG * NBUCKET + 1; i += 256) cnt[i] = 0;
  for (int i = tid; i < NROUND * DH_ * DH_; i += 256) {  // lshW fp16 split
    const float xv = lshW[i];
    const _Float16 hh = (fabsf(xv) < 6.1035156e-5f) ? (_Float16)0.0f
                                                    : (_Float16)xv;
    const float r = xv - (float)hh;
    *(_Float16*)(Lwh + i) = hh;
    *(_Float16*)(Lwl + i) = (_Float16)(r * 4096.0f);
  }
}

// ---------------------------------------------------------------------------
// proj_mfma v6: fused Q/K/V projections, fp16 3-term, TILED operands.
// grid (32, 8, 3) = 768 blocks; 2x4 16x16 tiles/wave (32x64). Every operand
// load is lane-linear 16B (coalesced 1KB/instr). Register double-buffered.
// ---------------------------------------------------------------------------
__global__ __launch_bounds__(256) void proj_mfma(
    const uint16_t* __restrict__ Aqh, const uint16_t* __restrict__ Aql,
    const uint16_t* __restrict__ Akh, const uint16_t* __restrict__ Akl,
    const uint16_t* __restrict__ Avh, const uint16_t* __restrict__ Avl,
    const uint16_t* __restrict__ Bqh, const uint16_t* __restrict__ Bql,
    const uint16_t* __restrict__ Bkh, const uint16_t* __restrict__ Bkl,
    const uint16_t* __restrict__ Bvh, const uint16_t* __restrict__ Bvl,
    const float* __restrict__ bq, const float* __restrict__ bk,
    const float* __restrict__ bv,
    float* __restrict__ Qo, float* __restrict__ Ko, float* __restrict__ Vo)
{
  const uint16_t *Ah, *Al, *Bh, *Bl;
  const float* bias; float* C;
  if (blockIdx.z == 0)      { Ah = Aqh; Al = Aql; Bh = Bqh; Bl = Bql; bias = bq; C = Qo; }
  else if (blockIdx.z == 1) { Ah = Akh; Al = Akl; Bh = Bkh; Bl = Bkl; bias = bk; C = Ko; }
  else                      { Ah = Avh; Al = Avl; Bh = Bvh; Bl = Bvl; bias = bv; C = Vo; }

  const int wid = threadIdx.x >> 6, lane = threadIdx.x & 63;
  const int mb = blockIdx.x * 4 + wid;        // 32-row block
  const int nb0 = blockIdx.y * 4;             // first 16-col block
  const int m0 = mb * 32, n0 = blockIdx.y * 64;
  const int l15 = lane & 15, quad = lane >> 4;

  // tiled bases (fp16 elem units); frag strides: A ks*1024, half 512; B ks*512
  const long aB = (long)mb * 16384 + lane * 8;
  long bB[4];
#pragma unroll
  for (int j = 0; j < 4; j++) bB[j] = (long)(nb0 + j) * 8192 + lane * 8;

  v4f accH[2][4] = {};
  v4f accX[2][4] = {};

  // prologue: ks = 0
  v8h ah0 = *(const v8h*)(Ah + aB);
  v8h ah1 = *(const v8h*)(Ah + aB + 512);
  v8h al0 = *(const v8h*)(Al + aB);
  v8h al1 = *(const v8h*)(Al + aB + 512);
  v8h bh[4], bl[4];
#pragma unroll
  for (int j = 0; j < 4; j++) {
    bh[j] = *(const v8h*)(Bh + bB[j]);
    bl[j] = *(const v8h*)(Bl + bB[j]);
  }

  for (int ks = 0; ks < 16; ks++) {
    const int kn = (ks + 1) & 15;   // wraps on last iter; values unused
    const v8h nah0 = *(const v8h*)(Ah + aB + kn * 1024);
    const v8h nah1 = *(const v8h*)(Ah + aB + kn * 1024 + 512);
    const v8h nal0 = *(const v8h*)(Al + aB + kn * 1024);
    const v8h nal1 = *(const v8h*)(Al + aB + kn * 1024 + 512);
    v8h nbh[4], nbl[4];
#pragma unroll
    for (int j = 0; j < 4; j++) {
      nbh[j] = *(const v8h*)(Bh + bB[j] + kn * 512);
      nbl[j] = *(const v8h*)(Bl + bB[j] + kn * 512);
    }

    // 24 MFMAs: hh -> accH; h*l' and l'*h -> accX (carries 2^12 scale)
#pragma unroll
    for (int j = 0; j < 4; j++) {
      accH[0][j] = __builtin_amdgcn_mfma_f32_16x16x32_f16(ah0, bh[j], accH[0][j], 0, 0, 0);
      accH[1][j] = __builtin_amdgcn_mfma_f32_16x16x32_f16(ah1, bh[j], accH[1][j], 0, 0, 0);
    }
#pragma unroll
    for (int j = 0; j < 4; j++) {
      accX[0][j] = __builtin_amdgcn_mfma_f32_16x16x32_f16(ah0, bl[j], accX[0][j], 0, 0, 0);
      accX[1][j] = __builtin_amdgcn_mfma_f32_16x16x32_f16(ah1, bl[j], accX[1][j], 0, 0, 0);
    }
#pragma unroll
    for (int j = 0; j < 4; j++) {
      accX[0][j] = __builtin_amdgcn_mfma_f32_16x16x32_f16(al0, bh[j], accX[0][j], 0, 0, 0);
      accX[1][j] = __builtin_amdgcn_mfma_f32_16x16x32_f16(al1, bh[j], accX[1][j], 0, 0, 0);
    }

    // rotate
    ah0 = nah0; al0 = nal0; ah1 = nah1; al1 = nal1;
#pragma unroll
    for (int j = 0; j < 4; j++) { bh[j] = nbh[j]; bl[j] = nbl[j]; }
  }

#pragma unroll
  for (int i = 0; i < 2; i++)
#pragma unroll
    for (int j = 0; j < 4; j++) {
      const int colg = n0 + j * 16 + l15;
      const float bb = bias[colg];
#pragma unroll
      for (int r = 0; r < 4; r++) {
        const int mm = m0 + i * 16 + quad * 4 + r;
        C[(long)mm * E_ + colg] =
            accH[i][j][r] + accX[i][j][r] * (1.0f / 4096.0f) + bb;
      }
    }
}

// ---------------------------------------------------------------------------
// mfma_gemm v6 (out-projection only): bf16 3-term, A fp32 row-major split
// in-register, B pre-split bf16 TILED (coalesced). permC write. 256 blocks.
// ---------------------------------------------------------------------------
__global__ __launch_bounds__(256) void mfma_gemm(
    const float* __restrict__ A,
    const uint16_t* __restrict__ Bht, const uint16_t* __restrict__ Blt,
    const float* __restrict__ bias, float* __restrict__ C)
{
  const int wid = threadIdx.x >> 6, lane = threadIdx.x & 63;
  const int m0 = (blockIdx.x * 4 + wid) * 32;
  const int nb0 = blockIdx.y * 4;
  const int n0 = blockIdx.y * 64;
  const int l15 = lane & 15, quad = lane >> 4;

  const long sa0 = (long)(m0 + l15) * E_ + quad * 8;
  const long sa1 = sa0 + 16L * E_;
  long bB[4];
#pragma unroll
  for (int j = 0; j < 4; j++) bB[j] = (long)(nb0 + j) * 8192 + lane * 8;

  v4f acc[2][4] = {};
  for (int ks = 0; ks < 16; ks++) {
    const int k0 = ks * 32;
    v8s ah0, al0, ah1, al1;
    split8(*(const float4*)(A + sa0 + k0), *(const float4*)(A + sa0 + k0 + 4),
           ah0, al0);
    split8(*(const float4*)(A + sa1 + k0), *(const float4*)(A + sa1 + k0 + 4),
           ah1, al1);
    v8s bh[4], bl[4];
#pragma unroll
    for (int j = 0; j < 4; j++) {
      bh[j] = *(const v8s*)(Bht + bB[j] + ks * 512);
      bl[j] = *(const v8s*)(Blt + bB[j] + ks * 512);
    }
#pragma unroll
    for (int j = 0; j < 4; j++) {
      acc[0][j] = __builtin_amdgcn_mfma_f32_16x16x32_bf16(ah0, bh[j], acc[0][j], 0, 0, 0);
      acc[1][j] = __builtin_amdgcn_mfma_f32_16x16x32_bf16(ah1, bh[j], acc[1][j], 0, 0, 0);
    }
#pragma unroll
    for (int j = 0; j < 4; j++) {
      acc[0][j] = __builtin_amdgcn_mfma_f32_16x16x32_bf16(ah0, bl[j], acc[0][j], 0, 0, 0);
      acc[1][j] = __builtin_amdgcn_mfma_f32_16x16x32_bf16(ah1, bl[j], acc[1][j], 0, 0, 0);
    }
#pragma unroll
    for (int j = 0; j < 4; j++) {
      acc[0][j] = __builtin_amdgcn_mfma_f32_16x16x32_bf16(al0, bh[j], acc[0][j], 0, 0, 0);
      acc[1][j] = __builtin_amdgcn_mfma_f32_16x16x32_bf16(al1, bh[j], acc[1][j], 0, 0, 0);
    }
  }

#pragma unroll
  for (int i = 0; i < 2; i++)
#pragma unroll
    for (int j = 0; j < 4; j++) {
      const int colg = n0 + j * 16 + l15;
      const float bb = bias[colg];
#pragma unroll
      for (int r = 0; r < 4; r++) {
        const int mm = m0 + i * 16 + quad * 4 + r;
        const int crow = (mm & (T_ - 1)) * B_ + (mm >> 11);
        C[(long)crow * E_ + colg] = acc[i][j][r] + bb;
      }
    }
}

// ---------------------------------------------------------------------------
// hash_mfma v4: LSH hash as 3-term fp16 MFMA GEMM + in-register argmax.
// grid (256, 4): y = src*2 + r; 256 thr; wave does 32 rows (2x4 tiles, K=64).
// ---------------------------------------------------------------------------
__global__ __launch_bounds__(256) void hash_mfma(
    const float* __restrict__ Q, const float* __restrict__ K,
    const uint16_t* __restrict__ Lwh, const uint16_t* __restrict__ Lwl,
    const float* __restrict__ lshb,
    int* __restrict__ qh, int* __restrict__ kh,
    int* __restrict__ qcnt, int* __restrict__ kcnt)
{
  const int comb = blockIdx.y;               // 0..3
  const int src = comb >> 1, r = comb & 1;
  const float* X = src ? K : Q;
  int* outh = src ? kh : qh;
  int* cnt  = src ? kcnt : qcnt;

  const int wid = threadIdx.x >> 6, lane = threadIdx.x & 63;
  const int m0 = (blockIdx.x * 4 + wid) * 32;  // head-row base (32 rows/wave)
  const int l15 = lane & 15, quad = lane >> 4;

  v8h bh[4][2], bl[4][2];
#pragma unroll
  for (int n = 0; n < 4; n++)
#pragma unroll
    for (int k = 0; k < 2; k++) {
      const int o = r * (DH_ * DH_) + (n * 16 + l15) * DH_ + k * 32 + quad * 8;
      bh[n][k] = *(const v8h*)(Lwh + o);
      bl[n][k] = *(const v8h*)(Lwl + o);
    }

  v4f accH[2][4] = {};
  v4f accX[2][4] = {};
#pragma unroll
  for (int k = 0; k < 2; k++) {
    const long a0 = (long)(m0 + l15) * DH_ + k * 32 + quad * 8;
    const long a1 = a0 + 16L * DH_;
    v8h ah0, al0, ah1, al1;
    split2h8(*(const float4*)(X + a0), *(const float4*)(X + a0 + 4), ah0, al0);
    split2h8(*(const float4*)(X + a1), *(const float4*)(X + a1 + 4), ah1, al1);
#pragma unroll
    for (int n = 0; n < 4; n++) {
      accH[0][n] = __builtin_amdgcn_mfma_f32_16x16x32_f16(ah0, bh[n][k], accH[0][n], 0, 0, 0);
      accH[1][n] = __builtin_amdgcn_mfma_f32_16x16x32_f16(ah1, bh[n][k], accH[1][n], 0, 0, 0);
      accX[0][n] = __builtin_amdgcn_mfma_f32_16x16x32_f16(ah0, bl[n][k], accX[0][n], 0, 0, 0);
      accX[1][n] = __builtin_amdgcn_mfma_f32_16x16x32_f16(ah1, bl[n][k], accX[1][n], 0, 0, 0);
      accX[0][n] = __builtin_amdgcn_mfma_f32_16x16x32_f16(al0, bh[n][k], accX[0][n], 0, 0, 0);
      accX[1][n] = __builtin_amdgcn_mfma_f32_16x16x32_f16(al1, bh[n][k], accX[1][n], 0, 0, 0);
    }
  }

  float bb[4];
#pragma unroll
  for (int n = 0; n < 4; n++) bb[n] = lshb[r * DH_ + n * 16 + l15];

#pragma unroll
  for (int i = 0; i < 2; i++)
#pragma unroll
    for (int reg = 0; reg < 4; reg++) {
      float bv = -INFINITY; int bi = 0x7fffffff;
#pragma unroll
      for (int n = 0; n < 4; n++) {
        const float v = accH[i][n][reg] + accX[i][n][reg] * (1.0f / 4096.0f)
                        + bb[n];
        const int idx = n * 16 + l15;
        if (v > bv || (v == bv && idx < bi)) { bv = v; bi = idx; }
      }
#pragma unroll
      for (int d = 8; d >= 1; d >>= 1) {
        const float ov = __shfl_xor(bv, d);
        const int oi = __shfl_xor(bi, d);
        if (ov > bv || (ov == bv && oi < bi)) { bv = ov; bi = oi; }
      }
      if (l15 == 0) {
        const int hr = m0 + i * 16 + quad * 4 + reg;
        const int p = hr >> 3, hh = hr & 7;
        const int bt = p >> 11, t = p & (T_ - 1);
        const int seg = r * 16 + bt * H_ + hh;
        outh[seg * T_ + t] = bi;
        if (bi < NBUCKET) atomicAdd(&cnt[seg * NBUCKET + bi], 1);
      }
    }
}

// ---------------------------------------------------------------------------
// Scan v3: 2 blocks x 1024 threads; one thread per (seg,bucket).
// ---------------------------------------------------------------------------
__global__ __launch_bounds__(1024) void scan_kernel(
    const int* __restrict__ kcnt, int* __restrict__ koff,
    int* __restrict__ kcur,
    const int* __restrict__ qcnt, int* __restrict__ qoff,
    int* __restrict__ qcur,
    int* __restrict__ ntasks, int* __restrict__ tasks)
{
  const int tid = threadIdx.x;          // 0..1023
  const int isq = blockIdx.x;           // 0 = k-side, 1 = q-side
  const int seg = tid >> 5;             // 0..31
  const int b   = tid & 31;             // bucket
  const int* cnt = isq ? qcnt : kcnt;
  int* off = isq ? qoff : koff;
  int* cur = isq ? qcur : kcur;

  const int c = cnt[seg * NBUCKET + b];

  int s = c;
#pragma unroll
  for (int d = 1; d < 32; d <<= 1) {
    const int t = __shfl_up(s, d, 32);
    if (b >= d) s += t;
  }
  const int excl = s - c;
  off[seg * (NBUCKET + 1) + b] = excl;
  cur[seg * NBUCKET + b] = excl;
  if (b == 31) off[seg * (NBUCKET + 1) + NBUCKET] = s;

  if (isq) {
    const int nt = (c + 15) >> 4;
    const int lane = tid & 63;
    int ws = nt;
#pragma unroll
    for (int d = 1; d < 64; d <<= 1) {
      const int t = __shfl_up(ws, d, 64);
      if (lane >= d) ws += t;
    }
    const int wtotal = __shfl(ws, 63, 64);
    int base = 0;
    if (lane == 63 && wtotal > 0) base = atomicAdd(ntasks, wtotal);
    base = __shfl(base, 63, 64);
    const int my = base + ws - nt;
    for (int i = 0; i < nt; i++)
      tasks[my + i] = (seg << 16) | (b << 8) | i;
  }
}

__global__ __launch_bounds__(256) void scatter2_kernel(
    const int* __restrict__ kh, const int* __restrict__ qh,
    int* __restrict__ kcur, int* __restrict__ qcur,
    int* __restrict__ klist, int* __restrict__ qlist)
{
  const int idx = blockIdx.x * 256 + threadIdx.x;
  const int y = blockIdx.y;
  const int* hsh = y ? qh : kh;
  int* cur = y ? qcur : kcur;
  int* list = y ? qlist : klist;
  const int v = hsh[idx];
  if (v < NBUCKET) {
    const int seg = idx >> 11;
    const int pos = atomicAdd(&cur[seg * NBUCKET + v], 1);
    list[seg * T_ + pos] = idx & (T_ - 1);
  }
}

// ---------------------------------------------------------------------------
// Task-parallel dense bucket attention (unchanged — proven).
// ---------------------------------------------------------------------------
__global__ __launch_bounds__(256) void attn_task(
    const float* __restrict__ Q, const float* __restrict__ K,
    const float* __restrict__ V,
    const int* __restrict__ qlist, const int* __restrict__ qoff,
    const int* __restrict__ klist, const int* __restrict__ koff,
    const int* __restrict__ tasks, const int* __restrict__ ntasks,
    float* __restrict__ attn)
{
  __shared__ __align__(16) float QPs[16 * 68];
  __shared__ __align__(16) float Ks[64 * 68];
  __shared__ __align__(16) float Vs[64 * 68];

  if ((int)blockIdx.x >= *ntasks) return;
  const int tk = tasks[blockIdx.x];
  const int seg = tk >> 16, bucket = (tk >> 8) & 255, qt = tk & 255;
  const int ctx = seg & 15;
  const int b = ctx >> 3, h = ctx & 7;

  const int qlo = qoff[seg * (NBUCKET + 1) + bucket] + qt * 16;
  const int nqt = min(16, qoff[seg * (NBUCKET + 1) + bucket + 1] - qlo);
  const int klo = koff[seg * (NBUCKET + 1) + bucket];
  const int nk  = koff[seg * (NBUCKET + 1) + bucket + 1] - klo;
  if (nk == 0) return;

  const int tid = threadIdx.x;
  const int qrow = tid >> 4, col = tid & 15;
  const float* Qb = Q + ((long)b * T_) * E_ + h * DH_;
  const float* Kb = K + ((long)b * T_) * E_ + h * DH_;
  const float* Vb = V + ((long)b * T_) * E_ + h * DH_;
  const int* ql = qlist + seg * T_;
  const int* kl = klist + seg * T_;

  {
    float4 v = make_float4(0.f, 0.f, 0.f, 0.f);
    if (qrow < nqt) v = *(const float4*)(Qb + (long)ql[qlo + qrow] * E_ + col * 4);
    *(float4*)&QPs[qrow * 68 + col * 4] = v;
  }
  __syncthreads();
  float4 qreg[16];
#pragma unroll
  for (int i = 0; i < 16; i++) qreg[i] = *(const float4*)&QPs[qrow * 68 + i * 4];

  float l = 0.f;
  float4 o = make_float4(0.f, 0.f, 0.f, 0.f);

  for (int kt = 0; kt < nk; kt += 64) {
    const int nkt = min(64, nk - kt);
    __syncthreads();
#pragma unroll
    for (int it = 0; it < 4; it++) {
      const int fidx = it * 256 + tid;
      const int row = fidx >> 4, c4 = fidx & 15;
      if (row < nkt) {
        const long src = (long)kl[klo + kt + row] * E_ + c4 * 4;
        *(float4*)&Ks[row * 68 + c4 * 4] = *(const float4*)(Kb + src);
        *(float4*)&Vs[row * 68 + c4 * 4] = *(const float4*)(Vb + src);
      } else {
        *(float4*)&Vs[row * 68 + c4 * 4] = make_float4(0.f, 0.f, 0.f, 0.f);
      }
    }
    __syncthreads();
#pragma unroll
    for (int kk = 0; kk < 4; kk++) {
      const int k = kk * 16 + col;
      float p = 0.f;
      if (k < nkt) {
        const float* kp = &Ks[k * 68];
        float s = 0.f;
#pragma unroll
        for (int d4 = 0; d4 < 16; d4++) {
          const float4 c = *(const float4*)(kp + d4 * 4);
          s += qreg[d4].x * c.x + qreg[d4].y * c.y +
               qreg[d4].z * c.z + qreg[d4].w * c.w;
        }
        p = __expf(s * 0.125f);
      }
      QPs[qrow * 68 + k] = p;
    }
    __syncthreads();
    const int nk4 = (nkt + 3) >> 2;
#pragma unroll 2
    for (int k4 = 0; k4 < nk4; k4++) {
      const float4 pk = *(const float4*)&QPs[qrow * 68 + k4 * 4];
      const float4 v0 = *(const float4*)&Vs[(k4 * 4 + 0) * 68 + col * 4];
      const float4 v1 = *(const float4*)&Vs[(k4 * 4 + 1) * 68 + col * 4];
      const float4 v2 = *(const float4*)&Vs[(k4 * 4 + 2) * 68 + col * 4];
      const float4 v3 = *(const float4*)&Vs[(k4 * 4 + 3) * 68 + col * 4];
      l += (pk.x + pk.y) + (pk.z + pk.w);
      o.x += pk.x * v0.x + pk.y * v1.x + pk.z * v2.x + pk.w * v3.x;
      o.y += pk.x * v0.y + pk.y * v1.y + pk.z * v2.y + pk.w * v3.y;
      o.z += pk.x * v0.z + pk.y * v1.z + pk.z * v2.z + pk.w * v3.z;
      o.w += pk.x * v0.w + pk.y * v1.w + pk.z * v2.w + pk.w * v3.w;
    }
  }

  if (qrow < nqt) {
    const float inv = 0.5f / l;
    const int t = ql[qlo + qrow];
    float* op = attn + ((long)b * T_ + t) * E_ + h * DH_ + col * 4;
    atomicAdd(op + 0, o.x * inv);
    atomicAdd(op + 1, o.y * inv);
    atomicAdd(op + 2, o.z * inv);
    atomicAdd(op + 3, o.w * inv);
  }
}

// ---------------------------------------------------------------------------
extern "C" void kernel_launch(void* const* d_in, const int* in_sizes, int n_in,
                              void* d_out, int out_size, void* d_ws, size_t ws_size,
                              hipStream_t stream) {
  const float* query = (const float*)d_in[0];
  const float* key   = (const float*)d_in[1];
  const float* value = (const float*)d_in[2];
  const float* Wq = (const float*)d_in[3];
  const float* bq = (const float*)d_in[4];
  const float* Wk = (const float*)d_in[5];
  const float* bk = (const float*)d_in[6];
  const float* Wv = (const float*)d_in[7];
  const float* bv = (const float*)d_in[8];
  const float* Wo = (const float*)d_in[9];
  const float* bo = (const float*)d_in[10];
  const float* lshW = (const float*)d_in[11];
  const float* lshb = (const float*)d_in[12];

  const size_t MSZ = (size_t)M_ * E_;
  const size_t WSZ = (size_t)E_ * E_;
  float* Q    = (float*)d_ws;
  float* K    = Q + MSZ;
  float* V    = K + MSZ;
  float* attn = V + MSZ;
  int* qh     = (int*)(attn + MSZ);
  int* kh     = qh + NSEG * T_;
  int* klist  = kh + NSEG * T_;
  int* qlist  = klist + NSEG * T_;
  int* kcnt   = qlist + NSEG * T_;       // start of zeroed region
  int* qcnt   = kcnt + NSEG * NBUCKET;
  int* ntasks = qcnt + NSEG * NBUCKET;   // end of zeroed region
  int* kcur   = ntasks + 1;
  int* qcur   = kcur + NSEG * NBUCKET;
  int* koff   = qcur + NSEG * NBUCKET;
  int* qoff   = koff + NSEG * (NBUCKET + 1);
  int* tasks  = qoff + NSEG * (NBUCKET + 1);
  uint16_t* Woh = (uint16_t*)(((uintptr_t)(tasks + MAXTASK) + 15) & ~(uintptr_t)15);
  uint16_t* Wol = Woh + WSZ;
  uint16_t* Wqh = Wol + WSZ;
  uint16_t* Wql = Wqh + WSZ;
  uint16_t* Wkh = Wql + WSZ;
  uint16_t* Wkl = Wkh + WSZ;
  uint16_t* Wvh = Wkl + WSZ;
  uint16_t* Wvl = Wvh + WSZ;
  uint16_t* Xqh = Wvl + WSZ;
  uint16_t* Xql = Xqh + MSZ;
  uint16_t* Xkh = Xql + MSZ;
  uint16_t* Xkl = Xkh + MSZ;
  uint16_t* Xvh = Xkl + MSZ;
  uint16_t* Xvl = Xvh + MSZ;
  uint16_t* Lwh = Xvl + MSZ;
  uint16_t* Lwl = Lwh + (size_t)NROUND * DH_ * DH_;

  prep_kernel<<<dim3(4609), 256, 0, stream>>>(
      query, key, value, Wq, Wk, Wv, Wo, lshW,
      Xqh, Xql, Xkh, Xkl, Xvh, Xvl,
      Wqh, Wql, Wkh, Wkl, Wvh, Wvl, Woh, Wol,
      Lwh, Lwl, attn, kcnt);
  proj_mfma<<<dim3(M_ / 128, E_ / 64, 3), 256, 0, stream>>>(
      Xqh, Xql, Xkh, Xkl, Xvh, Xvl,
      Wqh, Wql, Wkh, Wkl, Wvh, Wvl,
      bq, bk, bv, Q, K, V);
  hash_mfma<<<dim3(M_ * H_ / 128, 4), 256, 0, stream>>>(
      Q, K, Lwh, Lwl, lshb, qh, kh, qcnt, kcnt);
  scan_kernel<<<dim3(2), 1024, 0, stream>>>(kcnt, koff, kcur, qcnt, qoff, qcur,
                                            ntasks, tasks);
  scatter2_kernel<<<dim3(NSEG * T_ / 256, 2), 256, 0, stream>>>(
      kh, qh, kcur, qcur, klist, qlist);
  attn_task<<<dim3(MAXTASK), 256, 0, stream>>>(
      Q, K, V, qlist, qoff, klist, koff, tasks, ntasks, attn);
  mfma_gemm<<<dim3(M_ / 128, E_ / 64), 256, 0, stream>>>(
      attn, Woh, Wol, bo, (float*)d_out);
}

// Round 7
// 223.866 us; speedup vs baseline: 1.6905x; 1.0717x over previous
//
#include <hip/hip_runtime.h>
#include <stdint.h>
#include <math.h>

// ReformerAttention on MI355X — fp32 I/O. B=2,T=2048,E=512,H=8,Dh=64,
// 2 hash rounds, buckets<32 attend.
// Projection row p = logical (b'=p>>11, t'=p&2047); gathers input row (b=p&1, t=p>>1).
//
// 7 launches:
//   prep (fp16 2-way split of query/key/value/Wq/Wk/Wv + bf16 hi/lo Wo, all
//         written in TILED MFMA-fragment order; + lshW split + zero attn/cnt)
//   -> proj_mfma (fused Q,K,V projections, fp16 3-term, tiled operands)
//   -> hash_mfma(+hist) -> scan(+tasks) -> scatter2
//   -> attn_task (MFMA, v7) -> mfma_gemm(out, tiled-B, perm)
//
// r6 lessons: tiled fragment layout fixed proj (address divergence was the
//   per-CU serialized resource — 16 lines/load-instr). fillBufferAligned
//   (256MiB harness workspace zero, ~44us) is NOT ours — controllable budget
//   ~195us. attn_task 45us @ VALU 21 / MFMA 0 / occ 21% — an LDS+VALU dot
//   machine: ~150KB LDS traffic per wave per 64-key tile (scores re-read K
//   16x, PV re-reads V). v7: MFMA wave-split rewrite —
//   QK^T: wave owns 16 keys, K frags direct from global (read once), Q in
//   regs (bf16 hi/lo 3-term, = passing error class); exp + shfl row-sums +
//   LDS-atomic denominators; P (4.3KB) + V-transposed (17.4KB) in LDS;
//   PV: wave owns 16 dims, persistent 16x16 acc, P/Vt bf16 3-term.
//   12 MFMA/wave/tile replaces ~550 VALU + ~130 ds_read_b128. LDS 39->22KB.
// Q,K precision scheme (argmax needs fp32-class exactness):
//   x = h + l/4096, h=fp16(x) (|x|<2^-14 flushed), l=fp16((x-h)*2^12).
//   hh -> accH; h*l'+l'*h -> accX; C = accH + accX*2^-12. Verified r2-r6.
// scan v3 (r3): shfl prefix scans, ONE atomicAdd per wave.
// hash v4 (r4): 3-term fp16 MFMA + in-reg argmax.

#define T_ 2048
#define E_ 512
#define H_ 8
#define DH_ 64
#define B_ 2
#define M_ 4096
#define NROUND 2
#define NBUCKET 32
#define NSEG 32
#define MAXTASK 5120

typedef short v8s __attribute__((ext_vector_type(8)));
typedef _Float16 v8h __attribute__((ext_vector_type(8)));
typedef float v4f __attribute__((ext_vector_type(4)));

__device__ __forceinline__ float bf2f(uint16_t u) {
  union { uint32_t i; float f; } v; v.i = ((uint32_t)u) << 16; return v.f;
}
__device__ __forceinline__ uint16_t f2bf(float f) {
  union { float fv; uint32_t i; } v; v.fv = f;
  uint32_t x = v.i;
  x += 0x7fffu + ((x >> 16) & 1u);   // RN-even
  return (uint16_t)(x >> 16);
}
__device__ __forceinline__ void split8(const float4 a, const float4 b,
                                       v8s& h, v8s& l) {
  const float x[8] = {a.x, a.y, a.z, a.w, b.x, b.y, b.z, b.w};
#pragma unroll
  for (int j = 0; j < 8; j++) {
    const uint16_t hh = f2bf(x[j]);
    h[j] = (short)hh;
    l[j] = (short)f2bf(x[j] - bf2f(hh));
  }
}
// 2-way fp16 split with scaled residual: x = h + l*2^-12, no fp16 subnormals.
__device__ __forceinline__ void split2h8(const float4 a, const float4 b,
                                         v8h& h, v8h& l) {
  const float x[8] = {a.x, a.y, a.z, a.w, b.x, b.y, b.z, b.w};
#pragma unroll
  for (int j = 0; j < 8; j++) {
    const float xv = x[j];
    const _Float16 hh = (fabsf(xv) < 6.1035156e-5f) ? (_Float16)0.0f
                                                    : (_Float16)xv;
    const float r = xv - (float)hh;          // exact (Sterbenz / hh==0)
    h[j] = hh;
    l[j] = (_Float16)(r * 4096.0f);
  }
}

// ---------------------------------------------------------------------------
// prep: staging into tiled fragment layouts.
//   blocks [0,3072)    : query/key/value fp16 split, gathered, TILED
//   blocks [3072,3456) : Wq/Wk/Wv fp16 split, TILED
//   blocks [3456,3584) : Wo bf16 hi/lo split, TILED
//   blocks [3584,4608) : zero attn
//   block  4608        : zero cnt region + lshW fp16 split
// ---------------------------------------------------------------------------
__global__ __launch_bounds__(256) void prep_kernel(
    const float* __restrict__ Xq, const float* __restrict__ Xk,
    const float* __restrict__ Xv,
    const float* __restrict__ Wq, const float* __restrict__ Wk,
    const float* __restrict__ Wv, const float* __restrict__ Wo,
    const float* __restrict__ lshW,
    uint16_t* __restrict__ Xqh, uint16_t* __restrict__ Xql,
    uint16_t* __restrict__ Xkh, uint16_t* __restrict__ Xkl,
    uint16_t* __restrict__ Xvh, uint16_t* __restrict__ Xvl,
    uint16_t* __restrict__ Wqh, uint16_t* __restrict__ Wql,
    uint16_t* __restrict__ Wkh, uint16_t* __restrict__ Wkl,
    uint16_t* __restrict__ Wvh, uint16_t* __restrict__ Wvl,
    uint16_t* __restrict__ Woh, uint16_t* __restrict__ Wol,
    uint16_t* __restrict__ Lwh, uint16_t* __restrict__ Lwl,
    float* __restrict__ attn, int* __restrict__ cnt)
{
  const int bid = blockIdx.x;
  const int tid = threadIdx.x;

  if (bid < 3072) {                      // q/k/v fp16 split (gathered, tiled)
    const int sel = bid >> 10;           // 0=q,1=k,2=v
    const float* X = (sel == 0) ? Xq : (sel == 1) ? Xk : Xv;
    uint16_t* H = (sel == 0) ? Xqh : (sel == 1) ? Xkh : Xvh;
    uint16_t* L = (sel == 0) ? Xql : (sel == 1) ? Xkl : Xvl;
    const int e = ((bid & 1023) * 256 + tid) * 8;   // [0, M_*E_)
    const int p = e >> 9, k = e & 511;
    const long src = ((long)(p & 1) * T_ + (p >> 1)) * E_ + k;
    const float4 a = *(const float4*)(X + src);
    const float4 b = *(const float4*)(X + src + 4);
    v8h h, l;
    split2h8(a, b, h, l);
    // tiled offset: frag(mb=p>>5, ks=k>>5, half=(p>>4)&1), lane=(k>>3&3)*16+(p&15)
    const long to = ((long)((p >> 5) * 32 + (k >> 5) * 2 + ((p >> 4) & 1)) * 64
                     + ((k >> 3) & 3) * 16 + (p & 15)) * 8;
    *(v8h*)(H + to) = h;
    *(v8h*)(L + to) = l;
    return;
  }

  if (bid < 3584) {                      // weight splits, tiled
    const int wsel = (bid - 3072) >> 7;  // 0=Wq,1=Wk,2=Wv,3=Wo
    const int e = (((bid - 3072) & 127) * 256 + tid) * 8;   // [0, E_*E_)
    const int n = e >> 9, k = e & 511;
    const long to = ((long)((n >> 4) * 16 + (k >> 5)) * 64
                     + ((k >> 3) & 3) * 16 + (n & 15)) * 8;
    if (wsel < 3) {
      const float* S = (wsel == 0) ? Wq : (wsel == 1) ? Wk : Wv;
      const float4 a = *(const float4*)(S + e);
      const float4 b = *(const float4*)(S + e + 4);
      v8h h, l;
      split2h8(a, b, h, l);
      uint16_t* H = (wsel == 0) ? Wqh : (wsel == 1) ? Wkh : Wvh;
      uint16_t* L = (wsel == 0) ? Wql : (wsel == 1) ? Wkl : Wvl;
      *(v8h*)(H + to) = h;
      *(v8h*)(L + to) = l;
    } else {
      const float4 a = *(const float4*)(Wo + e);
      const float4 b = *(const float4*)(Wo + e + 4);
      v8s h, l;
      split8(a, b, h, l);
      *(v8s*)(Woh + to) = h;
      *(v8s*)(Wol + to) = l;
    }
    return;
  }

  if (bid < 4608) {                      // zero attn: 1024 blocks x 512 float4
    float4* a4 = (float4*)attn;
    const int g = (bid - 3584) * 512 + tid * 2;
    a4[g] = make_float4(0.f, 0.f, 0.f, 0.f);
    a4[g + 1] = make_float4(0.f, 0.f, 0.f, 0.f);
    return;
  }

  for (int i = tid; i < 2 * NSEG * NBUCKET + 1; i += 256) cnt[i] = 0;
  for (int i = tid; i < NROUND * DH_ * DH_; i += 256) {  // lshW fp16 split
    const float xv = lshW[i];
    const _Float16 hh = (fabsf(xv) < 6.1035156e-5f) ? (_Float16)0.0f
                                                    : (_Float16)xv;
    const float r = xv - (float)hh;
    *(_Float16*)(Lwh + i) = hh;
    *(_Float16*)(Lwl + i) = (_Float16)(r * 4096.0f);
  }
}

// ---------------------------------------------------------------------------
// proj_mfma v6: fused Q/K/V projections, fp16 3-term, TILED operands.
// grid (32, 8, 3) = 768 blocks; 2x4 16x16 tiles/wave (32x64). Every operand
// load is lane-linear 16B (coalesced 1KB/instr). Register double-buffered.
// ---------------------------------------------------------------------------
__global__ __launch_bounds__(256) void proj_mfma(
    const uint16_t* __restrict__ Aqh, const uint16_t* __restrict__ Aql,
    const uint16_t* __restrict__ Akh, const uint16_t* __restrict__ Akl,
    const uint16_t* __restrict__ Avh, const uint16_t* __restrict__ Avl,
    const uint16_t* __restrict__ Bqh, const uint16_t* __restrict__ Bql,
    const uint16_t* __restrict__ Bkh, const uint16_t* __restrict__ Bkl,
    const uint16_t* __restrict__ Bvh, const uint16_t* __restrict__ Bvl,
    const float* __restrict__ bq, const float* __restrict__ bk,
    const float* __restrict__ bv,
    float* __restrict__ Qo, float* __restrict__ Ko, float* __restrict__ Vo)
{
  const uint16_t *Ah, *Al, *Bh, *Bl;
  const float* bias; float* C;
  if (blockIdx.z == 0)      { Ah = Aqh; Al = Aql; Bh = Bqh; Bl = Bql; bias = bq; C = Qo; }
  else if (blockIdx.z == 1) { Ah = Akh; Al = Akl; Bh = Bkh; Bl = Bkl; bias = bk; C = Ko; }
  else                      { Ah = Avh; Al = Avl; Bh = Bvh; Bl = Bvl; bias = bv; C = Vo; }

  const int wid = threadIdx.x >> 6, lane = threadIdx.x & 63;
  const int mb = blockIdx.x * 4 + wid;        // 32-row block
  const int nb0 = blockIdx.y * 4;             // first 16-col block
  const int m0 = mb * 32, n0 = blockIdx.y * 64;
  const int l15 = lane & 15, quad = lane >> 4;

  // tiled bases (fp16 elem units); frag strides: A ks*1024, half 512; B ks*512
  const long aB = (long)mb * 16384 + lane * 8;
  long bB[4];
#pragma unroll
  for (int j = 0; j < 4; j++) bB[j] = (long)(nb0 + j) * 8192 + lane * 8;

  v4f accH[2][4] = {};
  v4f accX[2][4] = {};

  // prologue: ks = 0
  v8h ah0 = *(const v8h*)(Ah + aB);
  v8h ah1 = *(const v8h*)(Ah + aB + 512);
  v8h al0 = *(const v8h*)(Al + aB);
  v8h al1 = *(const v8h*)(Al + aB + 512);
  v8h bh[4], bl[4];
#pragma unroll
  for (int j = 0; j < 4; j++) {
    bh[j] = *(const v8h*)(Bh + bB[j]);
    bl[j] = *(const v8h*)(Bl + bB[j]);
  }

  for (int ks = 0; ks < 16; ks++) {
    const int kn = (ks + 1) & 15;   // wraps on last iter; values unused
    const v8h nah0 = *(const v8h*)(Ah + aB + kn * 1024);
    const v8h nah1 = *(const v8h*)(Ah + aB + kn * 1024 + 512);
    const v8h nal0 = *(const v8h*)(Al + aB + kn * 1024);
    const v8h nal1 = *(const v8h*)(Al + aB + kn * 1024 + 512);
    v8h nbh[4], nbl[4];
#pragma unroll
    for (int j = 0; j < 4; j++) {
      nbh[j] = *(const v8h*)(Bh + bB[j] + kn * 512);
      nbl[j] = *(const v8h*)(Bl + bB[j] + kn * 512);
    }

    // 24 MFMAs: hh -> accH; h*l' and l'*h -> accX (carries 2^12 scale)
#pragma unroll
    for (int j = 0; j < 4; j++) {
      accH[0][j] = __builtin_amdgcn_mfma_f32_16x16x32_f16(ah0, bh[j], accH[0][j], 0, 0, 0);
      accH[1][j] = __builtin_amdgcn_mfma_f32_16x16x32_f16(ah1, bh[j], accH[1][j], 0, 0, 0);
    }
#pragma unroll
    for (int j = 0; j < 4; j++) {
      accX[0][j] = __builtin_amdgcn_mfma_f32_16x16x32_f16(ah0, bl[j], accX[0][j], 0, 0, 0);
      accX[1][j] = __builtin_amdgcn_mfma_f32_16x16x32_f16(ah1, bl[j], accX[1][j], 0, 0, 0);
    }
#pragma unroll
    for (int j = 0; j < 4; j++) {
      accX[0][j] = __builtin_amdgcn_mfma_f32_16x16x32_f16(al0, bh[j], accX[0][j], 0, 0, 0);
      accX[1][j] = __builtin_amdgcn_mfma_f32_16x16x32_f16(al1, bh[j], accX[1][j], 0, 0, 0);
    }

    // rotate
    ah0 = nah0; al0 = nal0; ah1 = nah1; al1 = nal1;
#pragma unroll
    for (int j = 0; j < 4; j++) { bh[j] = nbh[j]; bl[j] = nbl[j]; }
  }

#pragma unroll
  for (int i = 0; i < 2; i++)
#pragma unroll
    for (int j = 0; j < 4; j++) {
      const int colg = n0 + j * 16 + l15;
      const float bb = bias[colg];
#pragma unroll
      for (int r = 0; r < 4; r++) {
        const int mm = m0 + i * 16 + quad * 4 + r;
        C[(long)mm * E_ + colg] =
            accH[i][j][r] + accX[i][j][r] * (1.0f / 4096.0f) + bb;
      }
    }
}

// ---------------------------------------------------------------------------
// mfma_gemm v6 (out-projection only): bf16 3-term, A fp32 row-major split
// in-register, B pre-split bf16 TILED (coalesced). permC write. 256 blocks.
// ---------------------------------------------------------------------------
__global__ __launch_bounds__(256) void mfma_gemm(
    const float* __restrict__ A,
    const uint16_t* __restrict__ Bht, const uint16_t* __restrict__ Blt,
    const float* __restrict__ bias, float* __restrict__ C)
{
  const int wid = threadIdx.x >> 6, lane = threadIdx.x & 63;
  const int m0 = (blockIdx.x * 4 + wid) * 32;
  const int nb0 = blockIdx.y * 4;
  const int n0 = blockIdx.y * 64;
  const int l15 = lane & 15, quad = lane >> 4;

  const long sa0 = (long)(m0 + l15) * E_ + quad * 8;
  const long sa1 = sa0 + 16L * E_;
  long bB[4];
#pragma unroll
  for (int j = 0; j < 4; j++) bB[j] = (long)(nb0 + j) * 8192 + lane * 8;

  v4f acc[2][4] = {};
  for (int ks = 0; ks < 16; ks++) {
    const int k0 = ks * 32;
    v8s ah0, al0, ah1, al1;
    split8(*(const float4*)(A + sa0 + k0), *(const float4*)(A + sa0 + k0 + 4),
           ah0, al0);
    split8(*(const float4*)(A + sa1 + k0), *(const float4*)(A + sa1 + k0 + 4),
           ah1, al1);
    v8s bh[4], bl[4];
#pragma unroll
    for (int j = 0; j < 4; j++) {
      bh[j] = *(const v8s*)(Bht + bB[j] + ks * 512);
      bl[j] = *(const v8s*)(Blt + bB[j] + ks * 512);
    }
#pragma unroll
    for (int j = 0; j < 4; j++) {
      acc[0][j] = __builtin_amdgcn_mfma_f32_16x16x32_bf16(ah0, bh[j], acc[0][j], 0, 0, 0);
      acc[1][j] = __builtin_amdgcn_mfma_f32_16x16x32_bf16(ah1, bh[j], acc[1][j], 0, 0, 0);
    }
#pragma unroll
    for (int j = 0; j < 4; j++) {
      acc[0][j] = __builtin_amdgcn_mfma_f32_16x16x32_bf16(ah0, bl[j], acc[0][j], 0, 0, 0);
      acc[1][j] = __builtin_amdgcn_mfma_f32_16x16x32_bf16(ah1, bl[j], acc[1][j], 0, 0, 0);
    }
#pragma unroll
    for (int j = 0; j < 4; j++) {
      acc[0][j] = __builtin_amdgcn_mfma_f32_16x16x32_bf16(al0, bh[j], acc[0][j], 0, 0, 0);
      acc[1][j] = __builtin_amdgcn_mfma_f32_16x16x32_bf16(al1, bh[j], acc[1][j], 0, 0, 0);
    }
  }

#pragma unroll
  for (int i = 0; i < 2; i++)
#pragma unroll
    for (int j = 0; j < 4; j++) {
      const int colg = n0 + j * 16 + l15;
      const float bb = bias[colg];
#pragma unroll
      for (int r = 0; r < 4; r++) {
        const int mm = m0 + i * 16 + quad * 4 + r;
        const int crow = (mm & (T_ - 1)) * B_ + (mm >> 11);
        C[(long)crow * E_ + colg] = acc[i][j][r] + bb;
      }
    }
}

// ---------------------------------------------------------------------------
// hash_mfma v4: LSH hash as 3-term fp16 MFMA GEMM + in-register argmax.
// grid (256, 4): y = src*2 + r; 256 thr; wave does 32 rows (2x4 tiles, K=64).
// ---------------------------------------------------------------------------
__global__ __launch_bounds__(256) void hash_mfma(
    const float* __restrict__ Q, const float* __restrict__ K,
    const uint16_t* __restrict__ Lwh, const uint16_t* __restrict__ Lwl,
    const float* __restrict__ lshb,
    int* __restrict__ qh, int* __restrict__ kh,
    int* __restrict__ qcnt, int* __restrict__ kcnt)
{
  const int comb = blockIdx.y;               // 0..3
  const int src = comb >> 1, r = comb & 1;
  const float* X = src ? K : Q;
  int* outh = src ? kh : qh;
  int* cnt  = src ? kcnt : qcnt;

  const int wid = threadIdx.x >> 6, lane = threadIdx.x & 63;
  const int m0 = (blockIdx.x * 4 + wid) * 32;  // head-row base (32 rows/wave)
  const int l15 = lane & 15, quad = lane >> 4;

  v8h bh[4][2], bl[4][2];
#pragma unroll
  for (int n = 0; n < 4; n++)
#pragma unroll
    for (int k = 0; k < 2; k++) {
      const int o = r * (DH_ * DH_) + (n * 16 + l15) * DH_ + k * 32 + quad * 8;
      bh[n][k] = *(const v8h*)(Lwh + o);
      bl[n][k] = *(const v8h*)(Lwl + o);
    }

  v4f accH[2][4] = {};
  v4f accX[2][4] = {};
#pragma unroll
  for (int k = 0; k < 2; k++) {
    const long a0 = (long)(m0 + l15) * DH_ + k * 32 + quad * 8;
    const long a1 = a0 + 16L * DH_;
    v8h ah0, al0, ah1, al1;
    split2h8(*(const float4*)(X + a0), *(const float4*)(X + a0 + 4), ah0, al0);
    split2h8(*(const float4*)(X + a1), *(const float4*)(X + a1 + 4), ah1, al1);
#pragma unroll
    for (int n = 0; n < 4; n++) {
      accH[0][n] = __builtin_amdgcn_mfma_f32_16x16x32_f16(ah0, bh[n][k], accH[0][n], 0, 0, 0);
      accH[1][n] = __builtin_amdgcn_mfma_f32_16x16x32_f16(ah1, bh[n][k], accH[1][n], 0, 0, 0);
      accX[0][n] = __builtin_amdgcn_mfma_f32_16x16x32_f16(ah0, bl[n][k], accX[0][n], 0, 0, 0);
      accX[1][n] = __builtin_amdgcn_mfma_f32_16x16x32_f16(ah1, bl[n][k], accX[1][n], 0, 0, 0);
      accX[0][n] = __builtin_amdgcn_mfma_f32_16x16x32_f16(al0, bh[n][k], accX[0][n], 0, 0, 0);
      accX[1][n] = __builtin_amdgcn_mfma_f32_16x16x32_f16(al1, bh[n][k], accX[1][n], 0, 0, 0);
    }
  }

  float bb[4];
#pragma unroll
  for (int n = 0; n < 4; n++) bb[n] = lshb[r * DH_ + n * 16 + l15];

#pragma unroll
  for (int i = 0; i < 2; i++)
#pragma unroll
    for (int reg = 0; reg < 4; reg++) {
      float bv = -INFINITY; int bi = 0x7fffffff;
#pragma unroll
      for (int n = 0; n < 4; n++) {
        const float v = accH[i][n][reg] + accX[i][n][reg] * (1.0f / 4096.0f)
                        + bb[n];
        const int idx = n * 16 + l15;
        if (v > bv || (v == bv && idx < bi)) { bv = v; bi = idx; }
      }
#pragma unroll
      for (int d = 8; d >= 1; d >>= 1) {
        const float ov = __shfl_xor(bv, d);
        const int oi = __shfl_xor(bi, d);
        if (ov > bv || (ov == bv && oi < bi)) { bv = ov; bi = oi; }
      }
      if (l15 == 0) {
        const int hr = m0 + i * 16 + quad * 4 + reg;
        const int p = hr >> 3, hh = hr & 7;
        const int bt = p >> 11, t = p & (T_ - 1);
        const int seg = r * 16 + bt * H_ + hh;
        outh[seg * T_ + t] = bi;
        if (bi < NBUCKET) atomicAdd(&cnt[seg * NBUCKET + bi], 1);
      }
    }
}

// ---------------------------------------------------------------------------
// Scan v3: 2 blocks x 1024 threads; one thread per (seg,bucket).
// ---------------------------------------------------------------------------
__global__ __launch_bounds__(1024) void scan_kernel(
    const int* __restrict__ kcnt, int* __restrict__ koff,
    int* __restrict__ kcur,
    const int* __restrict__ qcnt, int* __restrict__ qoff,
    int* __restrict__ qcur,
    int* __restrict__ ntasks, int* __restrict__ tasks)
{
  const int tid = threadIdx.x;          // 0..1023
  const int isq = blockIdx.x;           // 0 = k-side, 1 = q-side
  const int seg = tid >> 5;             // 0..31
  const int b   = tid & 31;             // bucket
  const int* cnt = isq ? qcnt : kcnt;
  int* off = isq ? qoff : koff;
  int* cur = isq ? qcur : kcur;

  const int c = cnt[seg * NBUCKET + b];

  int s = c;
#pragma unroll
  for (int d = 1; d < 32; d <<= 1) {
    const int t = __shfl_up(s, d, 32);
    if (b >= d) s += t;
  }
  const int excl = s - c;
  off[seg * (NBUCKET + 1) + b] = excl;
  cur[seg * NBUCKET + b] = excl;
  if (b == 31) off[seg * (NBUCKET + 1) + NBUCKET] = s;

  if (isq) {
    const int nt = (c + 15) >> 4;
    const int lane = tid & 63;
    int ws = nt;
#pragma unroll
    for (int d = 1; d < 64; d <<= 1) {
      const int t = __shfl_up(ws, d, 64);
      if (lane >= d) ws += t;
    }
    const int wtotal = __shfl(ws, 63, 64);
    int base = 0;
    if (lane == 63 && wtotal > 0) base = atomicAdd(ntasks, wtotal);
    base = __shfl(base, 63, 64);
    const int my = base + ws - nt;
    for (int i = 0; i < nt; i++)
      tasks[my + i] = (seg << 16) | (b << 8) | i;
  }
}

__global__ __launch_bounds__(256) void scatter2_kernel(
    const int* __restrict__ kh, const int* __restrict__ qh,
    int* __restrict__ kcur, int* __restrict__ qcur,
    int* __restrict__ klist, int* __restrict__ qlist)
{
  const int idx = blockIdx.x * 256 + threadIdx.x;
  const int y = blockIdx.y;
  const int* hsh = y ? qh : kh;
  int* cur = y ? qcur : kcur;
  int* list = y ? qlist : klist;
  const int v = hsh[idx];
  if (v < NBUCKET) {
    const int seg = idx >> 11;
    const int pos = atomicAdd(&cur[seg * NBUCKET + v], 1);
    list[seg * T_ + pos] = idx & (T_ - 1);
  }
}

// ---------------------------------------------------------------------------
// attn_task v7: MFMA bucket attention.
// Per task: 16 queries x nk keys (64-key tiles). Waves split work:
//   QK^T: wave w owns keys [w*16, w*16+16) of the tile. A = Q frags in regs
//     (bf16 hi/lo 3-term), B = K read direct from global (row=key via l15).
//     D[q=quad*4+r][key=l15]; p = exp(s/8) masked; row-sums via shfl_xor(16)
//     + one LDS atomicAdd per quad leader; P -> Plds[16][68].
//   V staged transposed: Vts[d][key] (loads issued at tile top, written
//     after QK so HBM latency hides under the MFMAs).
//   PV: wave w owns dims [w*16, w*16+16). A = P (bf16 3-term) from Plds,
//     B = Vt (bf16 3-term) from Vts; persistent 16x16 acc across tiles.
// Epilogue: oacc[q][d] * (0.5/larr[q]) atomicAdd to attn (rows q<nqt only).
// Invalid keys: index clamped, p=0 (no contribution). 2 syncs/tile.
// LDS 22KB (was 39.4) -> 7 blocks/CU.
// ---------------------------------------------------------------------------
__global__ __launch_bounds__(256) void attn_task(
    const float* __restrict__ Q, const float* __restrict__ K,
    const float* __restrict__ V,
    const int* __restrict__ qlist, const int* __restrict__ qoff,
    const int* __restrict__ klist, const int* __restrict__ koff,
    const int* __restrict__ tasks, const int* __restrict__ ntasks,
    float* __restrict__ attn)
{
  __shared__ __align__(16) float Plds[16][68];
  __shared__ __align__(16) float Vts[64][68];
  __shared__ float larr[16];

  if ((int)blockIdx.x >= *ntasks) return;
  const int tk = tasks[blockIdx.x];
  const int seg = tk >> 16, bucket = (tk >> 8) & 255, qt = tk & 255;
  const int ctx = seg & 15;
  const int b = ctx >> 3, h = ctx & 7;

  const int qlo = qoff[seg * (NBUCKET + 1) + bucket] + qt * 16;
  const int nqt = min(16, qoff[seg * (NBUCKET + 1) + bucket + 1] - qlo);
  const int klo = koff[seg * (NBUCKET + 1) + bucket];
  const int nk  = koff[seg * (NBUCKET + 1) + bucket + 1] - klo;
  if (nk == 0) return;

  const int tid = threadIdx.x;
  const int wid = tid >> 6, lane = tid & 63;
  const int l15 = lane & 15, quad = lane >> 4;
  const int r0 = tid >> 4, c4 = tid & 15;   // V-staging coords

  const float* Qb = Q + ((long)b * T_) * E_ + h * DH_;
  const float* Kb = K + ((long)b * T_) * E_ + h * DH_;
  const float* Vb = V + ((long)b * T_) * E_ + h * DH_;
  const int* ql = qlist + seg * T_;
  const int* kl = klist + seg * T_;

  if (tid < 16) larr[tid] = 0.f;

  // Q A-fragments: row=q=l15 (clamped), k=dim quad*8 (+32 per ks)
  const long qrow = (long)ql[qlo + min(l15, nqt - 1)] * E_;
  v8s qfh[2], qfl[2];
#pragma unroll
  for (int ks = 0; ks < 2; ks++) {
    const float4 a = *(const float4*)(Qb + qrow + ks * 32 + quad * 8);
    const float4 c = *(const float4*)(Qb + qrow + ks * 32 + quad * 8 + 4);
    split8(a, c, qfh[ks], qfl[ks]);
  }
  __syncthreads();          // larr init visible before first atomics

  v4f oacc = {0.f, 0.f, 0.f, 0.f};

  for (int kt = 0; kt < nk; kt += 64) {
    // --- V tile loads into registers (latency hides under QK MFMAs) ---
    float4 vreg[4];
#pragma unroll
    for (int it = 0; it < 4; it++) {
      const int key = kt + it * 16 + r0;
      const long krow = (long)kl[klo + min(key, nk - 1)] * E_;
      vreg[it] = *(const float4*)(Vb + krow + c4 * 4);
    }

    // --- QK^T: this wave's 16 keys (cols = l15), bf16 3-term ---
    const int keyg = kt + wid * 16 + l15;
    const long krow = (long)kl[klo + min(keyg, nk - 1)] * E_;
    v4f sacc = {0.f, 0.f, 0.f, 0.f};
#pragma unroll
    for (int ks = 0; ks < 2; ks++) {
      const float4 a = *(const float4*)(Kb + krow + ks * 32 + quad * 8);
      const float4 c = *(const float4*)(Kb + krow + ks * 32 + quad * 8 + 4);
      v8s kfh, kfl;
      split8(a, c, kfh, kfl);
      sacc = __builtin_amdgcn_mfma_f32_16x16x32_bf16(qfh[ks], kfh, sacc, 0, 0, 0);
      sacc = __builtin_amdgcn_mfma_f32_16x16x32_bf16(qfh[ks], kfl, sacc, 0, 0, 0);
      sacc = __builtin_amdgcn_mfma_f32_16x16x32_bf16(qfl[ks], kfh, sacc, 0, 0, 0);
    }

    const bool kvalid = keyg < nk;
    const float p0 = kvalid ? __expf(sacc[0] * 0.125f) : 0.f;
    const float p1 = kvalid ? __expf(sacc[1] * 0.125f) : 0.f;
    const float p2 = kvalid ? __expf(sacc[2] * 0.125f) : 0.f;
    const float p3 = kvalid ? __expf(sacc[3] * 0.125f) : 0.f;

    float rs0 = p0, rs1 = p1, rs2 = p2, rs3 = p3;
#pragma unroll
    for (int d = 1; d < 16; d <<= 1) {
      rs0 += __shfl_xor(rs0, d);
      rs1 += __shfl_xor(rs1, d);
      rs2 += __shfl_xor(rs2, d);
      rs3 += __shfl_xor(rs3, d);
    }
    if (l15 == 0) {
      atomicAdd(&larr[quad * 4 + 0], rs0);
      atomicAdd(&larr[quad * 4 + 1], rs1);
      atomicAdd(&larr[quad * 4 + 2], rs2);
      atomicAdd(&larr[quad * 4 + 3], rs3);
    }
    Plds[quad * 4 + 0][wid * 16 + l15] = p0;
    Plds[quad * 4 + 1][wid * 16 + l15] = p1;
    Plds[quad * 4 + 2][wid * 16 + l15] = p2;
    Plds[quad * 4 + 3][wid * 16 + l15] = p3;

    // --- Vt transpose store (waits on vreg loads here, post-MFMA) ---
#pragma unroll
    for (int it = 0; it < 4; it++) {
      const int row = it * 16 + r0;
      Vts[c4 * 4 + 0][row] = vreg[it].x;
      Vts[c4 * 4 + 1][row] = vreg[it].y;
      Vts[c4 * 4 + 2][row] = vreg[it].z;
      Vts[c4 * 4 + 3][row] = vreg[it].w;
    }
    __syncthreads();

    // --- PV: this wave's 16 dims (cols = wid*16+l15), keys as K-dim ---
#pragma unroll
    for (int ks = 0; ks < 2; ks++) {
      const float4 pa = *(const float4*)&Plds[l15][ks * 32 + quad * 8];
      const float4 pb = *(const float4*)&Plds[l15][ks * 32 + quad * 8 + 4];
      v8s pah, pal;
      split8(pa, pb, pah, pal);
      const float4 va = *(const float4*)&Vts[wid * 16 + l15][ks * 32 + quad * 8];
      const float4 vb = *(const float4*)&Vts[wid * 16 + l15][ks * 32 + quad * 8 + 4];
      v8s vfh, vfl;
      split8(va, vb, vfh, vfl);
      oacc = __builtin_amdgcn_mfma_f32_16x16x32_bf16(pah, vfh, oacc, 0, 0, 0);
      oacc = __builtin_amdgcn_mfma_f32_16x16x32_bf16(pah, vfl, oacc, 0, 0, 0);
      oacc = __builtin_amdgcn_mfma_f32_16x16x32_bf16(pal, vfh, oacc, 0, 0, 0);
    }
    __syncthreads();
  }

  // epilogue: oacc row q=quad*4+r, col d=wid*16+l15
#pragma unroll
  for (int r = 0; r < 4; r++) {
    const int q = quad * 4 + r;
    if (q < nqt) {
      const float inv = 0.5f / larr[q];
      const int t = ql[qlo + q];
      atomicAdd(attn + ((long)b * T_ + t) * E_ + h * DH_ + wid * 16 + l15,
                oacc[r] * inv);
    }
  }
}

// ---------------------------------------------------------------------------
extern "C" void kernel_launch(void* const* d_in, const int* in_sizes, int n_in,
                              void* d_out, int out_size, void* d_ws, size_t ws_size,
                              hipStream_t stream) {
  const float* query = (const float*)d_in[0];
  const float* key   = (const float*)d_in[1];
  const float* value = (const float*)d_in[2];
  const float* Wq = (const float*)d_in[3];
  const float* bq = (const float*)d_in[4];
  const float* Wk = (const float*)d_in[5];
  const float* bk = (const float*)d_in[6];
  const float* Wv = (const float*)d_in[7];
  const float* bv = (const float*)d_in[8];
  const float* Wo = (const float*)d_in[9];
  const float* bo = (const float*)d_in[10];
  const float* lshW = (const float*)d_in[11];
  const float* lshb = (const float*)d_in[12];

  const size_t MSZ = (size_t)M_ * E_;
  const size_t WSZ = (size_t)E_ * E_;
  float* Q    = (float*)d_ws;
  float* K    = Q + MSZ;
  float* V    = K + MSZ;
  float* attn = V + MSZ;
  int* qh     = (int*)(attn + MSZ);
  int* kh     = qh + NSEG * T_;
  int* klist  = kh + NSEG * T_;
  int* qlist  = klist + NSEG * T_;
  int* kcnt   = qlist + NSEG * T_;       // start of zeroed region
  int* qcnt   = kcnt + NSEG * NBUCKET;
  int* ntasks = qcnt + NSEG * NBUCKET;   // end of zeroed region
  int* kcur   = ntasks + 1;
  int* qcur   = kcur + NSEG * NBUCKET;
  int* koff   = qcur + NSEG * NBUCKET;
  int* qoff   = koff + NSEG * (NBUCKET + 1);
  int* tasks  = qoff + NSEG * (NBUCKET + 1);
  uint16_t* Woh = (uint16_t*)(((uintptr_t)(tasks + MAXTASK) + 15) & ~(uintptr_t)15);
  uint16_t* Wol = Woh + WSZ;
  uint16_t* Wqh = Wol + WSZ;
  uint16_t* Wql = Wqh + WSZ;
  uint16_t* Wkh = Wql + WSZ;
  uint16_t* Wkl = Wkh + WSZ;
  uint16_t* Wvh = Wkl + WSZ;
  uint16_t* Wvl = Wvh + WSZ;
  uint16_t* Xqh = Wvl + WSZ;
  uint16_t* Xql = Xqh + MSZ;
  uint16_t* Xkh = Xql + MSZ;
  uint16_t* Xkl = Xkh + MSZ;
  uint16_t* Xvh = Xkl + MSZ;
  uint16_t* Xvl = Xvh + MSZ;
  uint16_t* Lwh = Xvl + MSZ;
  uint16_t* Lwl = Lwh + (size_t)NROUND * DH_ * DH_;

  prep_kernel<<<dim3(4609), 256, 0, stream>>>(
      query, key, value, Wq, Wk, Wv, Wo, lshW,
      Xqh, Xql, Xkh, Xkl, Xvh, Xvl,
      Wqh, Wql, Wkh, Wkl, Wvh, Wvl, Woh, Wol,
      Lwh, Lwl, attn, kcnt);
  proj_mfma<<<dim3(M_ / 128, E_ / 64, 3), 256, 0, stream>>>(
      Xqh, Xql, Xkh, Xkl, Xvh, Xvl,
      Wqh, Wql, Wkh, Wkl, Wvh, Wvl,
      bq, bk, bv, Q, K, V);
  hash_mfma<<<dim3(M_ * H_ / 128, 4), 256, 0, stream>>>(
      Q, K, Lwh, Lwl, lshb, qh, kh, qcnt, kcnt);
  scan_kernel<<<dim3(2), 1024, 0, stream>>>(kcnt, koff, kcur, qcnt, qoff, qcur,
                                            ntasks, tasks);
  scatter2_kernel<<<dim3(NSEG * T_ / 256, 2), 256, 0, stream>>>(
      kh, qh, kcur, qcur, klist, qlist);
  attn_task<<<dim3(MAXTASK), 256, 0, stream>>>(
      Q, K, V, qlist, qoff, klist, koff, tasks, ntasks, attn);
  mfma_gemm<<<dim3(M_ / 128, E_ / 64), 256, 0, stream>>>(
      attn, Woh, Wol, bo, (float*)d_out);
}

// Round 8
// 219.722 us; speedup vs baseline: 1.7223x; 1.0189x over previous
//
#include <hip/hip_runtime.h>
#include <stdint.h>
#include <math.h>

// ReformerAttention on MI355X — fp32 I/O. B=2,T=2048,E=512,H=8,Dh=64,
// 2 hash rounds, buckets<32 attend.
// Projection row p = logical (b'=p>>11, t'=p&2047); gathers input row (b=p&1, t=p>>1).
//
// 7 launches:
//   prep (fp16 2-way split of query/key/value/Wq/Wk/Wv + bf16 hi/lo Wo, all
//         written in TILED MFMA-fragment order; + lshW split + zero attn/cnt)
//   -> proj_mfma (fused Q,K,V projections, fp16 3-term, tiled operands)
//   -> hash_mfma(+hist) -> scan(+tasks) -> scatter2
//   -> attn_task (MFMA, v7; writes attn in TILED fp32 layout)
//   -> mfma_gemm(out, tiled-A + tiled-B, perm)
//
// r7 lessons: top-5 is now ALL fillBufferAligned (256MiB harness workspace
//   re-poison, ~43.5us/iter — not controllable; must keep zeroing attn since
//   the fill pattern is a poison, not zero). All our kernels < 43us.
//   Remaining known structural defect: out-proj A-loads were lane=row
//   divergent (16 lines/instr — the r5 disease). attn's layout is free
//   (attn_task epilogue is scattered per-element atomics either way), so v8
//   stores attn directly in the tiled fp32 A-fragment order; out-proj A-loads
//   become lane-linear coalesced like proj_mfma's.
// Tiled layouts (elem offsets, fp16/bf16/fp32 units):
//   A[mb][ks][half]: ((mb*32 + ks*2 + half)*64 + lane)*8,
//     row=mb*32+half*16+(lane&15), k=ks*32+(lane>>4)*8
//   B[nb][ks]: ((nb*16 + ks)*64 + lane)*8, col=nb*16+(lane&15), k=ks*32+(lane>>4)*8
// Q,K precision scheme (argmax needs fp32-class exactness):
//   x = h + l/4096, h=fp16(x) (|x|<2^-14 flushed), l=fp16((x-h)*2^12).
//   hh -> accH; h*l'+l'*h -> accX; C = accH + accX*2^-12. Verified r2-r7.
// scan v3 (r3): shfl prefix scans, ONE atomicAdd per wave.
// hash v4 (r4): 3-term fp16 MFMA + in-reg argmax.
// attn v7 (r7): MFMA wave-split bucket attention, 22KB LDS.

#define T_ 2048
#define E_ 512
#define H_ 8
#define DH_ 64
#define B_ 2
#define M_ 4096
#define NROUND 2
#define NBUCKET 32
#define NSEG 32
#define MAXTASK 5120

typedef short v8s __attribute__((ext_vector_type(8)));
typedef _Float16 v8h __attribute__((ext_vector_type(8)));
typedef float v4f __attribute__((ext_vector_type(4)));

__device__ __forceinline__ float bf2f(uint16_t u) {
  union { uint32_t i; float f; } v; v.i = ((uint32_t)u) << 16; return v.f;
}
__device__ __forceinline__ uint16_t f2bf(float f) {
  union { float fv; uint32_t i; } v; v.fv = f;
  uint32_t x = v.i;
  x += 0x7fffu + ((x >> 16) & 1u);   // RN-even
  return (uint16_t)(x >> 16);
}
__device__ __forceinline__ void split8(const float4 a, const float4 b,
                                       v8s& h, v8s& l) {
  const float x[8] = {a.x, a.y, a.z, a.w, b.x, b.y, b.z, b.w};
#pragma unroll
  for (int j = 0; j < 8; j++) {
    const uint16_t hh = f2bf(x[j]);
    h[j] = (short)hh;
    l[j] = (short)f2bf(x[j] - bf2f(hh));
  }
}
// 2-way fp16 split with scaled residual: x = h + l*2^-12, no fp16 subnormals.
__device__ __forceinline__ void split2h8(const float4 a, const float4 b,
                                         v8h& h, v8h& l) {
  const float x[8] = {a.x, a.y, a.z, a.w, b.x, b.y, b.z, b.w};
#pragma unroll
  for (int j = 0; j < 8; j++) {
    const float xv = x[j];
    const _Float16 hh = (fabsf(xv) < 6.1035156e-5f) ? (_Float16)0.0f
                                                    : (_Float16)xv;
    const float r = xv - (float)hh;          // exact (Sterbenz / hh==0)
    h[j] = hh;
    l[j] = (_Float16)(r * 4096.0f);
  }
}

// ---------------------------------------------------------------------------
// prep: staging into tiled fragment layouts.
//   blocks [0,3072)    : query/key/value fp16 split, gathered, TILED
//   blocks [3072,3456) : Wq/Wk/Wv fp16 split, TILED
//   blocks [3456,3584) : Wo bf16 hi/lo split, TILED
//   blocks [3584,4608) : zero attn
//   block  4608        : zero cnt region + lshW fp16 split
// ---------------------------------------------------------------------------
__global__ __launch_bounds__(256) void prep_kernel(
    const float* __restrict__ Xq, const float* __restrict__ Xk,
    const float* __restrict__ Xv,
    const float* __restrict__ Wq, const float* __restrict__ Wk,
    const float* __restrict__ Wv, const float* __restrict__ Wo,
    const float* __restrict__ lshW,
    uint16_t* __restrict__ Xqh, uint16_t* __restrict__ Xql,
    uint16_t* __restrict__ Xkh, uint16_t* __restrict__ Xkl,
    uint16_t* __restrict__ Xvh, uint16_t* __restrict__ Xvl,
    uint16_t* __restrict__ Wqh, uint16_t* __restrict__ Wql,
    uint16_t* __restrict__ Wkh, uint16_t* __restrict__ Wkl,
    uint16_t* __restrict__ Wvh, uint16_t* __restrict__ Wvl,
    uint16_t* __restrict__ Woh, uint16_t* __restrict__ Wol,
    uint16_t* __restrict__ Lwh, uint16_t* __restrict__ Lwl,
    float* __restrict__ attn, int* __restrict__ cnt)
{
  const int bid = blockIdx.x;
  const int tid = threadIdx.x;

  if (bid < 3072) {                      // q/k/v fp16 split (gathered, tiled)
    const int sel = bid >> 10;           // 0=q,1=k,2=v
    const float* X = (sel == 0) ? Xq : (sel == 1) ? Xk : Xv;
    uint16_t* H = (sel == 0) ? Xqh : (sel == 1) ? Xkh : Xvh;
    uint16_t* L = (sel == 0) ? Xql : (sel == 1) ? Xkl : Xvl;
    const int e = ((bid & 1023) * 256 + tid) * 8;   // [0, M_*E_)
    const int p = e >> 9, k = e & 511;
    const long src = ((long)(p & 1) * T_ + (p >> 1)) * E_ + k;
    const float4 a = *(const float4*)(X + src);
    const float4 b = *(const float4*)(X + src + 4);
    v8h h, l;
    split2h8(a, b, h, l);
    // tiled offset: frag(mb=p>>5, ks=k>>5, half=(p>>4)&1), lane=(k>>3&3)*16+(p&15)
    const long to = ((long)((p >> 5) * 32 + (k >> 5) * 2 + ((p >> 4) & 1)) * 64
                     + ((k >> 3) & 3) * 16 + (p & 15)) * 8;
    *(v8h*)(H + to) = h;
    *(v8h*)(L + to) = l;
    return;
  }

  if (bid < 3584) {                      // weight splits, tiled
    const int wsel = (bid - 3072) >> 7;  // 0=Wq,1=Wk,2=Wv,3=Wo
    const int e = (((bid - 3072) & 127) * 256 + tid) * 8;   // [0, E_*E_)
    const int n = e >> 9, k = e & 511;
    const long to = ((long)((n >> 4) * 16 + (k >> 5)) * 64
                     + ((k >> 3) & 3) * 16 + (n & 15)) * 8;
    if (wsel < 3) {
      const float* S = (wsel == 0) ? Wq : (wsel == 1) ? Wk : Wv;
      const float4 a = *(const float4*)(S + e);
      const float4 b = *(const float4*)(S + e + 4);
      v8h h, l;
      split2h8(a, b, h, l);
      uint16_t* H = (wsel == 0) ? Wqh : (wsel == 1) ? Wkh : Wvh;
      uint16_t* L = (wsel == 0) ? Wql : (wsel == 1) ? Wkl : Wvl;
      *(v8h*)(H + to) = h;
      *(v8h*)(L + to) = l;
    } else {
      const float4 a = *(const float4*)(Wo + e);
      const float4 b = *(const float4*)(Wo + e + 4);
      v8s h, l;
      split8(a, b, h, l);
      *(v8s*)(Woh + to) = h;
      *(v8s*)(Wol + to) = l;
    }
    return;
  }

  if (bid < 4608) {                      // zero attn: 1024 blocks x 512 float4
    float4* a4 = (float4*)attn;
    const int g = (bid - 3584) * 512 + tid * 2;
    a4[g] = make_float4(0.f, 0.f, 0.f, 0.f);
    a4[g + 1] = make_float4(0.f, 0.f, 0.f, 0.f);
    return;
  }

  for (int i = tid; i < 2 * NSEG * NBUCKET + 1; i += 256) cnt[i] = 0;
  for (int i = tid; i < NROUND * DH_ * DH_; i += 256) {  // lshW fp16 split
    const float xv = lshW[i];
    const _Float16 hh = (fabsf(xv) < 6.1035156e-5f) ? (_Float16)0.0f
                                                    : (_Float16)xv;
    const float r = xv - (float)hh;
    *(_Float16*)(Lwh + i) = hh;
    *(_Float16*)(Lwl + i) = (_Float16)(r * 4096.0f);
  }
}

// ---------------------------------------------------------------------------
// proj_mfma v6: fused Q/K/V projections, fp16 3-term, TILED operands.
// grid (32, 8, 3) = 768 blocks; 2x4 16x16 tiles/wave (32x64). Every operand
// load is lane-linear 16B (coalesced 1KB/instr). Register double-buffered.
// ---------------------------------------------------------------------------
__global__ __launch_bounds__(256) void proj_mfma(
    const uint16_t* __restrict__ Aqh, const uint16_t* __restrict__ Aql,
    const uint16_t* __restrict__ Akh, const uint16_t* __restrict__ Akl,
    const uint16_t* __restrict__ Avh, const uint16_t* __restrict__ Avl,
    const uint16_t* __restrict__ Bqh, const uint16_t* __restrict__ Bql,
    const uint16_t* __restrict__ Bkh, const uint16_t* __restrict__ Bkl,
    const uint16_t* __restrict__ Bvh, const uint16_t* __restrict__ Bvl,
    const float* __restrict__ bq, const float* __restrict__ bk,
    const float* __restrict__ bv,
    float* __restrict__ Qo, float* __restrict__ Ko, float* __restrict__ Vo)
{
  const uint16_t *Ah, *Al, *Bh, *Bl;
  const float* bias; float* C;
  if (blockIdx.z == 0)      { Ah = Aqh; Al = Aql; Bh = Bqh; Bl = Bql; bias = bq; C = Qo; }
  else if (blockIdx.z == 1) { Ah = Akh; Al = Akl; Bh = Bkh; Bl = Bkl; bias = bk; C = Ko; }
  else                      { Ah = Avh; Al = Avl; Bh = Bvh; Bl = Bvl; bias = bv; C = Vo; }

  const int wid = threadIdx.x >> 6, lane = threadIdx.x & 63;
  const int mb = blockIdx.x * 4 + wid;        // 32-row block
  const int nb0 = blockIdx.y * 4;             // first 16-col block
  const int m0 = mb * 32, n0 = blockIdx.y * 64;
  const int l15 = lane & 15, quad = lane >> 4;

  // tiled bases (fp16 elem units); frag strides: A ks*1024, half 512; B ks*512
  const long aB = (long)mb * 16384 + lane * 8;
  long bB[4];
#pragma unroll
  for (int j = 0; j < 4; j++) bB[j] = (long)(nb0 + j) * 8192 + lane * 8;

  v4f accH[2][4] = {};
  v4f accX[2][4] = {};

  // prologue: ks = 0
  v8h ah0 = *(const v8h*)(Ah + aB);
  v8h ah1 = *(const v8h*)(Ah + aB + 512);
  v8h al0 = *(const v8h*)(Al + aB);
  v8h al1 = *(const v8h*)(Al + aB + 512);
  v8h bh[4], bl[4];
#pragma unroll
  for (int j = 0; j < 4; j++) {
    bh[j] = *(const v8h*)(Bh + bB[j]);
    bl[j] = *(const v8h*)(Bl + bB[j]);
  }

  for (int ks = 0; ks < 16; ks++) {
    const int kn = (ks + 1) & 15;   // wraps on last iter; values unused
    const v8h nah0 = *(const v8h*)(Ah + aB + kn * 1024);
    const v8h nah1 = *(const v8h*)(Ah + aB + kn * 1024 + 512);
    const v8h nal0 = *(const v8h*)(Al + aB + kn * 1024);
    const v8h nal1 = *(const v8h*)(Al + aB + kn * 1024 + 512);
    v8h nbh[4], nbl[4];
#pragma unroll
    for (int j = 0; j < 4; j++) {
      nbh[j] = *(const v8h*)(Bh + bB[j] + kn * 512);
      nbl[j] = *(const v8h*)(Bl + bB[j] + kn * 512);
    }

    // 24 MFMAs: hh -> accH; h*l' and l'*h -> accX (carries 2^12 scale)
#pragma unroll
    for (int j = 0; j < 4; j++) {
      accH[0][j] = __builtin_amdgcn_mfma_f32_16x16x32_f16(ah0, bh[j], accH[0][j], 0, 0, 0);
      accH[1][j] = __builtin_amdgcn_mfma_f32_16x16x32_f16(ah1, bh[j], accH[1][j], 0, 0, 0);
    }
#pragma unroll
    for (int j = 0; j < 4; j++) {
      accX[0][j] = __builtin_amdgcn_mfma_f32_16x16x32_f16(ah0, bl[j], accX[0][j], 0, 0, 0);
      accX[1][j] = __builtin_amdgcn_mfma_f32_16x16x32_f16(ah1, bl[j], accX[1][j], 0, 0, 0);
    }
#pragma unroll
    for (int j = 0; j < 4; j++) {
      accX[0][j] = __builtin_amdgcn_mfma_f32_16x16x32_f16(al0, bh[j], accX[0][j], 0, 0, 0);
      accX[1][j] = __builtin_amdgcn_mfma_f32_16x16x32_f16(al1, bh[j], accX[1][j], 0, 0, 0);
    }

    // rotate
    ah0 = nah0; al0 = nal0; ah1 = nah1; al1 = nal1;
#pragma unroll
    for (int j = 0; j < 4; j++) { bh[j] = nbh[j]; bl[j] = nbl[j]; }
  }

#pragma unroll
  for (int i = 0; i < 2; i++)
#pragma unroll
    for (int j = 0; j < 4; j++) {
      const int colg = n0 + j * 16 + l15;
      const float bb = bias[colg];
#pragma unroll
      for (int r = 0; r < 4; r++) {
        const int mm = m0 + i * 16 + quad * 4 + r;
        C[(long)mm * E_ + colg] =
            accH[i][j][r] + accX[i][j][r] * (1.0f / 4096.0f) + bb;
      }
    }
}

// ---------------------------------------------------------------------------
// mfma_gemm v8 (out-projection): bf16 3-term. A = attn in TILED fp32
// fragment layout (coalesced lane-linear loads, split in-register);
// B pre-split bf16 TILED. permC write. 256 blocks.
// ---------------------------------------------------------------------------
__global__ __launch_bounds__(256) void mfma_gemm(
    const float* __restrict__ A,
    const uint16_t* __restrict__ Bht, const uint16_t* __restrict__ Blt,
    const float* __restrict__ bias, float* __restrict__ C)
{
  const int wid = threadIdx.x >> 6, lane = threadIdx.x & 63;
  const int mb = blockIdx.x * 4 + wid;
  const int m0 = mb * 32;
  const int nb0 = blockIdx.y * 4;
  const int n0 = blockIdx.y * 64;
  const int l15 = lane & 15, quad = lane >> 4;

  const long aB = (long)mb * 16384 + lane * 8;   // fp32 elems, tiled
  long bB[4];
#pragma unroll
  for (int j = 0; j < 4; j++) bB[j] = (long)(nb0 + j) * 8192 + lane * 8;

  v4f acc[2][4] = {};
  for (int ks = 0; ks < 16; ks++) {
    const long a0 = aB + ks * 1024;     // half 0
    const long a1 = a0 + 512;           // half 1
    v8s ah0, al0, ah1, al1;
    split8(*(const float4*)(A + a0), *(const float4*)(A + a0 + 4), ah0, al0);
    split8(*(const float4*)(A + a1), *(const float4*)(A + a1 + 4), ah1, al1);
    v8s bh[4], bl[4];
#pragma unroll
    for (int j = 0; j < 4; j++) {
      bh[j] = *(const v8s*)(Bht + bB[j] + ks * 512);
      bl[j] = *(const v8s*)(Blt + bB[j] + ks * 512);
    }
#pragma unroll
    for (int j = 0; j < 4; j++) {
      acc[0][j] = __builtin_amdgcn_mfma_f32_16x16x32_bf16(ah0, bh[j], acc[0][j], 0, 0, 0);
      acc[1][j] = __builtin_amdgcn_mfma_f32_16x16x32_bf16(ah1, bh[j], acc[1][j], 0, 0, 0);
    }
#pragma unroll
    for (int j = 0; j < 4; j++) {
      acc[0][j] = __builtin_amdgcn_mfma_f32_16x16x32_bf16(ah0, bl[j], acc[0][j], 0, 0, 0);
      acc[1][j] = __builtin_amdgcn_mfma_f32_16x16x32_bf16(ah1, bl[j], acc[1][j], 0, 0, 0);
    }
#pragma unroll
    for (int j = 0; j < 4; j++) {
      acc[0][j] = __builtin_amdgcn_mfma_f32_16x16x32_bf16(al0, bh[j], acc[0][j], 0, 0, 0);
      acc[1][j] = __builtin_amdgcn_mfma_f32_16x16x32_bf16(al1, bh[j], acc[1][j], 0, 0, 0);
    }
  }

#pragma unroll
  for (int i = 0; i < 2; i++)
#pragma unroll
    for (int j = 0; j < 4; j++) {
      const int colg = n0 + j * 16 + l15;
      const float bb = bias[colg];
#pragma unroll
      for (int r = 0; r < 4; r++) {
        const int mm = m0 + i * 16 + quad * 4 + r;
        const int crow = (mm & (T_ - 1)) * B_ + (mm >> 11);
        C[(long)crow * E_ + colg] = acc[i][j][r] + bb;
      }
    }
}

// ---------------------------------------------------------------------------
// hash_mfma v4: LSH hash as 3-term fp16 MFMA GEMM + in-register argmax.
// grid (256, 4): y = src*2 + r; 256 thr; wave does 32 rows (2x4 tiles, K=64).
// ---------------------------------------------------------------------------
__global__ __launch_bounds__(256) void hash_mfma(
    const float* __restrict__ Q, const float* __restrict__ K,
    const uint16_t* __restrict__ Lwh, const uint16_t* __restrict__ Lwl,
    const float* __restrict__ lshb,
    int* __restrict__ qh, int* __restrict__ kh,
    int* __restrict__ qcnt, int* __restrict__ kcnt)
{
  const int comb = blockIdx.y;               // 0..3
  const int src = comb >> 1, r = comb & 1;
  const float* X = src ? K : Q;
  int* outh = src ? kh : qh;
  int* cnt  = src ? kcnt : qcnt;

  const int wid = threadIdx.x >> 6, lane = threadIdx.x & 63;
  const int m0 = (blockIdx.x * 4 + wid) * 32;  // head-row base (32 rows/wave)
  const int l15 = lane & 15, quad = lane >> 4;

  v8h bh[4][2], bl[4][2];
#pragma unroll
  for (int n = 0; n < 4; n++)
#pragma unroll
    for (int k = 0; k < 2; k++) {
      const int o = r * (DH_ * DH_) + (n * 16 + l15) * DH_ + k * 32 + quad * 8;
      bh[n][k] = *(const v8h*)(Lwh + o);
      bl[n][k] = *(const v8h*)(Lwl + o);
    }

  v4f accH[2][4] = {};
  v4f accX[2][4] = {};
#pragma unroll
  for (int k = 0; k < 2; k++) {
    const long a0 = (long)(m0 + l15) * DH_ + k * 32 + quad * 8;
    const long a1 = a0 + 16L * DH_;
    v8h ah0, al0, ah1, al1;
    split2h8(*(const float4*)(X + a0), *(const float4*)(X + a0 + 4), ah0, al0);
    split2h8(*(const float4*)(X + a1), *(const float4*)(X + a1 + 4), ah1, al1);
#pragma unroll
    for (int n = 0; n < 4; n++) {
      accH[0][n] = __builtin_amdgcn_mfma_f32_16x16x32_f16(ah0, bh[n][k], accH[0][n], 0, 0, 0);
      accH[1][n] = __builtin_amdgcn_mfma_f32_16x16x32_f16(ah1, bh[n][k], accH[1][n], 0, 0, 0);
      accX[0][n] = __builtin_amdgcn_mfma_f32_16x16x32_f16(ah0, bl[n][k], accX[0][n], 0, 0, 0);
      accX[1][n] = __builtin_amdgcn_mfma_f32_16x16x32_f16(ah1, bl[n][k], accX[1][n], 0, 0, 0);
      accX[0][n] = __builtin_amdgcn_mfma_f32_16x16x32_f16(al0, bh[n][k], accX[0][n], 0, 0, 0);
      accX[1][n] = __builtin_amdgcn_mfma_f32_16x16x32_f16(al1, bh[n][k], accX[1][n], 0, 0, 0);
    }
  }

  float bb[4];
#pragma unroll
  for (int n = 0; n < 4; n++) bb[n] = lshb[r * DH_ + n * 16 + l15];

#pragma unroll
  for (int i = 0; i < 2; i++)
#pragma unroll
    for (int reg = 0; reg < 4; reg++) {
      float bv = -INFINITY; int bi = 0x7fffffff;
#pragma unroll
      for (int n = 0; n < 4; n++) {
        const float v = accH[i][n][reg] + accX[i][n][reg] * (1.0f / 4096.0f)
                        + bb[n];
        const int idx = n * 16 + l15;
        if (v > bv || (v == bv && idx < bi)) { bv = v; bi = idx; }
      }
#pragma unroll
      for (int d = 8; d >= 1; d >>= 1) {
        const float ov = __shfl_xor(bv, d);
        const int oi = __shfl_xor(bi, d);
        if (ov > bv || (ov == bv && oi < bi)) { bv = ov; bi = oi; }
      }
      if (l15 == 0) {
        const int hr = m0 + i * 16 + quad * 4 + reg;
        const int p = hr >> 3, hh = hr & 7;
        const int bt = p >> 11, t = p & (T_ - 1);
        const int seg = r * 16 + bt * H_ + hh;
        outh[seg * T_ + t] = bi;
        if (bi < NBUCKET) atomicAdd(&cnt[seg * NBUCKET + bi], 1);
      }
    }
}

// ---------------------------------------------------------------------------
// Scan v3: 2 blocks x 1024 threads; one thread per (seg,bucket).
// ---------------------------------------------------------------------------
__global__ __launch_bounds__(1024) void scan_kernel(
    const int* __restrict__ kcnt, int* __restrict__ koff,
    int* __restrict__ kcur,
    const int* __restrict__ qcnt, int* __restrict__ qoff,
    int* __restrict__ qcur,
    int* __restrict__ ntasks, int* __restrict__ tasks)
{
  const int tid = threadIdx.x;          // 0..1023
  const int isq = blockIdx.x;           // 0 = k-side, 1 = q-side
  const int seg = tid >> 5;             // 0..31
  const int b   = tid & 31;             // bucket
  const int* cnt = isq ? qcnt : kcnt;
  int* off = isq ? qoff : koff;
  int* cur = isq ? qcur : kcur;

  const int c = cnt[seg * NBUCKET + b];

  int s = c;
#pragma unroll
  for (int d = 1; d < 32; d <<= 1) {
    const int t = __shfl_up(s, d, 32);
    if (b >= d) s += t;
  }
  const int excl = s - c;
  off[seg * (NBUCKET + 1) + b] = excl;
  cur[seg * NBUCKET + b] = excl;
  if (b == 31) off[seg * (NBUCKET + 1) + NBUCKET] = s;

  if (isq) {
    const int nt = (c + 15) >> 4;
    const int lane = tid & 63;
    int ws = nt;
#pragma unroll
    for (int d = 1; d < 64; d <<= 1) {
      const int t = __shfl_up(ws, d, 64);
      if (lane >= d) ws += t;
    }
    const int wtotal = __shfl(ws, 63, 64);
    int base = 0;
    if (lane == 63 && wtotal > 0) base = atomicAdd(ntasks, wtotal);
    base = __shfl(base, 63, 64);
    const int my = base + ws - nt;
    for (int i = 0; i < nt; i++)
      tasks[my + i] = (seg << 16) | (b << 8) | i;
  }
}

__global__ __launch_bounds__(256) void scatter2_kernel(
    const int* __restrict__ kh, const int* __restrict__ qh,
    int* __restrict__ kcur, int* __restrict__ qcur,
    int* __restrict__ klist, int* __restrict__ qlist)
{
  const int idx = blockIdx.x * 256 + threadIdx.x;
  const int y = blockIdx.y;
  const int* hsh = y ? qh : kh;
  int* cur = y ? qcur : kcur;
  int* list = y ? qlist : klist;
  const int v = hsh[idx];
  if (v < NBUCKET) {
    const int seg = idx >> 11;
    const int pos = atomicAdd(&cur[seg * NBUCKET + v], 1);
    list[seg * T_ + pos] = idx & (T_ - 1);
  }
}

// ---------------------------------------------------------------------------
// attn_task v8: MFMA bucket attention (v7 structure, proven r7) with the
// epilogue writing attn in the TILED fp32 A-fragment layout for the
// out-projection (atomics are scattered either way — layout is free).
// ---------------------------------------------------------------------------
__global__ __launch_bounds__(256) void attn_task(
    const float* __restrict__ Q, const float* __restrict__ K,
    const float* __restrict__ V,
    const int* __restrict__ qlist, const int* __restrict__ qoff,
    const int* __restrict__ klist, const int* __restrict__ koff,
    const int* __restrict__ tasks, const int* __restrict__ ntasks,
    float* __restrict__ attn)
{
  __shared__ __align__(16) float Plds[16][68];
  __shared__ __align__(16) float Vts[64][68];
  __shared__ float larr[16];

  if ((int)blockIdx.x >= *ntasks) return;
  const int tk = tasks[blockIdx.x];
  const int seg = tk >> 16, bucket = (tk >> 8) & 255, qt = tk & 255;
  const int ctx = seg & 15;
  const int b = ctx >> 3, h = ctx & 7;

  const int qlo = qoff[seg * (NBUCKET + 1) + bucket] + qt * 16;
  const int nqt = min(16, qoff[seg * (NBUCKET + 1) + bucket + 1] - qlo);
  const int klo = koff[seg * (NBUCKET + 1) + bucket];
  const int nk  = koff[seg * (NBUCKET + 1) + bucket + 1] - klo;
  if (nk == 0) return;

  const int tid = threadIdx.x;
  const int wid = tid >> 6, lane = tid & 63;
  const int l15 = lane & 15, quad = lane >> 4;
  const int r0 = tid >> 4, c4 = tid & 15;   // V-staging coords

  const float* Qb = Q + ((long)b * T_) * E_ + h * DH_;
  const float* Kb = K + ((long)b * T_) * E_ + h * DH_;
  const float* Vb = V + ((long)b * T_) * E_ + h * DH_;
  const int* ql = qlist + seg * T_;
  const int* kl = klist + seg * T_;

  if (tid < 16) larr[tid] = 0.f;

  // Q A-fragments: row=q=l15 (clamped), k=dim quad*8 (+32 per ks)
  const long qrow = (long)ql[qlo + min(l15, nqt - 1)] * E_;
  v8s qfh[2], qfl[2];
#pragma unroll
  for (int ks = 0; ks < 2; ks++) {
    const float4 a = *(const float4*)(Qb + qrow + ks * 32 + quad * 8);
    const float4 c = *(const float4*)(Qb + qrow + ks * 32 + quad * 8 + 4);
    split8(a, c, qfh[ks], qfl[ks]);
  }
  __syncthreads();          // larr init visible before first atomics

  v4f oacc = {0.f, 0.f, 0.f, 0.f};

  for (int kt = 0; kt < nk; kt += 64) {
    // --- V tile loads into registers (latency hides under QK MFMAs) ---
    float4 vreg[4];
#pragma unroll
    for (int it = 0; it < 4; it++) {
      const int key = kt + it * 16 + r0;
      const long krow = (long)kl[klo + min(key, nk - 1)] * E_;
      vreg[it] = *(const float4*)(Vb + krow + c4 * 4);
    }

    // --- QK^T: this wave's 16 keys (cols = l15), bf16 3-term ---
    const int keyg = kt + wid * 16 + l15;
    const long krow = (long)kl[klo + min(keyg, nk - 1)] * E_;
    v4f sacc = {0.f, 0.f, 0.f, 0.f};
#pragma unroll
    for (int ks = 0; ks < 2; ks++) {
      const float4 a = *(const float4*)(Kb + krow + ks * 32 + quad * 8);
      const float4 c = *(const float4*)(Kb + krow + ks * 32 + quad * 8 + 4);
      v8s kfh, kfl;
      split8(a, c, kfh, kfl);
      sacc = __builtin_amdgcn_mfma_f32_16x16x32_bf16(qfh[ks], kfh, sacc, 0, 0, 0);
      sacc = __builtin_amdgcn_mfma_f32_16x16x32_bf16(qfh[ks], kfl, sacc, 0, 0, 0);
      sacc = __builtin_amdgcn_mfma_f32_16x16x32_bf16(qfl[ks], kfh, sacc, 0, 0, 0);
    }

    const bool kvalid = keyg < nk;
    const float p0 = kvalid ? __expf(sacc[0] * 0.125f) : 0.f;
    const float p1 = kvalid ? __expf(sacc[1] * 0.125f) : 0.f;
    const float p2 = kvalid ? __expf(sacc[2] * 0.125f) : 0.f;
    const float p3 = kvalid ? __expf(sacc[3] * 0.125f) : 0.f;

    float rs0 = p0, rs1 = p1, rs2 = p2, rs3 = p3;
#pragma unroll
    for (int d = 1; d < 16; d <<= 1) {
      rs0 += __shfl_xor(rs0, d);
      rs1 += __shfl_xor(rs1, d);
      rs2 += __shfl_xor(rs2, d);
      rs3 += __shfl_xor(rs3, d);
    }
    if (l15 == 0) {
      atomicAdd(&larr[quad * 4 + 0], rs0);
      atomicAdd(&larr[quad * 4 + 1], rs1);
      atomicAdd(&larr[quad * 4 + 2], rs2);
      atomicAdd(&larr[quad * 4 + 3], rs3);
    }
    Plds[quad * 4 + 0][wid * 16 + l15] = p0;
    Plds[quad * 4 + 1][wid * 16 + l15] = p1;
    Plds[quad * 4 + 2][wid * 16 + l15] = p2;
    Plds[quad * 4 + 3][wid * 16 + l15] = p3;

    // --- Vt transpose store (waits on vreg loads here, post-MFMA) ---
#pragma unroll
    for (int it = 0; it < 4; it++) {
      const int row = it * 16 + r0;
      Vts[c4 * 4 + 0][row] = vreg[it].x;
      Vts[c4 * 4 + 1][row] = vreg[it].y;
      Vts[c4 * 4 + 2][row] = vreg[it].z;
      Vts[c4 * 4 + 3][row] = vreg[it].w;
    }
    __syncthreads();

    // --- PV: this wave's 16 dims (cols = wid*16+l15), keys as K-dim ---
#pragma unroll
    for (int ks = 0; ks < 2; ks++) {
      const float4 pa = *(const float4*)&Plds[l15][ks * 32 + quad * 8];
      const float4 pb = *(const float4*)&Plds[l15][ks * 32 + quad * 8 + 4];
      v8s pah, pal;
      split8(pa, pb, pah, pal);
      const float4 va = *(const float4*)&Vts[wid * 16 + l15][ks * 32 + quad * 8];
      const float4 vb = *(const float4*)&Vts[wid * 16 + l15][ks * 32 + quad * 8 + 4];
      v8s vfh, vfl;
      split8(va, vb, vfh, vfl);
      oacc = __builtin_amdgcn_mfma_f32_16x16x32_bf16(pah, vfh, oacc, 0, 0, 0);
      oacc = __builtin_amdgcn_mfma_f32_16x16x32_bf16(pah, vfl, oacc, 0, 0, 0);
      oacc = __builtin_amdgcn_mfma_f32_16x16x32_bf16(pal, vfh, oacc, 0, 0, 0);
    }
    __syncthreads();
  }

  // epilogue: oacc row q=quad*4+r, col d=wid*16+l15; write TILED attn:
  // p = b*T+t (row), kd = h*64+d (col);
  // off = ((p>>5)*32 + (kd>>5)*2 + ((p>>4)&1))*512 + (((kd>>3)&3)*16+(p&15))*8 + (kd&7)
  const int kd = h * DH_ + wid * 16 + l15;
  const int kpart = (kd >> 5) * 2 * 512 + ((kd >> 3) & 3) * 16 * 8 + (kd & 7);
#pragma unroll
  for (int r = 0; r < 4; r++) {
    const int q = quad * 4 + r;
    if (q < nqt) {
      const float inv = 0.5f / larr[q];
      const int t = ql[qlo + q];
      const int p = b * T_ + t;
      const long off = (long)(p >> 5) * 16384 + ((p >> 4) & 1) * 512
                       + (p & 15) * 8 + kpart;
      atomicAdd(attn + off, oacc[r] * inv);
    }
  }
}

// ---------------------------------------------------------------------------
extern "C" void kernel_launch(void* const* d_in, const int* in_sizes, int n_in,
                              void* d_out, int out_size, void* d_ws, size_t ws_size,
                              hipStream_t stream) {
  const float* query = (const float*)d_in[0];
  const float* key   = (const float*)d_in[1];
  const float* value = (const float*)d_in[2];
  const float* Wq = (const float*)d_in[3];
  const float* bq = (const float*)d_in[4];
  const float* Wk = (const float*)d_in[5];
  const float* bk = (const float*)d_in[6];
  const float* Wv = (const float*)d_in[7];
  const float* bv = (const float*)d_in[8];
  const float* Wo = (const float*)d_in[9];
  const float* bo = (const float*)d_in[10];
  const float* lshW = (const float*)d_in[11];
  const float* lshb = (const float*)d_in[12];

  const size_t MSZ = (size_t)M_ * E_;
  const size_t WSZ = (size_t)E_ * E_;
  float* Q    = (float*)d_ws;
  float* K    = Q + MSZ;
  float* V    = K + MSZ;
  float* attn = V + MSZ;
  int* qh     = (int*)(attn + MSZ);
  int* kh     = qh + NSEG * T_;
  int* klist  = kh + NSEG * T_;
  int* qlist  = klist + NSEG * T_;
  int* kcnt   = qlist + NSEG * T_;       // start of zeroed region
  int* qcnt   = kcnt + NSEG * NBUCKET;
  int* ntasks = qcnt + NSEG * NBUCKET;   // end of zeroed region
  int* kcur   = ntasks + 1;
  int* qcur   = kcur + NSEG * NBUCKET;
  int* koff   = qcur + NSEG * NBUCKET;
  int* qoff   = koff + NSEG * (NBUCKET + 1);
  int* tasks  = qoff + NSEG * (NBUCKET + 1);
  uint16_t* Woh = (uint16_t*)(((uintptr_t)(tasks + MAXTASK) + 15) & ~(uintptr_t)15);
  uint16_t* Wol = Woh + WSZ;
  uint16_t* Wqh = Wol + WSZ;
  uint16_t* Wql = Wqh + WSZ;
  uint16_t* Wkh = Wql + WSZ;
  uint16_t* Wkl = Wkh + WSZ;
  uint16_t* Wvh = Wkl + WSZ;
  uint16_t* Wvl = Wvh + WSZ;
  uint16_t* Xqh = Wvl + WSZ;
  uint16_t* Xql = Xqh + MSZ;
  uint16_t* Xkh = Xql + MSZ;
  uint16_t* Xkl = Xkh + MSZ;
  uint16_t* Xvh = Xkl + MSZ;
  uint16_t* Xvl = Xvh + MSZ;
  uint16_t* Lwh = Xvl + MSZ;
  uint16_t* Lwl = Lwh + (size_t)NROUND * DH_ * DH_;

  prep_kernel<<<dim3(4609), 256, 0, stream>>>(
      query, key, value, Wq, Wk, Wv, Wo, lshW,
      Xqh, Xql, Xkh, Xkl, Xvh, Xvl,
      Wqh, Wql, Wkh, Wkl, Wvh, Wvl, Woh, Wol,
      Lwh, Lwl, attn, kcnt);
  proj_mfma<<<dim3(M_ / 128, E_ / 64, 3), 256, 0, stream>>>(
      Xqh, Xql, Xkh, Xkl, Xvh, Xvl,
      Wqh, Wql, Wkh, Wkl, Wvh, Wvl,
      bq, bk, bv, Q, K, V);
  hash_mfma<<<dim3(M_ * H_ / 128, 4), 256, 0, stream>>>(
      Q, K, Lwh, Lwl, lshb, qh, kh, qcnt, kcnt);
  scan_kernel<<<dim3(2), 1024, 0, stream>>>(kcnt, koff, kcur, qcnt, qoff, qcur,
                                            ntasks, tasks);
  scatter2_kernel<<<dim3(NSEG * T_ / 256, 2), 256, 0, stream>>>(
      kh, qh, kcur, qcur, klist, qlist);
  attn_task<<<dim3(MAXTASK), 256, 0, stream>>>(
      Q, K, V, qlist, qoff, klist, koff, tasks, ntasks, attn);
  mfma_gemm<<<dim3(M_ / 128, E_ / 64), 256, 0, stream>>>(
      attn, Woh, Wol, bo, (float*)d_out);
}

// Round 9
// 211.753 us; speedup vs baseline: 1.7872x; 1.0376x over previous
//
#include <hip/hip_runtime.h>
#include <stdint.h>
#include <math.h>

// ReformerAttention on MI355X — fp32 I/O. B=2,T=2048,E=512,H=8,Dh=64,
// 2 hash rounds, buckets<32 attend.
// Projection row p = logical (b'=p>>11, t'=p&2047); gathers input row (b=p&1, t=p>>1).
//
// 7 launches:
//   prep (fp16 2-way split of query/key/value/Wq/Wk/Wv + bf16 hi/lo Wo, all
//         written in TILED MFMA-fragment order with DEST-LINEAR mapping;
//         + lshW split + zero attn/cnt)
//   -> proj_mfma (fused Q,K,V projections, fp16 3-term, tiled operands)
//   -> hash_mfma(+hist) -> scan(+tasks) -> scatter2
//   -> attn_task (MFMA; writes attn in TILED fp32 layout)
//   -> mfma_gemm(out, tiled-A + tiled-B, perm)
//
// r8 lessons: top-5 all fillBufferAligned (256MiB harness poison, ~45us —
//   not controllable). All our kernels < 44us, so optimization is now
//   model-driven. The line model (validated r5/r6: scattered 64B lines per
//   instruction serialize on the TA path, ~5cy/line/CU) says prep's tiled
//   WRITES are the biggest remaining offender: thread->src-linear mapping
//   scattered each wave's stores over ~64 lines (16KB span). v9 INVERTS the
//   mapping: thread owns a contiguous 16B chunk of the tiled DEST (stores =
//   contiguous 1KB/instr), reads become 16-row strided but L1/L2-cached
//   (block iterates all 32 frags of one mb over the same 32 rows).
// Tiled layouts (elem offsets, fp16/bf16/fp32 units):
//   A[mb][ks][half]: ((mb*32 + ks*2 + half)*64 + lane)*8,
//     row=mb*32+half*16+(lane&15), k=ks*32+(lane>>4)*8
//   B[nb][ks]: ((nb*16 + ks)*64 + lane)*8, col=nb*16+(lane&15), k=ks*32+(lane>>4)*8
// Q,K precision scheme (argmax needs fp32-class exactness):
//   x = h + l/4096, h=fp16(x) (|x|<2^-14 flushed), l=fp16((x-h)*2^12).
//   hh -> accH; h*l'+l'*h -> accX; C = accH + accX*2^-12. Verified r2-r8.
// scan v3 (r3): shfl prefix scans, ONE atomicAdd per wave.
// hash v4 (r4): 3-term fp16 MFMA + in-reg argmax.
// attn v8 (r7/r8): MFMA wave-split bucket attention, tiled attn output.

#define T_ 2048
#define E_ 512
#define H_ 8
#define DH_ 64
#define B_ 2
#define M_ 4096
#define NROUND 2
#define NBUCKET 32
#define NSEG 32
#define MAXTASK 5120

typedef short v8s __attribute__((ext_vector_type(8)));
typedef _Float16 v8h __attribute__((ext_vector_type(8)));
typedef float v4f __attribute__((ext_vector_type(4)));

__device__ __forceinline__ float bf2f(uint16_t u) {
  union { uint32_t i; float f; } v; v.i = ((uint32_t)u) << 16; return v.f;
}
__device__ __forceinline__ uint16_t f2bf(float f) {
  union { float fv; uint32_t i; } v; v.fv = f;
  uint32_t x = v.i;
  x += 0x7fffu + ((x >> 16) & 1u);   // RN-even
  return (uint16_t)(x >> 16);
}
__device__ __forceinline__ void split8(const float4 a, const float4 b,
                                       v8s& h, v8s& l) {
  const float x[8] = {a.x, a.y, a.z, a.w, b.x, b.y, b.z, b.w};
#pragma unroll
  for (int j = 0; j < 8; j++) {
    const uint16_t hh = f2bf(x[j]);
    h[j] = (short)hh;
    l[j] = (short)f2bf(x[j] - bf2f(hh));
  }
}
// 2-way fp16 split with scaled residual: x = h + l*2^-12, no fp16 subnormals.
__device__ __forceinline__ void split2h8(const float4 a, const float4 b,
                                         v8h& h, v8h& l) {
  const float x[8] = {a.x, a.y, a.z, a.w, b.x, b.y, b.z, b.w};
#pragma unroll
  for (int j = 0; j < 8; j++) {
    const float xv = x[j];
    const _Float16 hh = (fabsf(xv) < 6.1035156e-5f) ? (_Float16)0.0f
                                                    : (_Float16)xv;
    const float r = xv - (float)hh;          // exact (Sterbenz / hh==0)
    h[j] = hh;
    l[j] = (_Float16)(r * 4096.0f);
  }
}

// ---------------------------------------------------------------------------
// prep v9: staging into tiled fragment layouts, DEST-LINEAR (stores are
// contiguous 1KB/instr; strided reads get L1/L2 reuse within a block).
//   blocks [0,384)     : q/k/v fp16 split, gathered, tiled (block per mb)
//   blocks [384,896)   : Wq/Wk/Wv fp16 + Wo bf16 splits, tiled
//   blocks [896,1920)  : zero attn
//   block  1920        : zero cnt region + lshW fp16 split
// ---------------------------------------------------------------------------
__global__ __launch_bounds__(256) void prep_kernel(
    const float* __restrict__ Xq, const float* __restrict__ Xk,
    const float* __restrict__ Xv,
    const float* __restrict__ Wq, const float* __restrict__ Wk,
    const float* __restrict__ Wv, const float* __restrict__ Wo,
    const float* __restrict__ lshW,
    uint16_t* __restrict__ Xqh, uint16_t* __restrict__ Xql,
    uint16_t* __restrict__ Xkh, uint16_t* __restrict__ Xkl,
    uint16_t* __restrict__ Xvh, uint16_t* __restrict__ Xvl,
    uint16_t* __restrict__ Wqh, uint16_t* __restrict__ Wql,
    uint16_t* __restrict__ Wkh, uint16_t* __restrict__ Wkl,
    uint16_t* __restrict__ Wvh, uint16_t* __restrict__ Wvl,
    uint16_t* __restrict__ Woh, uint16_t* __restrict__ Wol,
    uint16_t* __restrict__ Lwh, uint16_t* __restrict__ Lwl,
    float* __restrict__ attn, int* __restrict__ cnt)
{
  const int bid = blockIdx.x;
  const int tid = threadIdx.x;

  if (bid < 384) {                       // q/k/v fp16 split (gathered, tiled)
    const int sel = bid >> 7;            // 0=q,1=k,2=v
    const int mb  = bid & 127;           // 32-row block
    const float* X = (sel == 0) ? Xq : (sel == 1) ? Xk : Xv;
    uint16_t* H = (sel == 0) ? Xqh : (sel == 1) ? Xkh : Xvh;
    uint16_t* L = (sel == 0) ? Xql : (sel == 1) ? Xkl : Xvl;
#pragma unroll
    for (int it = 0; it < 8; it++) {
      const int g = it * 256 + tid;      // chunk within mb: [0,2048)
      const int f = g >> 6;              // frag 0..31 (ks*2+half)
      const int lane = g & 63;
      const int ks = f >> 1, half = f & 1;
      const int p = mb * 32 + half * 16 + (lane & 15);
      const int k = ks * 32 + (lane >> 4) * 8;
      const long src = ((long)(p & 1) * T_ + (p >> 1)) * E_ + k;
      const float4 a = *(const float4*)(X + src);
      const float4 b = *(const float4*)(X + src + 4);
      v8h h, l;
      split2h8(a, b, h, l);
      const long dst = (long)mb * 16384 + (long)g * 8;
      *(v8h*)(H + dst) = h;
      *(v8h*)(L + dst) = l;
    }
    return;
  }

  if (bid < 896) {                       // weight splits, tiled, dest-linear
    const int wsel = (bid - 384) >> 7;   // 0=Wq,1=Wk,2=Wv,3=Wo
    const int g2 = ((bid - 384) & 127) * 256 + tid;   // chunk [0,32768)
    const int f = g2 >> 6;               // frag 0..511 (nb*16+ks)
    const int lane = g2 & 63;
    const int nb = f >> 4, ks = f & 15;
    const int n = nb * 16 + (lane & 15);
    const int k = ks * 32 + (lane >> 4) * 8;
    const long src = (long)n * E_ + k;
    const long dst = (long)g2 * 8;
    if (wsel < 3) {
      const float* S = (wsel == 0) ? Wq : (wsel == 1) ? Wk : Wv;
      const float4 a = *(const float4*)(S + src);
      const float4 b = *(const float4*)(S + src + 4);
      v8h h, l;
      split2h8(a, b, h, l);
      uint16_t* H = (wsel == 0) ? Wqh : (wsel == 1) ? Wkh : Wvh;
      uint16_t* L = (wsel == 0) ? Wql : (wsel == 1) ? Wkl : Wvl;
      *(v8h*)(H + dst) = h;
      *(v8h*)(L + dst) = l;
    } else {
      const float4 a = *(const float4*)(Wo + src);
      const float4 b = *(const float4*)(Wo + src + 4);
      v8s h, l;
      split8(a, b, h, l);
      *(v8s*)(Woh + dst) = h;
      *(v8s*)(Wol + dst) = l;
    }
    return;
  }

  if (bid < 1920) {                      // zero attn: 1024 blocks x 512 float4
    float4* a4 = (float4*)attn;
    const int g = (bid - 896) * 512 + tid * 2;
    a4[g] = make_float4(0.f, 0.f, 0.f, 0.f);
    a4[g + 1] = make_float4(0.f, 0.f, 0.f, 0.f);
    return;
  }

  for (int i = tid; i < 2 * NSEG * NBUCKET + 1; i += 256) cnt[i] = 0;
  for (int i = tid; i < NROUND * DH_ * DH_; i += 256) {  // lshW fp16 split
    const float xv = lshW[i];
    const _Float16 hh = (fabsf(xv) < 6.1035156e-5f) ? (_Float16)0.0f
                                                    : (_Float16)xv;
    const float r = xv - (float)hh;
    *(_Float16*)(Lwh + i) = hh;
    *(_Float16*)(Lwl + i) = (_Float16)(r * 4096.0f);
  }
}

// ---------------------------------------------------------------------------
// proj_mfma v6: fused Q/K/V projections, fp16 3-term, TILED operands.
// grid (32, 8, 3) = 768 blocks; 2x4 16x16 tiles/wave (32x64). Every operand
// load is lane-linear 16B (coalesced 1KB/instr). Register double-buffered.
// ---------------------------------------------------------------------------
__global__ __launch_bounds__(256) void proj_mfma(
    const uint16_t* __restrict__ Aqh, const uint16_t* __restrict__ Aql,
    const uint16_t* __restrict__ Akh, const uint16_t* __restrict__ Akl,
    const uint16_t* __restrict__ Avh, const uint16_t* __restrict__ Avl,
    const uint16_t* __restrict__ Bqh, const uint16_t* __restrict__ Bql,
    const uint16_t* __restrict__ Bkh, const uint16_t* __restrict__ Bkl,
    const uint16_t* __restrict__ Bvh, const uint16_t* __restrict__ Bvl,
    const float* __restrict__ bq, const float* __restrict__ bk,
    const float* __restrict__ bv,
    float* __restrict__ Qo, float* __restrict__ Ko, float* __restrict__ Vo)
{
  const uint16_t *Ah, *Al, *Bh, *Bl;
  const float* bias; float* C;
  if (blockIdx.z == 0)      { Ah = Aqh; Al = Aql; Bh = Bqh; Bl = Bql; bias = bq; C = Qo; }
  else if (blockIdx.z == 1) { Ah = Akh; Al = Akl; Bh = Bkh; Bl = Bkl; bias = bk; C = Ko; }
  else                      { Ah = Avh; Al = Avl; Bh = Bvh; Bl = Bvl; bias = bv; C = Vo; }

  const int wid = threadIdx.x >> 6, lane = threadIdx.x & 63;
  const int mb = blockIdx.x * 4 + wid;        // 32-row block
  const int nb0 = blockIdx.y * 4;             // first 16-col block
  const int m0 = mb * 32, n0 = blockIdx.y * 64;
  const int l15 = lane & 15, quad = lane >> 4;

  // tiled bases (fp16 elem units); frag strides: A ks*1024, half 512; B ks*512
  const long aB = (long)mb * 16384 + lane * 8;
  long bB[4];
#pragma unroll
  for (int j = 0; j < 4; j++) bB[j] = (long)(nb0 + j) * 8192 + lane * 8;

  v4f accH[2][4] = {};
  v4f accX[2][4] = {};

  // prologue: ks = 0
  v8h ah0 = *(const v8h*)(Ah + aB);
  v8h ah1 = *(const v8h*)(Ah + aB + 512);
  v8h al0 = *(const v8h*)(Al + aB);
  v8h al1 = *(const v8h*)(Al + aB + 512);
  v8h bh[4], bl[4];
#pragma unroll
  for (int j = 0; j < 4; j++) {
    bh[j] = *(const v8h*)(Bh + bB[j]);
    bl[j] = *(const v8h*)(Bl + bB[j]);
  }

  for (int ks = 0; ks < 16; ks++) {
    const int kn = (ks + 1) & 15;   // wraps on last iter; values unused
    const v8h nah0 = *(const v8h*)(Ah + aB + kn * 1024);
    const v8h nah1 = *(const v8h*)(Ah + aB + kn * 1024 + 512);
    const v8h nal0 = *(const v8h*)(Al + aB + kn * 1024);
    const v8h nal1 = *(const v8h*)(Al + aB + kn * 1024 + 512);
    v8h nbh[4], nbl[4];
#pragma unroll
    for (int j = 0; j < 4; j++) {
      nbh[j] = *(const v8h*)(Bh + bB[j] + kn * 512);
      nbl[j] = *(const v8h*)(Bl + bB[j] + kn * 512);
    }

    // 24 MFMAs: hh -> accH; h*l' and l'*h -> accX (carries 2^12 scale)
#pragma unroll
    for (int j = 0; j < 4; j++) {
      accH[0][j] = __builtin_amdgcn_mfma_f32_16x16x32_f16(ah0, bh[j], accH[0][j], 0, 0, 0);
      accH[1][j] = __builtin_amdgcn_mfma_f32_16x16x32_f16(ah1, bh[j], accH[1][j], 0, 0, 0);
    }
#pragma unroll
    for (int j = 0; j < 4; j++) {
      accX[0][j] = __builtin_amdgcn_mfma_f32_16x16x32_f16(ah0, bl[j], accX[0][j], 0, 0, 0);
      accX[1][j] = __builtin_amdgcn_mfma_f32_16x16x32_f16(ah1, bl[j], accX[1][j], 0, 0, 0);
    }
#pragma unroll
    for (int j = 0; j < 4; j++) {
      accX[0][j] = __builtin_amdgcn_mfma_f32_16x16x32_f16(al0, bh[j], accX[0][j], 0, 0, 0);
      accX[1][j] = __builtin_amdgcn_mfma_f32_16x16x32_f16(al1, bh[j], accX[1][j], 0, 0, 0);
    }

    // rotate
    ah0 = nah0; al0 = nal0; ah1 = nah1; al1 = nal1;
#pragma unroll
    for (int j = 0; j < 4; j++) { bh[j] = nbh[j]; bl[j] = nbl[j]; }
  }

#pragma unroll
  for (int i = 0; i < 2; i++)
#pragma unroll
    for (int j = 0; j < 4; j++) {
      const int colg = n0 + j * 16 + l15;
      const float bb = bias[colg];
#pragma unroll
      for (int r = 0; r < 4; r++) {
        const int mm = m0 + i * 16 + quad * 4 + r;
        C[(long)mm * E_ + colg] =
            accH[i][j][r] + accX[i][j][r] * (1.0f / 4096.0f) + bb;
      }
    }
}

// ---------------------------------------------------------------------------
// mfma_gemm v8 (out-projection): bf16 3-term. A = attn in TILED fp32
// fragment layout (coalesced lane-linear loads, split in-register);
// B pre-split bf16 TILED. permC write. 256 blocks.
// ---------------------------------------------------------------------------
__global__ __launch_bounds__(256) void mfma_gemm(
    const float* __restrict__ A,
    const uint16_t* __restrict__ Bht, const uint16_t* __restrict__ Blt,
    const float* __restrict__ bias, float* __restrict__ C)
{
  const int wid = threadIdx.x >> 6, lane = threadIdx.x & 63;
  const int mb = blockIdx.x * 4 + wid;
  const int m0 = mb * 32;
  const int nb0 = blockIdx.y * 4;
  const int n0 = blockIdx.y * 64;
  const int l15 = lane & 15, quad = lane >> 4;

  const long aB = (long)mb * 16384 + lane * 8;   // fp32 elems, tiled
  long bB[4];
#pragma unroll
  for (int j = 0; j < 4; j++) bB[j] = (long)(nb0 + j) * 8192 + lane * 8;

  v4f acc[2][4] = {};
  for (int ks = 0; ks < 16; ks++) {
    const long a0 = aB + ks * 1024;     // half 0
    const long a1 = a0 + 512;           // half 1
    v8s ah0, al0, ah1, al1;
    split8(*(const float4*)(A + a0), *(const float4*)(A + a0 + 4), ah0, al0);
    split8(*(const float4*)(A + a1), *(const float4*)(A + a1 + 4), ah1, al1);
    v8s bh[4], bl[4];
#pragma unroll
    for (int j = 0; j < 4; j++) {
      bh[j] = *(const v8s*)(Bht + bB[j] + ks * 512);
      bl[j] = *(const v8s*)(Blt + bB[j] + ks * 512);
    }
#pragma unroll
    for (int j = 0; j < 4; j++) {
      acc[0][j] = __builtin_amdgcn_mfma_f32_16x16x32_bf16(ah0, bh[j], acc[0][j], 0, 0, 0);
      acc[1][j] = __builtin_amdgcn_mfma_f32_16x16x32_bf16(ah1, bh[j], acc[1][j], 0, 0, 0);
    }
#pragma unroll
    for (int j = 0; j < 4; j++) {
      acc[0][j] = __builtin_amdgcn_mfma_f32_16x16x32_bf16(ah0, bl[j], acc[0][j], 0, 0, 0);
      acc[1][j] = __builtin_amdgcn_mfma_f32_16x16x32_bf16(ah1, bl[j], acc[1][j], 0, 0, 0);
    }
#pragma unroll
    for (int j = 0; j < 4; j++) {
      acc[0][j] = __builtin_amdgcn_mfma_f32_16x16x32_bf16(al0, bh[j], acc[0][j], 0, 0, 0);
      acc[1][j] = __builtin_amdgcn_mfma_f32_16x16x32_bf16(al1, bh[j], acc[1][j], 0, 0, 0);
    }
  }

#pragma unroll
  for (int i = 0; i < 2; i++)
#pragma unroll
    for (int j = 0; j < 4; j++) {
      const int colg = n0 + j * 16 + l15;
      const float bb = bias[colg];
#pragma unroll
      for (int r = 0; r < 4; r++) {
        const int mm = m0 + i * 16 + quad * 4 + r;
        const int crow = (mm & (T_ - 1)) * B_ + (mm >> 11);
        C[(long)crow * E_ + colg] = acc[i][j][r] + bb;
      }
    }
}

// ---------------------------------------------------------------------------
// hash_mfma v4: LSH hash as 3-term fp16 MFMA GEMM + in-register argmax.
// grid (256, 4): y = src*2 + r; 256 thr; wave does 32 rows (2x4 tiles, K=64).
// ---------------------------------------------------------------------------
__global__ __launch_bounds__(256) void hash_mfma(
    const float* __restrict__ Q, const float* __restrict__ K,
    const uint16_t* __restrict__ Lwh, const uint16_t* __restrict__ Lwl,
    const float* __restrict__ lshb,
    int* __restrict__ qh, int* __restrict__ kh,
    int* __restrict__ qcnt, int* __restrict__ kcnt)
{
  const int comb = blockIdx.y;               // 0..3
  const int src = comb >> 1, r = comb & 1;
  const float* X = src ? K : Q;
  int* outh = src ? kh : qh;
  int* cnt  = src ? kcnt : qcnt;

  const int wid = threadIdx.x >> 6, lane = threadIdx.x & 63;
  const int m0 = (blockIdx.x * 4 + wid) * 32;  // head-row base (32 rows/wave)
  const int l15 = lane & 15, quad = lane >> 4;

  v8h bh[4][2], bl[4][2];
#pragma unroll
  for (int n = 0; n < 4; n++)
#pragma unroll
    for (int k = 0; k < 2; k++) {
      const int o = r * (DH_ * DH_) + (n * 16 + l15) * DH_ + k * 32 + quad * 8;
      bh[n][k] = *(const v8h*)(Lwh + o);
      bl[n][k] = *(const v8h*)(Lwl + o);
    }

  v4f accH[2][4] = {};
  v4f accX[2][4] = {};
#pragma unroll
  for (int k = 0; k < 2; k++) {
    const long a0 = (long)(m0 + l15) * DH_ + k * 32 + quad * 8;
    const long a1 = a0 + 16L * DH_;
    v8h ah0, al0, ah1, al1;
    split2h8(*(const float4*)(X + a0), *(const float4*)(X + a0 + 4), ah0, al0);
    split2h8(*(const float4*)(X + a1), *(const float4*)(X + a1 + 4), ah1, al1);
#pragma unroll
    for (int n = 0; n < 4; n++) {
      accH[0][n] = __builtin_amdgcn_mfma_f32_16x16x32_f16(ah0, bh[n][k], accH[0][n], 0, 0, 0);
      accH[1][n] = __builtin_amdgcn_mfma_f32_16x16x32_f16(ah1, bh[n][k], accH[1][n], 0, 0, 0);
      accX[0][n] = __builtin_amdgcn_mfma_f32_16x16x32_f16(ah0, bl[n][k], accX[0][n], 0, 0, 0);
      accX[1][n] = __builtin_amdgcn_mfma_f32_16x16x32_f16(ah1, bl[n][k], accX[1][n], 0, 0, 0);
      accX[0][n] = __builtin_amdgcn_mfma_f32_16x16x32_f16(al0, bh[n][k], accX[0][n], 0, 0, 0);
      accX[1][n] = __builtin_amdgcn_mfma_f32_16x16x32_f16(al1, bh[n][k], accX[1][n], 0, 0, 0);
    }
  }

  float bb[4];
#pragma unroll
  for (int n = 0; n < 4; n++) bb[n] = lshb[r * DH_ + n * 16 + l15];

#pragma unroll
  for (int i = 0; i < 2; i++)
#pragma unroll
    for (int reg = 0; reg < 4; reg++) {
      float bv = -INFINITY; int bi = 0x7fffffff;
#pragma unroll
      for (int n = 0; n < 4; n++) {
        const float v = accH[i][n][reg] + accX[i][n][reg] * (1.0f / 4096.0f)
                        + bb[n];
        const int idx = n * 16 + l15;
        if (v > bv || (v == bv && idx < bi)) { bv = v; bi = idx; }
      }
#pragma unroll
      for (int d = 8; d >= 1; d >>= 1) {
        const float ov = __shfl_xor(bv, d);
        const int oi = __shfl_xor(bi, d);
        if (ov > bv || (ov == bv && oi < bi)) { bv = ov; bi = oi; }
      }
      if (l15 == 0) {
        const int hr = m0 + i * 16 + quad * 4 + reg;
        const int p = hr >> 3, hh = hr & 7;
        const int bt = p >> 11, t = p & (T_ - 1);
        const int seg = r * 16 + bt * H_ + hh;
        outh[seg * T_ + t] = bi;
        if (bi < NBUCKET) atomicAdd(&cnt[seg * NBUCKET + bi], 1);
      }
    }
}

// ---------------------------------------------------------------------------
// Scan v3: 2 blocks x 1024 threads; one thread per (seg,bucket).
// ---------------------------------------------------------------------------
__global__ __launch_bounds__(1024) void scan_kernel(
    const int* __restrict__ kcnt, int* __restrict__ koff,
    int* __restrict__ kcur,
    const int* __restrict__ qcnt, int* __restrict__ qoff,
    int* __restrict__ qcur,
    int* __restrict__ ntasks, int* __restrict__ tasks)
{
  const int tid = threadIdx.x;          // 0..1023
  const int isq = blockIdx.x;           // 0 = k-side, 1 = q-side
  const int seg = tid >> 5;             // 0..31
  const int b   = tid & 31;             // bucket
  const int* cnt = isq ? qcnt : kcnt;
  int* off = isq ? qoff : koff;
  int* cur = isq ? qcur : kcur;

  const int c = cnt[seg * NBUCKET + b];

  int s = c;
#pragma unroll
  for (int d = 1; d < 32; d <<= 1) {
    const int t = __shfl_up(s, d, 32);
    if (b >= d) s += t;
  }
  const int excl = s - c;
  off[seg * (NBUCKET + 1) + b] = excl;
  cur[seg * NBUCKET + b] = excl;
  if (b == 31) off[seg * (NBUCKET + 1) + NBUCKET] = s;

  if (isq) {
    const int nt = (c + 15) >> 4;
    const int lane = tid & 63;
    int ws = nt;
#pragma unroll
    for (int d = 1; d < 64; d <<= 1) {
      const int t = __shfl_up(ws, d, 64);
      if (lane >= d) ws += t;
    }
    const int wtotal = __shfl(ws, 63, 64);
    int base = 0;
    if (lane == 63 && wtotal > 0) base = atomicAdd(ntasks, wtotal);
    base = __shfl(base, 63, 64);
    const int my = base + ws - nt;
    for (int i = 0; i < nt; i++)
      tasks[my + i] = (seg << 16) | (b << 8) | i;
  }
}

__global__ __launch_bounds__(256) void scatter2_kernel(
    const int* __restrict__ kh, const int* __restrict__ qh,
    int* __restrict__ kcur, int* __restrict__ qcur,
    int* __restrict__ klist, int* __restrict__ qlist)
{
  const int idx = blockIdx.x * 256 + threadIdx.x;
  const int y = blockIdx.y;
  const int* hsh = y ? qh : kh;
  int* cur = y ? qcur : kcur;
  int* list = y ? qlist : klist;
  const int v = hsh[idx];
  if (v < NBUCKET) {
    const int seg = idx >> 11;
    const int pos = atomicAdd(&cur[seg * NBUCKET + v], 1);
    list[seg * T_ + pos] = idx & (T_ - 1);
  }
}

// ---------------------------------------------------------------------------
// attn_task v8: MFMA bucket attention; epilogue writes attn in the TILED
// fp32 A-fragment layout for the out-projection.
// ---------------------------------------------------------------------------
__global__ __launch_bounds__(256) void attn_task(
    const float* __restrict__ Q, const float* __restrict__ K,
    const float* __restrict__ V,
    const int* __restrict__ qlist, const int* __restrict__ qoff,
    const int* __restrict__ klist, const int* __restrict__ koff,
    const int* __restrict__ tasks, const int* __restrict__ ntasks,
    float* __restrict__ attn)
{
  __shared__ __align__(16) float Plds[16][68];
  __shared__ __align__(16) float Vts[64][68];
  __shared__ float larr[16];

  if ((int)blockIdx.x >= *ntasks) return;
  const int tk = tasks[blockIdx.x];
  const int seg = tk >> 16, bucket = (tk >> 8) & 255, qt = tk & 255;
  const int ctx = seg & 15;
  const int b = ctx >> 3, h = ctx & 7;

  const int qlo = qoff[seg * (NBUCKET + 1) + bucket] + qt * 16;
  const int nqt = min(16, qoff[seg * (NBUCKET + 1) + bucket + 1] - qlo);
  const int klo = koff[seg * (NBUCKET + 1) + bucket];
  const int nk  = koff[seg * (NBUCKET + 1) + bucket + 1] - klo;
  if (nk == 0) return;

  const int tid = threadIdx.x;
  const int wid = tid >> 6, lane = tid & 63;
  const int l15 = lane & 15, quad = lane >> 4;
  const int r0 = tid >> 4, c4 = tid & 15;   // V-staging coords

  const float* Qb = Q + ((long)b * T_) * E_ + h * DH_;
  const float* Kb = K + ((long)b * T_) * E_ + h * DH_;
  const float* Vb = V + ((long)b * T_) * E_ + h * DH_;
  const int* ql = qlist + seg * T_;
  const int* kl = klist + seg * T_;

  if (tid < 16) larr[tid] = 0.f;

  // Q A-fragments: row=q=l15 (clamped), k=dim quad*8 (+32 per ks)
  const long qrow = (long)ql[qlo + min(l15, nqt - 1)] * E_;
  v8s qfh[2], qfl[2];
#pragma unroll
  for (int ks = 0; ks < 2; ks++) {
    const float4 a = *(const float4*)(Qb + qrow + ks * 32 + quad * 8);
    const float4 c = *(const float4*)(Qb + qrow + ks * 32 + quad * 8 + 4);
    split8(a, c, qfh[ks], qfl[ks]);
  }
  __syncthreads();          // larr init visible before first atomics

  v4f oacc = {0.f, 0.f, 0.f, 0.f};

  for (int kt = 0; kt < nk; kt += 64) {
    // --- V tile loads into registers (latency hides under QK MFMAs) ---
    float4 vreg[4];
#pragma unroll
    for (int it = 0; it < 4; it++) {
      const int key = kt + it * 16 + r0;
      const long krow = (long)kl[klo + min(key, nk - 1)] * E_;
      vreg[it] = *(const float4*)(Vb + krow + c4 * 4);
    }

    // --- QK^T: this wave's 16 keys (cols = l15), bf16 3-term ---
    const int keyg = kt + wid * 16 + l15;
    const long krow = (long)kl[klo + min(keyg, nk - 1)] * E_;
    v4f sacc = {0.f, 0.f, 0.f, 0.f};
#pragma unroll
    for (int ks = 0; ks < 2; ks++) {
      const float4 a = *(const float4*)(Kb + krow + ks * 32 + quad * 8);
      const float4 c = *(const float4*)(Kb + krow + ks * 32 + quad * 8 + 4);
      v8s kfh, kfl;
      split8(a, c, kfh, kfl);
      sacc = __builtin_amdgcn_mfma_f32_16x16x32_bf16(qfh[ks], kfh, sacc, 0, 0, 0);
      sacc = __builtin_amdgcn_mfma_f32_16x16x32_bf16(qfh[ks], kfl, sacc, 0, 0, 0);
      sacc = __builtin_amdgcn_mfma_f32_16x16x32_bf16(qfl[ks], kfh, sacc, 0, 0, 0);
    }

    const bool kvalid = keyg < nk;
    const float p0 = kvalid ? __expf(sacc[0] * 0.125f) : 0.f;
    const float p1 = kvalid ? __expf(sacc[1] * 0.125f) : 0.f;
    const float p2 = kvalid ? __expf(sacc[2] * 0.125f) : 0.f;
    const float p3 = kvalid ? __expf(sacc[3] * 0.125f) : 0.f;

    float rs0 = p0, rs1 = p1, rs2 = p2, rs3 = p3;
#pragma unroll
    for (int d = 1; d < 16; d <<= 1) {
      rs0 += __shfl_xor(rs0, d);
      rs1 += __shfl_xor(rs1, d);
      rs2 += __shfl_xor(rs2, d);
      rs3 += __shfl_xor(rs3, d);
    }
    if (l15 == 0) {
      atomicAdd(&larr[quad * 4 + 0], rs0);
      atomicAdd(&larr[quad * 4 + 1], rs1);
      atomicAdd(&larr[quad * 4 + 2], rs2);
      atomicAdd(&larr[quad * 4 + 3], rs3);
    }
    Plds[quad * 4 + 0][wid * 16 + l15] = p0;
    Plds[quad * 4 + 1][wid * 16 + l15] = p1;
    Plds[quad * 4 + 2][wid * 16 + l15] = p2;
    Plds[quad * 4 + 3][wid * 16 + l15] = p3;

    // --- Vt transpose store (waits on vreg loads here, post-MFMA) ---
#pragma unroll
    for (int it = 0; it < 4; it++) {
      const int row = it * 16 + r0;
      Vts[c4 * 4 + 0][row] = vreg[it].x;
      Vts[c4 * 4 + 1][row] = vreg[it].y;
      Vts[c4 * 4 + 2][row] = vreg[it].z;
      Vts[c4 * 4 + 3][row] = vreg[it].w;
    }
    __syncthreads();

    // --- PV: this wave's 16 dims (cols = wid*16+l15), keys as K-dim ---
#pragma unroll
    for (int ks = 0; ks < 2; ks++) {
      const float4 pa = *(const float4*)&Plds[l15][ks * 32 + quad * 8];
      const float4 pb = *(const float4*)&Plds[l15][ks * 32 + quad * 8 + 4];
      v8s pah, pal;
      split8(pa, pb, pah, pal);
      const float4 va = *(const float4*)&Vts[wid * 16 + l15][ks * 32 + quad * 8];
      const float4 vb = *(const float4*)&Vts[wid * 16 + l15][ks * 32 + quad * 8 + 4];
      v8s vfh, vfl;
      split8(va, vb, vfh, vfl);
      oacc = __builtin_amdgcn_mfma_f32_16x16x32_bf16(pah, vfh, oacc, 0, 0, 0);
      oacc = __builtin_amdgcn_mfma_f32_16x16x32_bf16(pah, vfl, oacc, 0, 0, 0);
      oacc = __builtin_amdgcn_mfma_f32_16x16x32_bf16(pal, vfh, oacc, 0, 0, 0);
    }
    __syncthreads();
  }

  // epilogue: oacc row q=quad*4+r, col d=wid*16+l15; write TILED attn:
  // p = b*T+t (row), kd = h*64+d (col);
  const int kd = h * DH_ + wid * 16 + l15;
  const int kpart = (kd >> 5) * 2 * 512 + ((kd >> 3) & 3) * 16 * 8 + (kd & 7);
#pragma unroll
  for (int r = 0; r < 4; r++) {
    const int q = quad * 4 + r;
    if (q < nqt) {
      const float inv = 0.5f / larr[q];
      const int t = ql[qlo + q];
      const int p = b * T_ + t;
      const long off = (long)(p >> 5) * 16384 + ((p >> 4) & 1) * 512
                       + (p & 15) * 8 + kpart;
      atomicAdd(attn + off, oacc[r] * inv);
    }
  }
}

// ---------------------------------------------------------------------------
extern "C" void kernel_launch(void* const* d_in, const int* in_sizes, int n_in,
                              void* d_out, int out_size, void* d_ws, size_t ws_size,
                              hipStream_t stream) {
  const float* query = (const float*)d_in[0];
  const float* key   = (const float*)d_in[1];
  const float* value = (const float*)d_in[2];
  const float* Wq = (const float*)d_in[3];
  const float* bq = (const float*)d_in[4];
  const float* Wk = (const float*)d_in[5];
  const float* bk = (const float*)d_in[6];
  const float* Wv = (const float*)d_in[7];
  const float* bv = (const float*)d_in[8];
  const float* Wo = (const float*)d_in[9];
  const float* bo = (const float*)d_in[10];
  const float* lshW = (const float*)d_in[11];
  const float* lshb = (const float*)d_in[12];

  const size_t MSZ = (size_t)M_ * E_;
  const size_t WSZ = (size_t)E_ * E_;
  float* Q    = (float*)d_ws;
  float* K    = Q + MSZ;
  float* V    = K + MSZ;
  float* attn = V + MSZ;
  int* qh     = (int*)(attn + MSZ);
  int* kh     = qh + NSEG * T_;
  int* klist  = kh + NSEG * T_;
  int* qlist  = klist + NSEG * T_;
  int* kcnt   = qlist + NSEG * T_;       // start of zeroed region
  int* qcnt   = kcnt + NSEG * NBUCKET;
  int* ntasks = qcnt + NSEG * NBUCKET;   // end of zeroed region
  int* kcur   = ntasks + 1;
  int* qcur   = kcur + NSEG * NBUCKET;
  int* koff   = qcur + NSEG * NBUCKET;
  int* qoff   = koff + NSEG * (NBUCKET + 1);
  int* tasks  = qoff + NSEG * (NBUCKET + 1);
  uint16_t* Woh = (uint16_t*)(((uintptr_t)(tasks + MAXTASK) + 15) & ~(uintptr_t)15);
  uint16_t* Wol = Woh + WSZ;
  uint16_t* Wqh = Wol + WSZ;
  uint16_t* Wql = Wqh + WSZ;
  uint16_t* Wkh = Wql + WSZ;
  uint16_t* Wkl = Wkh + WSZ;
  uint16_t* Wvh = Wkl + WSZ;
  uint16_t* Wvl = Wvh + WSZ;
  uint16_t* Xqh = Wvl + WSZ;
  uint16_t* Xql = Xqh + MSZ;
  uint16_t* Xkh = Xql + MSZ;
  uint16_t* Xkl = Xkh + MSZ;
  uint16_t* Xvh = Xkl + MSZ;
  uint16_t* Xvl = Xvh + MSZ;
  uint16_t* Lwh = Xvl + MSZ;
  uint16_t* Lwl = Lwh + (size_t)NROUND * DH_ * DH_;

  prep_kernel<<<dim3(1921), 256, 0, stream>>>(
      query, key, value, Wq, Wk, Wv, Wo, lshW,
      Xqh, Xql, Xkh, Xkl, Xvh, Xvl,
      Wqh, Wql, Wkh, Wkl, Wvh, Wvl, Woh, Wol,
      Lwh, Lwl, attn, kcnt);
  proj_mfma<<<dim3(M_ / 128, E_ / 64, 3), 256, 0, stream>>>(
      Xqh, Xql, Xkh, Xkl, Xvh, Xvl,
      Wqh, Wql, Wkh, Wkl, Wvh, Wvl,
      bq, bk, bv, Q, K, V);
  hash_mfma<<<dim3(M_ * H_ / 128, 4), 256, 0, stream>>>(
      Q, K, Lwh, Lwl, lshb, qh, kh, qcnt, kcnt);
  scan_kernel<<<dim3(2), 1024, 0, stream>>>(kcnt, koff, kcur, qcnt, qoff, qcur,
                                            ntasks, tasks);
  scatter2_kernel<<<dim3(NSEG * T_ / 256, 2), 256, 0, stream>>>(
      kh, qh, kcur, qcur, klist, qlist);
  attn_task<<<dim3(MAXTASK), 256, 0, stream>>>(
      Q, K, V, qlist, qoff, klist, koff, tasks, ntasks, attn);
  mfma_gemm<<<dim3(M_ / 128, E_ / 64), 256, 0, stream>>>(
      attn, Woh, Wol, bo, (float*)d_out);
}